// Round 1
// baseline (720.489 us; speedup 1.0000x reference)
//
#include <hip/hip_runtime.h>
#include <stdint.h>

// ---------- small helpers ----------
typedef __attribute__((ext_vector_type(8))) short bf16x8;
typedef __attribute__((ext_vector_type(4))) float floatx4;

__device__ __forceinline__ uint16_t f2bf(float f) {
  union { float f; uint32_t u; } v; v.f = f;
  uint32_t r = v.u + 0x7fffu + ((v.u >> 16) & 1u);
  return (uint16_t)(r >> 16);
}
__device__ __forceinline__ float bf2f(uint16_t b) {
  union { uint32_t u; float f; } v; v.u = ((uint32_t)b) << 16;
  return v.f;
}
__device__ __forceinline__ float ld_as_float(float v) { return v; }
__device__ __forceinline__ float ld_as_float(uint16_t v) { return bf2f(v); }

__device__ __forceinline__ void mfma16(floatx4& d, bf16x8 a, bf16x8 b) {
  asm("v_mfma_f32_16x16x32_bf16 %0, %1, %2, %0" : "+v"(d) : "v"(a), "v"(b));
}

// ---------- GEMM: C(M,N) = A(M,K) @ B(N,K)^T, bf16 in, fp32 acc ----------
// 128x128 tile, BK=32, 4 waves (2x2), 16x16x32 MFMA, global_load_lds staging.
// grid = (M/128, N/128, batches), block = 256.
template<int OUTB>  // 0: fp32 out, 1: bf16 out
__global__ void __launch_bounds__(256) gemm_bt(
    const uint16_t* __restrict__ A, const uint16_t* __restrict__ B,
    void* __restrict__ Cv, int K, int lda, int ldb, int ldc,
    long sA, long sB, long sC)
{
  __shared__ alignas(16) uint16_t As[4096];  // 128 rows x 32 cols
  __shared__ alignas(16) uint16_t Bs[4096];
  const int tid = threadIdx.x;
  const int w = tid >> 6, l = tid & 63;
  const int wr = w >> 1, wc = w & 1;
  const long bm = (long)blockIdx.x * 128, bn = (long)blockIdx.y * 128;
  A += (long)blockIdx.z * sA;
  B += (long)blockIdx.z * sB;

  // staging: 8 chunks of 16 rows each; wave w owns chunks w and w+4.
  // lane l -> row (l>>2) of chunk, 8 bf16 at col (l&3)*8. LDS dest = base + lane*16B.
  const uint16_t* ga0 = A + (bm + w * 16 + (l >> 2)) * (long)lda + (l & 3) * 8;
  const uint16_t* ga1 = ga0 + 64L * lda;
  const uint16_t* gb0 = B + (bn + w * 16 + (l >> 2)) * (long)ldb + (l & 3) * 8;
  const uint16_t* gb1 = gb0 + 64L * ldb;
  uint16_t* la0 = &As[w * 512];
  uint16_t* la1 = &As[2048 + w * 512];
  uint16_t* lb0 = &Bs[w * 512];
  uint16_t* lb1 = &Bs[2048 + w * 512];

  floatx4 acc[4][4];
#pragma unroll
  for (int i = 0; i < 4; i++)
#pragma unroll
    for (int j = 0; j < 4; j++) acc[i][j] = (floatx4){0.f, 0.f, 0.f, 0.f};

  // fragment read offsets (elements): row*(32) + (l>>4)*8
  const int rA = (wr * 64 + (l & 15)) * 32 + (l >> 4) * 8;
  const int rB = (wc * 64 + (l & 15)) * 32 + (l >> 4) * 8;

  for (int k0 = 0; k0 < K; k0 += 32) {
    __builtin_amdgcn_global_load_lds(ga0, la0, 16, 0, 0);
    __builtin_amdgcn_global_load_lds(ga1, la1, 16, 0, 0);
    __builtin_amdgcn_global_load_lds(gb0, lb0, 16, 0, 0);
    __builtin_amdgcn_global_load_lds(gb1, lb1, 16, 0, 0);
    ga0 += 32; ga1 += 32; gb0 += 32; gb1 += 32;
    __syncthreads();
    bf16x8 af[4], bfr[4];
#pragma unroll
    for (int i = 0; i < 4; i++) af[i] = *(const bf16x8*)&As[rA + i * 512];
#pragma unroll
    for (int j = 0; j < 4; j++) bfr[j] = *(const bf16x8*)&Bs[rB + j * 512];
#pragma unroll
    for (int i = 0; i < 4; i++)
#pragma unroll
      for (int j = 0; j < 4; j++) mfma16(acc[i][j], af[i], bfr[j]);
    __syncthreads();
  }

  const long crow = bm + wr * 64 + ((l >> 4) * 4);
  const long ccol = bn + wc * 64 + (l & 15);
  if constexpr (OUTB == 0) {
    float* C = (float*)Cv + (long)blockIdx.z * sC;
#pragma unroll
    for (int i = 0; i < 4; i++)
#pragma unroll
      for (int r = 0; r < 4; r++) {
        long row = crow + i * 16 + r;
#pragma unroll
        for (int j = 0; j < 4; j++) C[row * (long)ldc + ccol + j * 16] = acc[i][j][r];
      }
  } else {
    uint16_t* C = (uint16_t*)Cv + (long)blockIdx.z * sC;
#pragma unroll
    for (int i = 0; i < 4; i++)
#pragma unroll
      for (int r = 0; r < 4; r++) {
        long row = crow + i * 16 + r;
#pragma unroll
        for (int j = 0; j < 4; j++) C[row * (long)ldc + ccol + j * 16] = f2bf(acc[i][j][r]);
      }
  }
}

// ---------- fp32 -> bf16 convert (n % 4 == 0) ----------
__global__ void __launch_bounds__(256) cvt_k(const float* __restrict__ in,
                                             uint16_t* __restrict__ out, long n) {
  long i = ((long)blockIdx.x * 256 + threadIdx.x) * 4;
  if (i >= n) return;
  float4 v = *(const float4*)(in + i);
  ushort4 o; o.x = f2bf(v.x); o.y = f2bf(v.y); o.z = f2bf(v.z); o.w = f2bf(v.w);
  *(ushort4*)(out + i) = o;
}

// ---------- transpose (R,Cc) -> (Cc,R), output bf16; grid (Cc/32, R/32, bat), block (32,8) ----------
template<typename TIN>
__global__ void __launch_bounds__(256) transpose_to_bf16(
    const TIN* __restrict__ in, uint16_t* __restrict__ out,
    int ld_in, int ld_out, long sIn, long sOut)
{
  __shared__ float tile[32][33];
  in += (long)blockIdx.z * sIn;
  out += (long)blockIdx.z * sOut;
  const int rb = blockIdx.y * 32, cb = blockIdx.x * 32;
#pragma unroll
  for (int i = 0; i < 32; i += 8)
    tile[threadIdx.y + i][threadIdx.x] =
        ld_as_float(in[(long)(rb + threadIdx.y + i) * ld_in + cb + threadIdx.x]);
  __syncthreads();
#pragma unroll
  for (int i = 0; i < 32; i += 8)
    out[(long)(cb + threadIdx.y + i) * ld_out + rb + threadIdx.x] =
        f2bf(tile[threadIdx.x][threadIdx.y + i]);
}

// ---------- rmsnorm: one block per row; DIM = PT*256 ----------
template<int PT>
__global__ void __launch_bounds__(256) rmsnorm_k(
    const float* __restrict__ in, const float* __restrict__ g,
    float* __restrict__ out_f, uint16_t* __restrict__ out_b, int ld_b)
{
  constexpr int DIM = PT * 256;
  __shared__ float sm[9];
  const float* x = in + (long)blockIdx.x * DIM;
  const int base = threadIdx.x * PT;
  float v[PT];
  if constexpr (PT == 2) {
    float2 t = *(const float2*)&x[base]; v[0] = t.x; v[1] = t.y;
  } else {
#pragma unroll
    for (int i = 0; i < PT; i += 4) {
      float4 t = *(const float4*)&x[base + i];
      v[i] = t.x; v[i + 1] = t.y; v[i + 2] = t.z; v[i + 3] = t.w;
    }
  }
  float ss = 0.f;
#pragma unroll
  for (int i = 0; i < PT; i++) ss += v[i] * v[i];
#pragma unroll
  for (int o = 32; o; o >>= 1) ss += __shfl_down(ss, o);
  if ((threadIdx.x & 63) == 0) sm[threadIdx.x >> 6] = ss;
  __syncthreads();
  if (threadIdx.x == 0)
    sm[8] = rsqrtf((sm[0] + sm[1] + sm[2] + sm[3]) * (1.0f / DIM) + 1.1920929e-7f);
  __syncthreads();
  const float sc = sm[8];
#pragma unroll
  for (int i = 0; i < PT; i++) {
    float y = v[i] * sc * g[base + i];
    if (out_f) out_f[(long)blockIdx.x * DIM + base + i] = y;
    if (out_b) out_b[(long)blockIdx.x * ld_b + base + i] = f2bf(y);
  }
}

// ---------- rope table: tab[s*64 + i] = (cos, sin)(s * 10000^(-i/64)) ----------
__global__ void __launch_bounds__(256) rope_table(float2* __restrict__ tab) {
  int idx = blockIdx.x * 256 + threadIdx.x;  // 2048*64
  int s = idx >> 6, fi = idx & 63;
  float f = powf(10000.0f, -(float)fi * (1.0f / 64.0f));
  float ang = (float)s * f;
  tab[idx] = make_float2(cosf(ang), sinf(ang));
}

// ---------- rope apply: in fp32 (8192,2048); bf16 out -> cat[:,512:] ; optional fp32 out ----------
template<bool WF32>
__global__ void __launch_bounds__(256) rope_k(
    const float* __restrict__ in, uint16_t* __restrict__ outb,
    float* __restrict__ outf, const float2* __restrict__ tab)
{
  long idx = (long)blockIdx.x * 256 + threadIdx.x;  // 8192*1024 pairs
  int r = (int)(idx >> 10);
  int pp = (int)idx & 1023;
  int s = r & 2047;
  int fi = pp & 63;
  float2 x = *(const float2*)(in + ((long)r << 11) + 2 * pp);
  float2 cs = tab[(s << 6) + fi];
  float y0 = x.x * cs.x - x.y * cs.y;
  float y1 = x.x * cs.y + x.y * cs.x;
  ushort2 ov; ov.x = f2bf(y0); ov.y = f2bf(y1);
  *(ushort2*)(outb + (long)r * 2560 + 512 + 2 * pp) = ov;
  if (WF32) *(float2*)(outf + ((long)r << 11) + 2 * pp) = make_float2(y0, y1);
}

// ---------- softmax over rows of 2048, scale 1/12, fp32 in, bf16 out ----------
__global__ void __launch_bounds__(256) softmax_k(const float* __restrict__ sc,
                                                 uint16_t* __restrict__ attn) {
  __shared__ float sm[9];
  const float* x = sc + ((long)blockIdx.x << 11);
  const int base = threadIdx.x * 8;
  float v[8];
  *(float4*)&v[0] = *(const float4*)&x[base];
  *(float4*)&v[4] = *(const float4*)&x[base + 4];
  const float inv = 1.0f / 12.0f;
  float m = -1e30f;
#pragma unroll
  for (int i = 0; i < 8; i++) { v[i] *= inv; m = fmaxf(m, v[i]); }
#pragma unroll
  for (int o = 32; o; o >>= 1) m = fmaxf(m, __shfl_down(m, o));
  if ((threadIdx.x & 63) == 0) sm[threadIdx.x >> 6] = m;
  __syncthreads();
  if (threadIdx.x == 0)
    sm[8] = fmaxf(fmaxf(sm[0], sm[1]), fmaxf(sm[2], sm[3]));
  __syncthreads();
  m = sm[8];
  __syncthreads();
  float ss = 0.f;
#pragma unroll
  for (int i = 0; i < 8; i++) { v[i] = __expf(v[i] - m); ss += v[i]; }
#pragma unroll
  for (int o = 32; o; o >>= 1) ss += __shfl_down(ss, o);
  if ((threadIdx.x & 63) == 0) sm[threadIdx.x >> 6] = ss;
  __syncthreads();
  if (threadIdx.x == 0) sm[8] = 1.0f / (sm[0] + sm[1] + sm[2] + sm[3]);
  __syncthreads();
  const float r = sm[8];
  ushort4 o1, o2;
  o1.x = f2bf(v[0] * r); o1.y = f2bf(v[1] * r); o1.z = f2bf(v[2] * r); o1.w = f2bf(v[3] * r);
  o2.x = f2bf(v[4] * r); o2.y = f2bf(v[5] * r); o2.z = f2bf(v[6] * r); o2.w = f2bf(v[7] * r);
  uint16_t* dst = attn + ((long)blockIdx.x << 11) + base;
  *(ushort4*)dst = o1;
  *(ushort4*)(dst + 4) = o2;
}

// ---------- orchestration ----------
extern "C" void kernel_launch(void* const* d_in, const int* in_sizes, int n_in,
                              void* d_out, int out_size, void* d_ws, size_t ws_size,
                              hipStream_t stream) {
  (void)in_sizes; (void)n_in; (void)out_size; (void)ws_size;
  const float* h    = (const float*)d_in[0];
  const float* wdkv = (const float*)d_in[1];
  const float* wuk  = (const float*)d_in[2];
  const float* wuv  = (const float*)d_in[3];
  const float* wdq  = (const float*)d_in[4];
  const float* wuq  = (const float*)d_in[5];
  const float* wkr  = (const float*)d_in[6];
  const float* wqr  = (const float*)d_in[7];
  const float* wo   = (const float*)d_in[8];
  const float* g1   = (const float*)d_in[9];
  const float* g2   = (const float*)d_in[10];
  const float* g3   = (const float*)d_in[11];

  float* u_out   = (float*)d_out;                 // (4,2048,2048)
  float* ckv_out = u_out + 16777216L;             // (4,2048,512)
  float* kr_out  = ckv_out + 4194304L;            // (4,2048,2048)

  char* p = (char*)d_ws;
  auto alloc = [&](size_t bytes) -> void* {
    void* q = (void*)p; p += (bytes + 255) & ~(size_t)255; return q;
  };
  uint16_t* hb     = (uint16_t*)alloc(16777216ULL * 2);  // h bf16
  uint16_t* wdq_b  = (uint16_t*)alloc(1048576ULL * 2);
  uint16_t* wdkv_b = (uint16_t*)alloc(1048576ULL * 2);
  uint16_t* wqr_b  = (uint16_t*)alloc(1048576ULL * 2);
  uint16_t* wkr_b  = (uint16_t*)alloc(4194304ULL * 2);
  uint16_t* wo_b   = (uint16_t*)alloc(4194304ULL * 2);
  uint16_t* wukT   = (uint16_t*)alloc(1048576ULL * 2);   // (512,2048)
  uint16_t* wuqT   = (uint16_t*)alloc(1048576ULL * 2);
  uint16_t* wuvT   = (uint16_t*)alloc(1048576ULL * 2);
  uint16_t* wdqT   = (uint16_t*)alloc(1048576ULL * 2);   // (2048,512)
  uint16_t* T1t    = (uint16_t*)alloc(262144ULL * 2);    // (512,512)
  uint16_t* Bqt    = (uint16_t*)alloc(1048576ULL * 2);   // absorbed_w_q^T (512,2048)
  uint16_t* awoT   = (uint16_t*)alloc(1048576ULL * 2);   // absorbed_w_o^T (2048,512)
  uint16_t* cq_b   = (uint16_t*)alloc(4194304ULL * 2);   // (8192,512)
  uint16_t* catq   = (uint16_t*)alloc(20971520ULL * 2);  // (8192,2560) [aq|qr]
  uint16_t* catk   = (uint16_t*)alloc(20971520ULL * 2);  // (8192,2560) [ckv|kr]
  uint16_t* ckvT   = (uint16_t*)alloc(4194304ULL * 2);   // 4 x (512,2048)
  uint16_t* o_b    = (uint16_t*)alloc(4194304ULL * 2);   // (8192,512)
  float2*   rtab   = (float2*)alloc(131072ULL * 8);      // 2048x64 (cos,sin)
  float*    tmpS   = (float*)alloc(4194304ULL * 4);      // (8192,512) fp32
  float*    tmpB   = (float*)alloc(16777216ULL * 4);     // (8192,2048) fp32 (reused)
  uint16_t* attn   = catq;  // alias: catq dead after scores GEMM

  const dim3 b256(256);
  const dim3 tb(32, 8);

  // dtype converts
  cvt_k<<<dim3(16384), b256, 0, stream>>>(h, hb, 16777216L);
  cvt_k<<<dim3(1024),  b256, 0, stream>>>(wdq, wdq_b, 1048576L);
  cvt_k<<<dim3(1024),  b256, 0, stream>>>(wdkv, wdkv_b, 1048576L);
  cvt_k<<<dim3(1024),  b256, 0, stream>>>(wqr, wqr_b, 1048576L);
  cvt_k<<<dim3(4096),  b256, 0, stream>>>(wkr, wkr_b, 4194304L);
  cvt_k<<<dim3(4096),  b256, 0, stream>>>(wo, wo_b, 4194304L);
  // weight transposes (fp32 -> bf16)
  transpose_to_bf16<float><<<dim3(16, 64, 1), tb, 0, stream>>>(wuk, wukT, 512, 2048, 0, 0);
  transpose_to_bf16<float><<<dim3(16, 64, 1), tb, 0, stream>>>(wuq, wuqT, 512, 2048, 0, 0);
  transpose_to_bf16<float><<<dim3(16, 64, 1), tb, 0, stream>>>(wuv, wuvT, 512, 2048, 0, 0);
  transpose_to_bf16<float><<<dim3(64, 16, 1), tb, 0, stream>>>(wdq, wdqT, 2048, 512, 0, 0);
  rope_table<<<dim3(512), b256, 0, stream>>>(rtab);

  // absorbed weights
  // T1t(512,512): T1t[a][b] = sum_e wuk[e][a]*wuq[e][b]
  gemm_bt<1><<<dim3(4, 4, 1), b256, 0, stream>>>(wukT, wuqT, T1t, 2048, 2048, 2048, 512, 0, 0, 0);
  // Bqt(512,2048) = absorbed_w_q^T: Bqt[c][e] = sum_c' T1t[c][c'] * wdq[c'][e]
  gemm_bt<1><<<dim3(4, 16, 1), b256, 0, stream>>>(T1t, wdqT, Bqt, 512, 512, 512, 2048, 0, 0, 0);
  // awoT(2048,512) = (w_u_v^T w_o^T)^T = w_o @ w_u_v
  gemm_bt<1><<<dim3(16, 4, 1), b256, 0, stream>>>(wo_b, wuvT, awoT, 2048, 2048, 2048, 512, 0, 0, 0);

  // cq = rmsnorm(h @ wdq^T, g1)
  gemm_bt<0><<<dim3(64, 4, 1), b256, 0, stream>>>(hb, wdq_b, tmpS, 2048, 2048, 2048, 512, 0, 0, 0);
  rmsnorm_k<2><<<dim3(8192), b256, 0, stream>>>(tmpS, g1, nullptr, cq_b, 512);
  // qr = rope(cq @ wqr^T) -> catq[:,512:]
  gemm_bt<0><<<dim3(64, 16, 1), b256, 0, stream>>>(cq_b, wqr_b, tmpB, 512, 512, 512, 2048, 0, 0, 0);
  rope_k<false><<<dim3(32768), b256, 0, stream>>>(tmpB, catq, nullptr, rtab);
  // ckv = rmsnorm(h @ wdkv^T, g2) -> ckv_out (fp32) + catk[:,0:512] (bf16)
  gemm_bt<0><<<dim3(64, 4, 1), b256, 0, stream>>>(hb, wdkv_b, tmpS, 2048, 2048, 2048, 512, 0, 0, 0);
  rmsnorm_k<2><<<dim3(8192), b256, 0, stream>>>(tmpS, g2, ckv_out, catk, 2560);
  // ckvT: 4 x (512,2048) from catk cols 0..511
  transpose_to_bf16<uint16_t><<<dim3(16, 64, 4), tb, 0, stream>>>(
      catk, ckvT, 2560, 2048, 2048L * 2560, 512L * 2048);
  // kr = rope(h @ wkr^T) -> kr_out (fp32) + catk[:,512:]
  gemm_bt<0><<<dim3(64, 16, 1), b256, 0, stream>>>(hb, wkr_b, tmpB, 2048, 2048, 2048, 2048, 0, 0, 0);
  rope_k<true><<<dim3(32768), b256, 0, stream>>>(tmpB, catk, kr_out, rtab);
  // aq = h @ absorbed_w_q -> catq[:,0:512]
  gemm_bt<1><<<dim3(64, 4, 1), b256, 0, stream>>>(hb, Bqt, catq, 2048, 2048, 2048, 2560, 0, 0, 0);
  // scores[b] = catq_b @ catk_b^T (K=2560) -> tmpB fp32
  gemm_bt<0><<<dim3(16, 16, 4), b256, 0, stream>>>(
      catq, catk, tmpB, 2560, 2560, 2560, 2048, 5242880L, 5242880L, 4194304L);
  // softmax(scores/12) -> attn bf16 (aliases catq)
  softmax_k<<<dim3(8192), b256, 0, stream>>>(tmpB, attn);
  // o[b] = attn_b @ ckv_b  (via ckvT) -> o_b bf16
  gemm_bt<1><<<dim3(16, 4, 4), b256, 0, stream>>>(
      attn, ckvT, o_b, 2048, 2048, 2048, 512, 4194304L, 1048576L, 1048576L);
  // u = rmsnorm(o @ absorbed_w_o, g3) -> u_out
  gemm_bt<0><<<dim3(64, 16, 1), b256, 0, stream>>>(o_b, awoT, tmpB, 512, 512, 512, 2048, 0, 0, 0);
  rmsnorm_k<8><<<dim3(8192), b256, 0, stream>>>(tmpB, g3, u_out, nullptr, 0);
}

// Round 2
// 653.094 us; speedup vs baseline: 1.1032x; 1.1032x over previous
//
#include <hip/hip_runtime.h>
#include <stdint.h>

// ---------- small helpers ----------
typedef __attribute__((ext_vector_type(8))) short bf16x8;
typedef __attribute__((ext_vector_type(8))) unsigned short u16x8;
typedef __attribute__((ext_vector_type(4))) float floatx4;

__device__ __forceinline__ uint16_t f2bf(float f) {
  union { float f; uint32_t u; } v; v.f = f;
  uint32_t r = v.u + 0x7fffu + ((v.u >> 16) & 1u);
  return (uint16_t)(r >> 16);
}
__device__ __forceinline__ float bf2f(uint16_t b) {
  union { uint32_t u; float f; } v; v.u = ((uint32_t)b) << 16;
  return v.f;
}
__device__ __forceinline__ float ld_as_float(float v) { return v; }
__device__ __forceinline__ float ld_as_float(uint16_t v) { return bf2f(v); }

__device__ __forceinline__ void mfma16(floatx4& d, bf16x8 a, bf16x8 b) {
  asm("v_mfma_f32_16x16x32_bf16 %0, %1, %2, %0" : "+v"(d) : "v"(a), "v"(b));
}

#define FENCE() asm volatile("" ::: "memory")
#define SBAR()                                  \
  do {                                          \
    FENCE();                                    \
    __builtin_amdgcn_sched_barrier(0);          \
    __builtin_amdgcn_s_barrier();               \
    __builtin_amdgcn_sched_barrier(0);          \
    FENCE();                                    \
  } while (0)

// ================= deep-pipelined GEMM =================
// C(M,N) = A(M,K) @ B(N,K)^T, bf16 in, fp32 acc.
// BM=256, BN=128, BK=64. 512 threads = 8 waves (4 M x 2 N), per-wave 64x64 out.
// 3-deep LDS ring (A 32KB + B 16KB per buf = 144KB), global_load_lds staging
// 2 tiles ahead, counted vmcnt(6), XOR-swizzled LDS (row&7)<<4 on byte offset,
// per-phase barrier + setprio MFMA cluster, XCD-aware block swizzle.
// grid = (M/256, N/128, batches), block = 512.
template<int OUTB>  // 0: fp32 out, 1: bf16 out
__global__ void __launch_bounds__(512, 2) gemm256(
    const uint16_t* __restrict__ A, const uint16_t* __restrict__ B,
    void* __restrict__ Cv, int K, int lda, int ldb, int ldc,
    long sA, long sB, long sC)
{
  __shared__ __attribute__((aligned(16))) char lds[147456];  // 3 x (32768 A + 16384 B)
  const int tid = threadIdx.x;
  const int w = tid >> 6, l = tid & 63;
  const int wm = w >> 1, wn = w & 1;

  // XCD-aware swizzle over the (x,y) plane (all grids here have nwg % 8 == 0)
  const int gx = gridDim.x;
  const int nwg = gx * gridDim.y;
  int id = blockIdx.y * gx + blockIdx.x;
  if ((nwg & 7) == 0) id = (id & 7) * (nwg >> 3) + (id >> 3);
  const long bm = (long)(id % gx) * 256;
  const long bn = (long)(id / gx) * 128;
  A += (long)blockIdx.z * sA;
  B += (long)blockIdx.z * sB;

  // ---- staging geometry: each round = 64 rows x 128B, wave w owns 8 rows ----
  const int sr = l >> 3;                 // sub-row 0..7  (== row&7 of the staged row)
  const int sc = l & 7;                  // 16B chunk 0..7
  const int scol = ((sc ^ sr) << 3);     // pre-swizzled source col (elements)
  const uint16_t* gA = A + (bm + w * 8 + sr) * (long)lda + scol;
  const uint16_t* gB = B + (bn + w * 8 + sr) * (long)ldb + scol;
  const int ldsw = w * 1024;             // wave-uniform LDS chunk within a round

#define STAGE_A(bufi, k0, r)                                                     \
  __builtin_amdgcn_global_load_lds(gA + (k0) + (long)(r) * 64 * lda,             \
      (uint16_t*)(lds + (bufi) * 49152 + (r) * 8192 + ldsw), 16, 0, 0)
#define STAGE_B(bufi, k0, r)                                                     \
  __builtin_amdgcn_global_load_lds(gB + (k0) + (long)(r) * 64 * ldb,             \
      (uint16_t*)(lds + (bufi) * 49152 + 32768 + (r) * 8192 + ldsw), 16, 0, 0)

  // ---- fragment read geometry ----
  const int lr = l & 15;
  const int kk = (l >> 4) << 4;          // kbyte group 0,16,32,48
  const int msk = (l & 7) << 4;          // swizzle mask (row&7)<<4, row&7 == l&7
  const int ko0 = kk ^ msk;              // phase 0 k-offset (bytes, swizzled)
  const int ko1 = (64 + kk) ^ msk;       // phase 1
  const int arow = (wm * 64 + lr) * 128; // byte offset of A frag row
  const int brow = (wn * 64 + lr) * 128;

  floatx4 acc[4][4];
#pragma unroll
  for (int i = 0; i < 4; i++)
#pragma unroll
    for (int j = 0; j < 4; j++) acc[i][j] = (floatx4){0.f, 0.f, 0.f, 0.f};

  const int nt = K >> 6;
  // prologue: stage tiles 0 and 1
#pragma unroll
  for (int r = 0; r < 4; r++) STAGE_A(0, 0, r);
#pragma unroll
  for (int r = 0; r < 2; r++) STAGE_B(0, 0, r);
#pragma unroll
  for (int r = 0; r < 4; r++) STAGE_A(1, 64, r);
#pragma unroll
  for (int r = 0; r < 2; r++) STAGE_B(1, 64, r);
  asm volatile("s_waitcnt vmcnt(6)" ::: "memory");  // tile 0 landed; tile 1 in flight
  SBAR();

  for (int t = 0; t < nt; t++) {
    const int buf = t % 3;
    const int pbuf = (t + 2) % 3;
    const long pk0 = (long)(t + 2) << 6;
    const char* LA = lds + buf * 49152 + arow;
    const char* LB = lds + buf * 49152 + 32768 + brow;
    const bool pf = (t + 2 < nt);

    // ---- phase 0 (k elems 0..31) ----
    bf16x8 af[4], bfr[4];
#pragma unroll
    for (int i = 0; i < 4; i++) af[i] = *(const bf16x8*)(LA + i * 2048 + ko0);
#pragma unroll
    for (int j = 0; j < 4; j++) bfr[j] = *(const bf16x8*)(LB + j * 2048 + ko0);
    if (pf) { STAGE_A(pbuf, pk0, 0); STAGE_A(pbuf, pk0, 1); STAGE_B(pbuf, pk0, 0); }
    SBAR();
    __builtin_amdgcn_s_setprio(1);
#pragma unroll
    for (int i = 0; i < 4; i++)
#pragma unroll
      for (int j = 0; j < 4; j++) mfma16(acc[i][j], af[i], bfr[j]);
    __builtin_amdgcn_s_setprio(0);

    // ---- phase 1 (k elems 32..63) ----
#pragma unroll
    for (int i = 0; i < 4; i++) af[i] = *(const bf16x8*)(LA + i * 2048 + ko1);
#pragma unroll
    for (int j = 0; j < 4; j++) bfr[j] = *(const bf16x8*)(LB + j * 2048 + ko1);
    if (pf) { STAGE_A(pbuf, pk0, 2); STAGE_A(pbuf, pk0, 3); STAGE_B(pbuf, pk0, 1); }
    SBAR();
    __builtin_amdgcn_s_setprio(1);
#pragma unroll
    for (int i = 0; i < 4; i++)
#pragma unroll
      for (int j = 0; j < 4; j++) mfma16(acc[i][j], af[i], bfr[j]);
    __builtin_amdgcn_s_setprio(0);

    // tile-end: ensure next tile landed (counted — loads stay in flight)
    if (t < nt - 2) asm volatile("s_waitcnt vmcnt(6)" ::: "memory");
    else            asm volatile("s_waitcnt vmcnt(0)" ::: "memory");
    SBAR();
  }
#undef STAGE_A
#undef STAGE_B

  const long crow = bm + wm * 64 + ((l >> 4) * 4);
  const long ccol = bn + wn * 64 + (l & 15);
  if constexpr (OUTB == 0) {
    float* C = (float*)Cv + (long)blockIdx.z * sC;
#pragma unroll
    for (int i = 0; i < 4; i++)
#pragma unroll
      for (int r = 0; r < 4; r++) {
        long row = crow + i * 16 + r;
#pragma unroll
        for (int j = 0; j < 4; j++) C[row * (long)ldc + ccol + j * 16] = acc[i][j][r];
      }
  } else {
    uint16_t* C = (uint16_t*)Cv + (long)blockIdx.z * sC;
#pragma unroll
    for (int i = 0; i < 4; i++)
#pragma unroll
      for (int r = 0; r < 4; r++) {
        long row = crow + i * 16 + r;
#pragma unroll
        for (int j = 0; j < 4; j++) C[row * (long)ldc + ccol + j * 16] = f2bf(acc[i][j][r]);
      }
  }
}

// ================= legacy 128x128 GEMM (small weight-prep matmuls) =================
template<int OUTB>
__global__ void __launch_bounds__(256) gemm_bt(
    const uint16_t* __restrict__ A, const uint16_t* __restrict__ B,
    void* __restrict__ Cv, int K, int lda, int ldb, int ldc,
    long sA, long sB, long sC)
{
  __shared__ alignas(16) uint16_t As[4096];
  __shared__ alignas(16) uint16_t Bs[4096];
  const int tid = threadIdx.x;
  const int w = tid >> 6, l = tid & 63;
  const int wr = w >> 1, wc = w & 1;
  const long bm = (long)blockIdx.x * 128, bn = (long)blockIdx.y * 128;
  A += (long)blockIdx.z * sA;
  B += (long)blockIdx.z * sB;

  const uint16_t* ga0 = A + (bm + w * 16 + (l >> 2)) * (long)lda + (l & 3) * 8;
  const uint16_t* ga1 = ga0 + 64L * lda;
  const uint16_t* gb0 = B + (bn + w * 16 + (l >> 2)) * (long)ldb + (l & 3) * 8;
  const uint16_t* gb1 = gb0 + 64L * ldb;
  uint16_t* la0 = &As[w * 512];
  uint16_t* la1 = &As[2048 + w * 512];
  uint16_t* lb0 = &Bs[w * 512];
  uint16_t* lb1 = &Bs[2048 + w * 512];

  floatx4 acc[4][4];
#pragma unroll
  for (int i = 0; i < 4; i++)
#pragma unroll
    for (int j = 0; j < 4; j++) acc[i][j] = (floatx4){0.f, 0.f, 0.f, 0.f};

  const int rA = (wr * 64 + (l & 15)) * 32 + (l >> 4) * 8;
  const int rB = (wc * 64 + (l & 15)) * 32 + (l >> 4) * 8;

  for (int k0 = 0; k0 < K; k0 += 32) {
    __builtin_amdgcn_global_load_lds(ga0, la0, 16, 0, 0);
    __builtin_amdgcn_global_load_lds(ga1, la1, 16, 0, 0);
    __builtin_amdgcn_global_load_lds(gb0, lb0, 16, 0, 0);
    __builtin_amdgcn_global_load_lds(gb1, lb1, 16, 0, 0);
    ga0 += 32; ga1 += 32; gb0 += 32; gb1 += 32;
    __syncthreads();
    bf16x8 af[4], bfr[4];
#pragma unroll
    for (int i = 0; i < 4; i++) af[i] = *(const bf16x8*)&As[rA + i * 512];
#pragma unroll
    for (int j = 0; j < 4; j++) bfr[j] = *(const bf16x8*)&Bs[rB + j * 512];
#pragma unroll
    for (int i = 0; i < 4; i++)
#pragma unroll
      for (int j = 0; j < 4; j++) mfma16(acc[i][j], af[i], bfr[j]);
    __syncthreads();
  }

  const long crow = bm + wr * 64 + ((l >> 4) * 4);
  const long ccol = bn + wc * 64 + (l & 15);
  if constexpr (OUTB == 0) {
    float* C = (float*)Cv + (long)blockIdx.z * sC;
#pragma unroll
    for (int i = 0; i < 4; i++)
#pragma unroll
      for (int r = 0; r < 4; r++) {
        long row = crow + i * 16 + r;
#pragma unroll
        for (int j = 0; j < 4; j++) C[row * (long)ldc + ccol + j * 16] = acc[i][j][r];
      }
  } else {
    uint16_t* C = (uint16_t*)Cv + (long)blockIdx.z * sC;
#pragma unroll
    for (int i = 0; i < 4; i++)
#pragma unroll
      for (int r = 0; r < 4; r++) {
        long row = crow + i * 16 + r;
#pragma unroll
        for (int j = 0; j < 4; j++) C[row * (long)ldc + ccol + j * 16] = f2bf(acc[i][j][r]);
      }
  }
}

// ---------- fp32 -> bf16 convert ----------
__global__ void __launch_bounds__(256) cvt_k(const float* __restrict__ in,
                                             uint16_t* __restrict__ out, long n) {
  long i = ((long)blockIdx.x * 256 + threadIdx.x) * 4;
  if (i >= n) return;
  float4 v = *(const float4*)(in + i);
  ushort4 o; o.x = f2bf(v.x); o.y = f2bf(v.y); o.z = f2bf(v.z); o.w = f2bf(v.w);
  *(ushort4*)(out + i) = o;
}

// ---------- transpose (R,Cc) -> (Cc,R), bf16 out ----------
template<typename TIN>
__global__ void __launch_bounds__(256) transpose_to_bf16(
    const TIN* __restrict__ in, uint16_t* __restrict__ out,
    int ld_in, int ld_out, long sIn, long sOut)
{
  __shared__ float tile[32][33];
  in += (long)blockIdx.z * sIn;
  out += (long)blockIdx.z * sOut;
  const int rb = blockIdx.y * 32, cb = blockIdx.x * 32;
#pragma unroll
  for (int i = 0; i < 32; i += 8)
    tile[threadIdx.y + i][threadIdx.x] =
        ld_as_float(in[(long)(rb + threadIdx.y + i) * ld_in + cb + threadIdx.x]);
  __syncthreads();
#pragma unroll
  for (int i = 0; i < 32; i += 8)
    out[(long)(cb + threadIdx.y + i) * ld_out + rb + threadIdx.x] =
        f2bf(tile[threadIdx.x][threadIdx.y + i]);
}

// ---------- rmsnorm: one block per row; DIM = PT*256 ----------
template<int PT, typename TIN>
__global__ void __launch_bounds__(256) rmsnorm_k(
    const TIN* __restrict__ in, const float* __restrict__ g,
    float* __restrict__ out_f, uint16_t* __restrict__ out_b, int ld_b)
{
  constexpr int DIM = PT * 256;
  __shared__ float sm[9];
  const TIN* x = in + (long)blockIdx.x * DIM;
  const int base = threadIdx.x * PT;
  float v[PT];
  if constexpr (sizeof(TIN) == 2) {
#pragma unroll
    for (int i = 0; i < PT; i += 8) {
      u16x8 t = *(const u16x8*)&x[base + i];
#pragma unroll
      for (int q = 0; q < 8; q++) v[i + q] = bf2f(t[q]);
    }
  } else if constexpr (PT == 2) {
    float2 t = *(const float2*)&x[base]; v[0] = t.x; v[1] = t.y;
  } else {
#pragma unroll
    for (int i = 0; i < PT; i += 4) {
      float4 t = *(const float4*)&x[base + i];
      v[i] = t.x; v[i + 1] = t.y; v[i + 2] = t.z; v[i + 3] = t.w;
    }
  }
  float ss = 0.f;
#pragma unroll
  for (int i = 0; i < PT; i++) ss += v[i] * v[i];
#pragma unroll
  for (int o = 32; o; o >>= 1) ss += __shfl_down(ss, o);
  if ((threadIdx.x & 63) == 0) sm[threadIdx.x >> 6] = ss;
  __syncthreads();
  if (threadIdx.x == 0)
    sm[8] = rsqrtf((sm[0] + sm[1] + sm[2] + sm[3]) * (1.0f / DIM) + 1.1920929e-7f);
  __syncthreads();
  const float sc = sm[8];
#pragma unroll
  for (int i = 0; i < PT; i++) {
    float y = v[i] * sc * g[base + i];
    if (out_f) out_f[(long)blockIdx.x * DIM + base + i] = y;
    if (out_b) out_b[(long)blockIdx.x * ld_b + base + i] = f2bf(y);
  }
}

// ---------- rope table ----------
__global__ void __launch_bounds__(256) rope_table(float2* __restrict__ tab) {
  int idx = blockIdx.x * 256 + threadIdx.x;  // 2048*64
  int s = idx >> 6, fi = idx & 63;
  float f = powf(10000.0f, -(float)fi * (1.0f / 64.0f));
  float ang = (float)s * f;
  tab[idx] = make_float2(cosf(ang), sinf(ang));
}

// ---------- rope apply: in bf16 (8192,2048); bf16 out -> cat[:,512:]; optional fp32 out ----------
template<bool WF32>
__global__ void __launch_bounds__(256) rope_k(
    const uint16_t* __restrict__ in, uint16_t* __restrict__ outb,
    float* __restrict__ outf, const float2* __restrict__ tab)
{
  long idx = (long)blockIdx.x * 256 + threadIdx.x;  // 8192*1024 pairs
  int r = (int)(idx >> 10);
  int pp = (int)idx & 1023;
  int s = r & 2047;
  int fi = pp & 63;
  ushort2 xv = *(const ushort2*)(in + ((long)r << 11) + 2 * pp);
  float x0 = bf2f(xv.x), x1 = bf2f(xv.y);
  float2 cs = tab[(s << 6) + fi];
  float y0 = x0 * cs.x - x1 * cs.y;
  float y1 = x0 * cs.y + x1 * cs.x;
  ushort2 ov; ov.x = f2bf(y0); ov.y = f2bf(y1);
  *(ushort2*)(outb + (long)r * 2560 + 512 + 2 * pp) = ov;
  if (WF32) *(float2*)(outf + ((long)r << 11) + 2 * pp) = make_float2(y0, y1);
}

// ---------- softmax over rows of 2048, scale 1/12, fp32 in, bf16 out ----------
__global__ void __launch_bounds__(256) softmax_k(const float* __restrict__ sc,
                                                 uint16_t* __restrict__ attn) {
  __shared__ float sm[9];
  const float* x = sc + ((long)blockIdx.x << 11);
  const int base = threadIdx.x * 8;
  float v[8];
  *(float4*)&v[0] = *(const float4*)&x[base];
  *(float4*)&v[4] = *(const float4*)&x[base + 4];
  const float inv = 1.0f / 12.0f;
  float m = -1e30f;
#pragma unroll
  for (int i = 0; i < 8; i++) { v[i] *= inv; m = fmaxf(m, v[i]); }
#pragma unroll
  for (int o = 32; o; o >>= 1) m = fmaxf(m, __shfl_down(m, o));
  if ((threadIdx.x & 63) == 0) sm[threadIdx.x >> 6] = m;
  __syncthreads();
  if (threadIdx.x == 0)
    sm[8] = fmaxf(fmaxf(sm[0], sm[1]), fmaxf(sm[2], sm[3]));
  __syncthreads();
  m = sm[8];
  __syncthreads();
  float ss = 0.f;
#pragma unroll
  for (int i = 0; i < 8; i++) { v[i] = __expf(v[i] - m); ss += v[i]; }
#pragma unroll
  for (int o = 32; o; o >>= 1) ss += __shfl_down(ss, o);
  if ((threadIdx.x & 63) == 0) sm[threadIdx.x >> 6] = ss;
  __syncthreads();
  if (threadIdx.x == 0) sm[8] = 1.0f / (sm[0] + sm[1] + sm[2] + sm[3]);
  __syncthreads();
  const float r = sm[8];
  ushort4 o1, o2;
  o1.x = f2bf(v[0] * r); o1.y = f2bf(v[1] * r); o1.z = f2bf(v[2] * r); o1.w = f2bf(v[3] * r);
  o2.x = f2bf(v[4] * r); o2.y = f2bf(v[5] * r); o2.z = f2bf(v[6] * r); o2.w = f2bf(v[7] * r);
  uint16_t* dst = attn + ((long)blockIdx.x << 11) + base;
  *(ushort4*)dst = o1;
  *(ushort4*)(dst + 4) = o2;
}

// ---------- orchestration ----------
extern "C" void kernel_launch(void* const* d_in, const int* in_sizes, int n_in,
                              void* d_out, int out_size, void* d_ws, size_t ws_size,
                              hipStream_t stream) {
  (void)in_sizes; (void)n_in; (void)out_size; (void)ws_size;
  const float* h    = (const float*)d_in[0];
  const float* wdkv = (const float*)d_in[1];
  const float* wuk  = (const float*)d_in[2];
  const float* wuv  = (const float*)d_in[3];
  const float* wdq  = (const float*)d_in[4];
  const float* wuq  = (const float*)d_in[5];
  const float* wkr  = (const float*)d_in[6];
  const float* wqr  = (const float*)d_in[7];
  const float* wo   = (const float*)d_in[8];
  const float* g1   = (const float*)d_in[9];
  const float* g2   = (const float*)d_in[10];
  const float* g3   = (const float*)d_in[11];

  float* u_out   = (float*)d_out;                 // (4,2048,2048)
  float* ckv_out = u_out + 16777216L;             // (4,2048,512)
  float* kr_out  = ckv_out + 4194304L;            // (4,2048,2048)

  char* p = (char*)d_ws;
  auto alloc = [&](size_t bytes) -> void* {
    void* q = (void*)p; p += (bytes + 255) & ~(size_t)255; return q;
  };
  uint16_t* hb     = (uint16_t*)alloc(16777216ULL * 2);  // h bf16
  uint16_t* wdq_b  = (uint16_t*)alloc(1048576ULL * 2);
  uint16_t* wdkv_b = (uint16_t*)alloc(1048576ULL * 2);
  uint16_t* wqr_b  = (uint16_t*)alloc(1048576ULL * 2);
  uint16_t* wkr_b  = (uint16_t*)alloc(4194304ULL * 2);
  uint16_t* wo_b   = (uint16_t*)alloc(4194304ULL * 2);
  uint16_t* wukT   = (uint16_t*)alloc(1048576ULL * 2);   // (512,2048)
  uint16_t* wuqT   = (uint16_t*)alloc(1048576ULL * 2);
  uint16_t* wuvT   = (uint16_t*)alloc(1048576ULL * 2);
  uint16_t* wdqT   = (uint16_t*)alloc(1048576ULL * 2);   // (2048,512)
  uint16_t* T1t    = (uint16_t*)alloc(262144ULL * 2);    // (512,512)
  uint16_t* Bqt    = (uint16_t*)alloc(1048576ULL * 2);   // absorbed_w_q^T (512,2048)
  uint16_t* awoT   = (uint16_t*)alloc(1048576ULL * 2);   // absorbed_w_o^T (2048,512)
  uint16_t* cq_b   = (uint16_t*)alloc(4194304ULL * 2);   // (8192,512)
  uint16_t* catq   = (uint16_t*)alloc(20971520ULL * 2);  // (8192,2560) [aq|qr]
  uint16_t* catk   = (uint16_t*)alloc(20971520ULL * 2);  // (8192,2560) [ckv|kr]
  uint16_t* ckvT   = (uint16_t*)alloc(4194304ULL * 2);   // 4 x (512,2048)
  uint16_t* o_b    = (uint16_t*)alloc(4194304ULL * 2);   // (8192,512)
  float2*   rtab   = (float2*)alloc(131072ULL * 8);      // 2048x64 (cos,sin)
  float*    tmpS   = (float*)alloc(4194304ULL * 4);      // (8192,512) fp32
  float*    tmpB   = (float*)alloc(16777216ULL * 4);     // (8192,2048) fp32 scores
  uint16_t* tmpBb  = (uint16_t*)tmpB;                    // alias: (8192,2048) bf16
  uint16_t* attn   = catq;  // alias: catq dead after scores GEMM

  const dim3 b256(256);
  const dim3 b512(512);
  const dim3 tb(32, 8);

  // dtype converts
  cvt_k<<<dim3(16384), b256, 0, stream>>>(h, hb, 16777216L);
  cvt_k<<<dim3(1024),  b256, 0, stream>>>(wdq, wdq_b, 1048576L);
  cvt_k<<<dim3(1024),  b256, 0, stream>>>(wdkv, wdkv_b, 1048576L);
  cvt_k<<<dim3(1024),  b256, 0, stream>>>(wqr, wqr_b, 1048576L);
  cvt_k<<<dim3(4096),  b256, 0, stream>>>(wkr, wkr_b, 4194304L);
  cvt_k<<<dim3(4096),  b256, 0, stream>>>(wo, wo_b, 4194304L);
  // weight transposes (fp32 -> bf16)
  transpose_to_bf16<float><<<dim3(16, 64, 1), tb, 0, stream>>>(wuk, wukT, 512, 2048, 0, 0);
  transpose_to_bf16<float><<<dim3(16, 64, 1), tb, 0, stream>>>(wuq, wuqT, 512, 2048, 0, 0);
  transpose_to_bf16<float><<<dim3(16, 64, 1), tb, 0, stream>>>(wuv, wuvT, 512, 2048, 0, 0);
  transpose_to_bf16<float><<<dim3(64, 16, 1), tb, 0, stream>>>(wdq, wdqT, 2048, 512, 0, 0);
  rope_table<<<dim3(512), b256, 0, stream>>>(rtab);

  // absorbed weights (small — legacy kernel)
  gemm_bt<1><<<dim3(4, 4, 1), b256, 0, stream>>>(wukT, wuqT, T1t, 2048, 2048, 2048, 512, 0, 0, 0);
  gemm_bt<1><<<dim3(4, 16, 1), b256, 0, stream>>>(T1t, wdqT, Bqt, 512, 512, 512, 2048, 0, 0, 0);
  gemm_bt<1><<<dim3(16, 4, 1), b256, 0, stream>>>(wo_b, wuvT, awoT, 2048, 2048, 2048, 512, 0, 0, 0);

  // cq = rmsnorm(h @ wdq^T, g1)
  gemm256<0><<<dim3(32, 4, 1), b512, 0, stream>>>(hb, wdq_b, tmpS, 2048, 2048, 2048, 512, 0, 0, 0);
  rmsnorm_k<2, float><<<dim3(8192), b256, 0, stream>>>(tmpS, g1, nullptr, cq_b, 512);
  // qr = rope(cq @ wqr^T) -> catq[:,512:]
  gemm256<1><<<dim3(32, 16, 1), b512, 0, stream>>>(cq_b, wqr_b, tmpBb, 512, 512, 512, 2048, 0, 0, 0);
  rope_k<false><<<dim3(32768), b256, 0, stream>>>(tmpBb, catq, nullptr, rtab);
  // ckv = rmsnorm(h @ wdkv^T, g2) -> ckv_out (fp32) + catk[:,0:512] (bf16)
  gemm256<0><<<dim3(32, 4, 1), b512, 0, stream>>>(hb, wdkv_b, tmpS, 2048, 2048, 2048, 512, 0, 0, 0);
  rmsnorm_k<2, float><<<dim3(8192), b256, 0, stream>>>(tmpS, g2, ckv_out, catk, 2560);
  // ckvT: 4 x (512,2048) from catk cols 0..511
  transpose_to_bf16<uint16_t><<<dim3(16, 64, 4), tb, 0, stream>>>(
      catk, ckvT, 2560, 2048, 2048L * 2560, 512L * 2048);
  // kr = rope(h @ wkr^T) -> kr_out (fp32) + catk[:,512:]
  gemm256<1><<<dim3(32, 16, 1), b512, 0, stream>>>(hb, wkr_b, tmpBb, 2048, 2048, 2048, 2048, 0, 0, 0);
  rope_k<true><<<dim3(32768), b256, 0, stream>>>(tmpBb, catk, kr_out, rtab);
  // aq = h @ absorbed_w_q -> catq[:,0:512]
  gemm256<1><<<dim3(32, 4, 1), b512, 0, stream>>>(hb, Bqt, catq, 2048, 2048, 2048, 2560, 0, 0, 0);
  // scores[b] = catq_b @ catk_b^T (K=2560) -> tmpB fp32
  gemm256<0><<<dim3(8, 16, 4), b512, 0, stream>>>(
      catq, catk, tmpB, 2560, 2560, 2560, 2048, 5242880L, 5242880L, 4194304L);
  // softmax(scores/12) -> attn bf16 (aliases catq)
  softmax_k<<<dim3(8192), b256, 0, stream>>>(tmpB, attn);
  // o[b] = attn_b @ ckv_b (via ckvT) -> o_b bf16
  gemm256<1><<<dim3(8, 4, 4), b512, 0, stream>>>(
      attn, ckvT, o_b, 2048, 2048, 2048, 512, 4194304L, 1048576L, 1048576L);
  // u = rmsnorm(o @ absorbed_w_o, g3) -> u_out
  gemm256<1><<<dim3(32, 16, 1), b512, 0, stream>>>(o_b, awoT, tmpBb, 512, 512, 512, 2048, 0, 0, 0);
  rmsnorm_k<8, uint16_t><<<dim3(8192), b256, 0, stream>>>(tmpBb, g3, u_out, nullptr, 0);
}

// Round 3
// 643.465 us; speedup vs baseline: 1.1197x; 1.0150x over previous
//
#include <hip/hip_runtime.h>
#include <stdint.h>

// ---------- small helpers ----------
typedef __attribute__((ext_vector_type(8))) short bf16x8;
typedef __attribute__((ext_vector_type(8))) unsigned short u16x8;
typedef __attribute__((ext_vector_type(4))) float floatx4;

__device__ __forceinline__ uint16_t f2bf(float f) {
  union { float f; uint32_t u; } v; v.f = f;
  uint32_t r = v.u + 0x7fffu + ((v.u >> 16) & 1u);
  return (uint16_t)(r >> 16);
}
__device__ __forceinline__ float bf2f(uint16_t b) {
  union { uint32_t u; float f; } v; v.u = ((uint32_t)b) << 16;
  return v.f;
}
__device__ __forceinline__ float ld_as_float(float v) { return v; }
__device__ __forceinline__ float ld_as_float(uint16_t v) { return bf2f(v); }

__device__ __forceinline__ void mfma16(floatx4& d, bf16x8 a, bf16x8 b) {
  asm("v_mfma_f32_16x16x32_bf16 %0, %1, %2, %0" : "+v"(d) : "v"(a), "v"(b));
}

#define FENCE() asm volatile("" ::: "memory")
#define SCHED() __builtin_amdgcn_sched_barrier(0)
#define SBAR()                                  \
  do {                                          \
    FENCE();                                    \
    __builtin_amdgcn_sched_barrier(0);          \
    __builtin_amdgcn_s_barrier();               \
    __builtin_amdgcn_sched_barrier(0);          \
    FENCE();                                    \
  } while (0)

// ================= deep-pipelined GEMM =================
// C(M,N) = A(M,K) @ B(N,K)^T, bf16 in, fp32 acc.
// BM=256, BN=128, BK=64. 512 threads = 8 waves (4 M x 2 N), per-wave 64x64 out.
// 3-deep LDS ring, global_load_lds staging 2 tiles ahead, ONE barrier per
// K-tile (counted vmcnt(6) + lgkmcnt(0) drain), register-level fragment
// double-buffer so every MFMA cluster's LDS reads were issued a phase earlier,
// XOR-swizzled LDS, setprio around MFMA, XCD-aware block swizzle.
// grid = (M/256, N/128, batches), block = 512.
template<int OUTB>  // 0: fp32 out, 1: bf16 out
__global__ void __launch_bounds__(512, 2) gemm256(
    const uint16_t* __restrict__ A, const uint16_t* __restrict__ B,
    void* __restrict__ Cv, int K, int lda, int ldb, int ldc,
    long sA, long sB, long sC)
{
  __shared__ __attribute__((aligned(16))) char lds[147456];  // 3 x (32768 A + 16384 B)
  const int tid = threadIdx.x;
  const int w = tid >> 6, l = tid & 63;
  const int wm = w >> 1, wn = w & 1;

  // XCD-aware swizzle over the (x,y) plane (all grids here have nwg % 8 == 0)
  const int gx = gridDim.x;
  const int nwg = gx * gridDim.y;
  int id = blockIdx.y * gx + blockIdx.x;
  if ((nwg & 7) == 0) id = (id & 7) * (nwg >> 3) + (id >> 3);
  const long bm = (long)(id % gx) * 256;
  const long bn = (long)(id / gx) * 128;
  A += (long)blockIdx.z * sA;
  B += (long)blockIdx.z * sB;

  // ---- staging geometry: each round = 64 rows x 128B, wave w owns 8 rows ----
  const int sr = l >> 3;                 // sub-row 0..7  (== row&7 of the staged row)
  const int sc = l & 7;                  // 16B chunk 0..7
  const int scol = ((sc ^ sr) << 3);     // pre-swizzled source col (elements)
  const uint16_t* gA = A + (bm + w * 8 + sr) * (long)lda + scol;
  const uint16_t* gB = B + (bn + w * 8 + sr) * (long)ldb + scol;
  const int ldsw = w * 1024;             // wave-uniform LDS chunk within a round

#define STAGE_A(bufi, k0, r)                                                     \
  __builtin_amdgcn_global_load_lds(gA + (k0) + (long)(r) * 64 * lda,             \
      (uint16_t*)(lds + (bufi) * 49152 + (r) * 8192 + ldsw), 16, 0, 0)
#define STAGE_B(bufi, k0, r)                                                     \
  __builtin_amdgcn_global_load_lds(gB + (k0) + (long)(r) * 64 * ldb,             \
      (uint16_t*)(lds + (bufi) * 49152 + 32768 + (r) * 8192 + ldsw), 16, 0, 0)

  // ---- fragment read geometry ----
  const int lr = l & 15;
  const int kk = (l >> 4) << 4;          // kbyte group 0,16,32,48
  const int msk = (l & 7) << 4;          // swizzle mask (row&7)<<4, row&7 == l&7
  const int ko0 = kk ^ msk;              // phase 0 k-offset (bytes, swizzled)
  const int ko1 = (64 + kk) ^ msk;       // phase 1
  const int arow = (wm * 64 + lr) * 128; // byte offset of A frag row
  const int brow = (wn * 64 + lr) * 128;

  floatx4 acc[4][4];
#pragma unroll
  for (int i = 0; i < 4; i++)
#pragma unroll
    for (int j = 0; j < 4; j++) acc[i][j] = (floatx4){0.f, 0.f, 0.f, 0.f};

  const int nt = K >> 6;
  // prologue: stage tiles 0 and 1
#pragma unroll
  for (int r = 0; r < 4; r++) STAGE_A(0, 0, r);
#pragma unroll
  for (int r = 0; r < 2; r++) STAGE_B(0, 0, r);
#pragma unroll
  for (int r = 0; r < 4; r++) STAGE_A(1, 64, r);
#pragma unroll
  for (int r = 0; r < 2; r++) STAGE_B(1, 64, r);
  asm volatile("s_waitcnt vmcnt(6)" ::: "memory");  // tile 0 landed; tile 1 in flight
  SBAR();

  bf16x8 af0[4], bf0[4], af1[4], bf1[4];
  {
    const char* LA = lds + arow;
    const char* LB = lds + 32768 + brow;
#pragma unroll
    for (int i = 0; i < 4; i++) af0[i] = *(const bf16x8*)(LA + i * 2048 + ko0);
#pragma unroll
    for (int j = 0; j < 4; j++) bf0[j] = *(const bf16x8*)(LB + j * 2048 + ko0);
  }

  for (int t = 0; t < nt; t++) {
    const int buf = t % 3;
    const int pbuf = (t + 2) % 3;
    const long pk0 = (long)(t + 2) << 6;
    const char* LA = lds + buf * 49152 + arow;
    const char* LB = lds + buf * 49152 + 32768 + brow;
    const bool pf = (t + 2 < nt);

    // ---- phase 0: issue prefetch, read phase-1 frags, MFMA phase-0 frags ----
    if (pf) { STAGE_A(pbuf, pk0, 0); STAGE_A(pbuf, pk0, 1); STAGE_B(pbuf, pk0, 0); }
#pragma unroll
    for (int i = 0; i < 4; i++) af1[i] = *(const bf16x8*)(LA + i * 2048 + ko1);
#pragma unroll
    for (int j = 0; j < 4; j++) bf1[j] = *(const bf16x8*)(LB + j * 2048 + ko1);
    SCHED();
    __builtin_amdgcn_s_setprio(1);
#pragma unroll
    for (int i = 0; i < 4; i++)
#pragma unroll
      for (int j = 0; j < 4; j++) mfma16(acc[i][j], af0[i], bf0[j]);
    __builtin_amdgcn_s_setprio(0);
    SCHED();

    // ---- phase 1: issue prefetch, tile barrier, read next-tile frags, MFMA ----
    if (pf) { STAGE_A(pbuf, pk0, 2); STAGE_A(pbuf, pk0, 3); STAGE_B(pbuf, pk0, 1); }
    // drain LDS reads (buf[t] reads complete) + counted vmcnt (buf[t+1] landed)
    if (t < nt - 2) asm volatile("s_waitcnt vmcnt(6) lgkmcnt(0)" ::: "memory");
    else            asm volatile("s_waitcnt vmcnt(0) lgkmcnt(0)" ::: "memory");
    SBAR();
    if (t < nt - 1) {
      const char* LAn = lds + ((t + 1) % 3) * 49152 + arow;
      const char* LBn = lds + ((t + 1) % 3) * 49152 + 32768 + brow;
#pragma unroll
      for (int i = 0; i < 4; i++) af0[i] = *(const bf16x8*)(LAn + i * 2048 + ko0);
#pragma unroll
      for (int j = 0; j < 4; j++) bf0[j] = *(const bf16x8*)(LBn + j * 2048 + ko0);
    }
    SCHED();
    __builtin_amdgcn_s_setprio(1);
#pragma unroll
    for (int i = 0; i < 4; i++)
#pragma unroll
      for (int j = 0; j < 4; j++) mfma16(acc[i][j], af1[i], bf1[j]);
    __builtin_amdgcn_s_setprio(0);
    SCHED();
  }
#undef STAGE_A
#undef STAGE_B

  const long crow = bm + wm * 64 + ((l >> 4) * 4);
  const long ccol = bn + wn * 64 + (l & 15);
  if constexpr (OUTB == 0) {
    float* C = (float*)Cv + (long)blockIdx.z * sC;
#pragma unroll
    for (int i = 0; i < 4; i++)
#pragma unroll
      for (int r = 0; r < 4; r++) {
        long row = crow + i * 16 + r;
#pragma unroll
        for (int j = 0; j < 4; j++) C[row * (long)ldc + ccol + j * 16] = acc[i][j][r];
      }
  } else {
    uint16_t* C = (uint16_t*)Cv + (long)blockIdx.z * sC;
#pragma unroll
    for (int i = 0; i < 4; i++)
#pragma unroll
      for (int r = 0; r < 4; r++) {
        long row = crow + i * 16 + r;
#pragma unroll
        for (int j = 0; j < 4; j++) C[row * (long)ldc + ccol + j * 16] = f2bf(acc[i][j][r]);
      }
  }
}

// ================= legacy 128x128 GEMM (small weight-prep matmuls) =================
template<int OUTB>
__global__ void __launch_bounds__(256) gemm_bt(
    const uint16_t* __restrict__ A, const uint16_t* __restrict__ B,
    void* __restrict__ Cv, int K, int lda, int ldb, int ldc,
    long sA, long sB, long sC)
{
  __shared__ alignas(16) uint16_t As[4096];
  __shared__ alignas(16) uint16_t Bs[4096];
  const int tid = threadIdx.x;
  const int w = tid >> 6, l = tid & 63;
  const int wr = w >> 1, wc = w & 1;
  const long bm = (long)blockIdx.x * 128, bn = (long)blockIdx.y * 128;
  A += (long)blockIdx.z * sA;
  B += (long)blockIdx.z * sB;

  const uint16_t* ga0 = A + (bm + w * 16 + (l >> 2)) * (long)lda + (l & 3) * 8;
  const uint16_t* ga1 = ga0 + 64L * lda;
  const uint16_t* gb0 = B + (bn + w * 16 + (l >> 2)) * (long)ldb + (l & 3) * 8;
  const uint16_t* gb1 = gb0 + 64L * ldb;
  uint16_t* la0 = &As[w * 512];
  uint16_t* la1 = &As[2048 + w * 512];
  uint16_t* lb0 = &Bs[w * 512];
  uint16_t* lb1 = &Bs[2048 + w * 512];

  floatx4 acc[4][4];
#pragma unroll
  for (int i = 0; i < 4; i++)
#pragma unroll
    for (int j = 0; j < 4; j++) acc[i][j] = (floatx4){0.f, 0.f, 0.f, 0.f};

  const int rA = (wr * 64 + (l & 15)) * 32 + (l >> 4) * 8;
  const int rB = (wc * 64 + (l & 15)) * 32 + (l >> 4) * 8;

  for (int k0 = 0; k0 < K; k0 += 32) {
    __builtin_amdgcn_global_load_lds(ga0, la0, 16, 0, 0);
    __builtin_amdgcn_global_load_lds(ga1, la1, 16, 0, 0);
    __builtin_amdgcn_global_load_lds(gb0, lb0, 16, 0, 0);
    __builtin_amdgcn_global_load_lds(gb1, lb1, 16, 0, 0);
    ga0 += 32; ga1 += 32; gb0 += 32; gb1 += 32;
    __syncthreads();
    bf16x8 af[4], bfr[4];
#pragma unroll
    for (int i = 0; i < 4; i++) af[i] = *(const bf16x8*)&As[rA + i * 512];
#pragma unroll
    for (int j = 0; j < 4; j++) bfr[j] = *(const bf16x8*)&Bs[rB + j * 512];
#pragma unroll
    for (int i = 0; i < 4; i++)
#pragma unroll
      for (int j = 0; j < 4; j++) mfma16(acc[i][j], af[i], bfr[j]);
    __syncthreads();
  }

  const long crow = bm + wr * 64 + ((l >> 4) * 4);
  const long ccol = bn + wc * 64 + (l & 15);
  if constexpr (OUTB == 0) {
    float* C = (float*)Cv + (long)blockIdx.z * sC;
#pragma unroll
    for (int i = 0; i < 4; i++)
#pragma unroll
      for (int r = 0; r < 4; r++) {
        long row = crow + i * 16 + r;
#pragma unroll
        for (int j = 0; j < 4; j++) C[row * (long)ldc + ccol + j * 16] = acc[i][j][r];
      }
  } else {
    uint16_t* C = (uint16_t*)Cv + (long)blockIdx.z * sC;
#pragma unroll
    for (int i = 0; i < 4; i++)
#pragma unroll
      for (int r = 0; r < 4; r++) {
        long row = crow + i * 16 + r;
#pragma unroll
        for (int j = 0; j < 4; j++) C[row * (long)ldc + ccol + j * 16] = f2bf(acc[i][j][r]);
      }
  }
}

// ---------- fp32 -> bf16 convert ----------
__global__ void __launch_bounds__(256) cvt_k(const float* __restrict__ in,
                                             uint16_t* __restrict__ out, long n) {
  long i = ((long)blockIdx.x * 256 + threadIdx.x) * 4;
  if (i >= n) return;
  float4 v = *(const float4*)(in + i);
  ushort4 o; o.x = f2bf(v.x); o.y = f2bf(v.y); o.z = f2bf(v.z); o.w = f2bf(v.w);
  *(ushort4*)(out + i) = o;
}

// ---------- transpose (R,Cc) -> (Cc,R), bf16 out ----------
template<typename TIN>
__global__ void __launch_bounds__(256) transpose_to_bf16(
    const TIN* __restrict__ in, uint16_t* __restrict__ out,
    int ld_in, int ld_out, long sIn, long sOut)
{
  __shared__ float tile[32][33];
  in += (long)blockIdx.z * sIn;
  out += (long)blockIdx.z * sOut;
  const int rb = blockIdx.y * 32, cb = blockIdx.x * 32;
#pragma unroll
  for (int i = 0; i < 32; i += 8)
    tile[threadIdx.y + i][threadIdx.x] =
        ld_as_float(in[(long)(rb + threadIdx.y + i) * ld_in + cb + threadIdx.x]);
  __syncthreads();
#pragma unroll
  for (int i = 0; i < 32; i += 8)
    out[(long)(cb + threadIdx.y + i) * ld_out + rb + threadIdx.x] =
        f2bf(tile[threadIdx.x][threadIdx.y + i]);
}

// ---------- rmsnorm: one block per row; DIM = PT*256 ----------
template<int PT, typename TIN>
__global__ void __launch_bounds__(256) rmsnorm_k(
    const TIN* __restrict__ in, const float* __restrict__ g,
    float* __restrict__ out_f, uint16_t* __restrict__ out_b, int ld_b)
{
  constexpr int DIM = PT * 256;
  __shared__ float sm[9];
  const TIN* x = in + (long)blockIdx.x * DIM;
  const int base = threadIdx.x * PT;
  float v[PT];
  if constexpr (sizeof(TIN) == 2) {
#pragma unroll
    for (int i = 0; i < PT; i += 8) {
      u16x8 t = *(const u16x8*)&x[base + i];
#pragma unroll
      for (int q = 0; q < 8; q++) v[i + q] = bf2f(t[q]);
    }
  } else if constexpr (PT == 2) {
    float2 t = *(const float2*)&x[base]; v[0] = t.x; v[1] = t.y;
  } else {
#pragma unroll
    for (int i = 0; i < PT; i += 4) {
      float4 t = *(const float4*)&x[base + i];
      v[i] = t.x; v[i + 1] = t.y; v[i + 2] = t.z; v[i + 3] = t.w;
    }
  }
  float ss = 0.f;
#pragma unroll
  for (int i = 0; i < PT; i++) ss += v[i] * v[i];
#pragma unroll
  for (int o = 32; o; o >>= 1) ss += __shfl_down(ss, o);
  if ((threadIdx.x & 63) == 0) sm[threadIdx.x >> 6] = ss;
  __syncthreads();
  if (threadIdx.x == 0)
    sm[8] = rsqrtf((sm[0] + sm[1] + sm[2] + sm[3]) * (1.0f / DIM) + 1.1920929e-7f);
  __syncthreads();
  const float sc = sm[8];
#pragma unroll
  for (int i = 0; i < PT; i++) {
    float y = v[i] * sc * g[base + i];
    if (out_f) out_f[(long)blockIdx.x * DIM + base + i] = y;
    if (out_b) out_b[(long)blockIdx.x * ld_b + base + i] = f2bf(y);
  }
}

// ---------- rope table ----------
__global__ void __launch_bounds__(256) rope_table(float2* __restrict__ tab) {
  int idx = blockIdx.x * 256 + threadIdx.x;  // 2048*64
  int s = idx >> 6, fi = idx & 63;
  float f = powf(10000.0f, -(float)fi * (1.0f / 64.0f));
  float ang = (float)s * f;
  tab[idx] = make_float2(cosf(ang), sinf(ang));
}

// ---------- rope apply: in bf16 (8192,2048); bf16 out -> cat[:,512:]; optional fp32 out ----------
template<bool WF32>
__global__ void __launch_bounds__(256) rope_k(
    const uint16_t* __restrict__ in, uint16_t* __restrict__ outb,
    float* __restrict__ outf, const float2* __restrict__ tab)
{
  long idx = (long)blockIdx.x * 256 + threadIdx.x;  // 8192*1024 pairs
  int r = (int)(idx >> 10);
  int pp = (int)idx & 1023;
  int s = r & 2047;
  int fi = pp & 63;
  ushort2 xv = *(const ushort2*)(in + ((long)r << 11) + 2 * pp);
  float x0 = bf2f(xv.x), x1 = bf2f(xv.y);
  float2 cs = tab[(s << 6) + fi];
  float y0 = x0 * cs.x - x1 * cs.y;
  float y1 = x0 * cs.y + x1 * cs.x;
  ushort2 ov; ov.x = f2bf(y0); ov.y = f2bf(y1);
  *(ushort2*)(outb + (long)r * 2560 + 512 + 2 * pp) = ov;
  if (WF32) *(float2*)(outf + ((long)r << 11) + 2 * pp) = make_float2(y0, y1);
}

// ---------- softmax over rows of 2048, scale 1/12, fp32 in, bf16 out ----------
__global__ void __launch_bounds__(256) softmax_k(const float* __restrict__ sc,
                                                 uint16_t* __restrict__ attn) {
  __shared__ float sm[9];
  const float* x = sc + ((long)blockIdx.x << 11);
  const int base = threadIdx.x * 8;
  float v[8];
  *(float4*)&v[0] = *(const float4*)&x[base];
  *(float4*)&v[4] = *(const float4*)&x[base + 4];
  const float inv = 1.0f / 12.0f;
  float m = -1e30f;
#pragma unroll
  for (int i = 0; i < 8; i++) { v[i] *= inv; m = fmaxf(m, v[i]); }
#pragma unroll
  for (int o = 32; o; o >>= 1) m = fmaxf(m, __shfl_down(m, o));
  if ((threadIdx.x & 63) == 0) sm[threadIdx.x >> 6] = m;
  __syncthreads();
  if (threadIdx.x == 0)
    sm[8] = fmaxf(fmaxf(sm[0], sm[1]), fmaxf(sm[2], sm[3]));
  __syncthreads();
  m = sm[8];
  __syncthreads();
  float ss = 0.f;
#pragma unroll
  for (int i = 0; i < 8; i++) { v[i] = __expf(v[i] - m); ss += v[i]; }
#pragma unroll
  for (int o = 32; o; o >>= 1) ss += __shfl_down(ss, o);
  if ((threadIdx.x & 63) == 0) sm[threadIdx.x >> 6] = ss;
  __syncthreads();
  if (threadIdx.x == 0) sm[8] = 1.0f / (sm[0] + sm[1] + sm[2] + sm[3]);
  __syncthreads();
  const float r = sm[8];
  ushort4 o1, o2;
  o1.x = f2bf(v[0] * r); o1.y = f2bf(v[1] * r); o1.z = f2bf(v[2] * r); o1.w = f2bf(v[3] * r);
  o2.x = f2bf(v[4] * r); o2.y = f2bf(v[5] * r); o2.z = f2bf(v[6] * r); o2.w = f2bf(v[7] * r);
  uint16_t* dst = attn + ((long)blockIdx.x << 11) + base;
  *(ushort4*)dst = o1;
  *(ushort4*)(dst + 4) = o2;
}

// ---------- orchestration ----------
extern "C" void kernel_launch(void* const* d_in, const int* in_sizes, int n_in,
                              void* d_out, int out_size, void* d_ws, size_t ws_size,
                              hipStream_t stream) {
  (void)in_sizes; (void)n_in; (void)out_size; (void)ws_size;
  const float* h    = (const float*)d_in[0];
  const float* wdkv = (const float*)d_in[1];
  const float* wuk  = (const float*)d_in[2];
  const float* wuv  = (const float*)d_in[3];
  const float* wdq  = (const float*)d_in[4];
  const float* wuq  = (const float*)d_in[5];
  const float* wkr  = (const float*)d_in[6];
  const float* wqr  = (const float*)d_in[7];
  const float* wo   = (const float*)d_in[8];
  const float* g1   = (const float*)d_in[9];
  const float* g2   = (const float*)d_in[10];
  const float* g3   = (const float*)d_in[11];

  float* u_out   = (float*)d_out;                 // (4,2048,2048)
  float* ckv_out = u_out + 16777216L;             // (4,2048,512)
  float* kr_out  = ckv_out + 4194304L;            // (4,2048,2048)

  char* p = (char*)d_ws;
  auto alloc = [&](size_t bytes) -> void* {
    void* q = (void*)p; p += (bytes + 255) & ~(size_t)255; return q;
  };
  uint16_t* hb     = (uint16_t*)alloc(16777216ULL * 2);  // h bf16
  uint16_t* wdq_b  = (uint16_t*)alloc(1048576ULL * 2);
  uint16_t* wdkv_b = (uint16_t*)alloc(1048576ULL * 2);
  uint16_t* wqr_b  = (uint16_t*)alloc(1048576ULL * 2);
  uint16_t* wkr_b  = (uint16_t*)alloc(4194304ULL * 2);
  uint16_t* wo_b   = (uint16_t*)alloc(4194304ULL * 2);
  uint16_t* wukT   = (uint16_t*)alloc(1048576ULL * 2);   // (512,2048)
  uint16_t* wuqT   = (uint16_t*)alloc(1048576ULL * 2);
  uint16_t* wuvT   = (uint16_t*)alloc(1048576ULL * 2);
  uint16_t* wdqT   = (uint16_t*)alloc(1048576ULL * 2);   // (2048,512)
  uint16_t* T1t    = (uint16_t*)alloc(262144ULL * 2);    // (512,512)
  uint16_t* Bqt    = (uint16_t*)alloc(1048576ULL * 2);   // absorbed_w_q^T (512,2048)
  uint16_t* awoT   = (uint16_t*)alloc(1048576ULL * 2);   // absorbed_w_o^T (2048,512)
  uint16_t* cq_b   = (uint16_t*)alloc(4194304ULL * 2);   // (8192,512)
  uint16_t* catq   = (uint16_t*)alloc(20971520ULL * 2);  // (8192,2560) [aq|qr]
  uint16_t* catk   = (uint16_t*)alloc(20971520ULL * 2);  // (8192,2560) [ckv|kr]
  uint16_t* ckvT   = (uint16_t*)alloc(4194304ULL * 2);   // 4 x (512,2048)
  uint16_t* o_b    = (uint16_t*)alloc(4194304ULL * 2);   // (8192,512)
  float2*   rtab   = (float2*)alloc(131072ULL * 8);      // 2048x64 (cos,sin)
  float*    tmpS   = (float*)alloc(4194304ULL * 4);      // (8192,512) fp32
  float*    tmpB   = (float*)alloc(16777216ULL * 4);     // (8192,2048) fp32 scores
  uint16_t* tmpBb  = (uint16_t*)tmpB;                    // alias: (8192,2048) bf16
  uint16_t* attn   = catq;  // alias: catq dead after scores GEMM

  const dim3 b256(256);
  const dim3 b512(512);
  const dim3 tb(32, 8);

  // dtype converts
  cvt_k<<<dim3(16384), b256, 0, stream>>>(h, hb, 16777216L);
  cvt_k<<<dim3(1024),  b256, 0, stream>>>(wdq, wdq_b, 1048576L);
  cvt_k<<<dim3(1024),  b256, 0, stream>>>(wdkv, wdkv_b, 1048576L);
  cvt_k<<<dim3(1024),  b256, 0, stream>>>(wqr, wqr_b, 1048576L);
  cvt_k<<<dim3(4096),  b256, 0, stream>>>(wkr, wkr_b, 4194304L);
  cvt_k<<<dim3(4096),  b256, 0, stream>>>(wo, wo_b, 4194304L);
  // weight transposes (fp32 -> bf16)
  transpose_to_bf16<float><<<dim3(16, 64, 1), tb, 0, stream>>>(wuk, wukT, 512, 2048, 0, 0);
  transpose_to_bf16<float><<<dim3(16, 64, 1), tb, 0, stream>>>(wuq, wuqT, 512, 2048, 0, 0);
  transpose_to_bf16<float><<<dim3(16, 64, 1), tb, 0, stream>>>(wuv, wuvT, 512, 2048, 0, 0);
  transpose_to_bf16<float><<<dim3(64, 16, 1), tb, 0, stream>>>(wdq, wdqT, 2048, 512, 0, 0);
  rope_table<<<dim3(512), b256, 0, stream>>>(rtab);

  // absorbed weights (small — legacy kernel)
  gemm_bt<1><<<dim3(4, 4, 1), b256, 0, stream>>>(wukT, wuqT, T1t, 2048, 2048, 2048, 512, 0, 0, 0);
  gemm_bt<1><<<dim3(4, 16, 1), b256, 0, stream>>>(T1t, wdqT, Bqt, 512, 512, 512, 2048, 0, 0, 0);
  gemm_bt<1><<<dim3(16, 4, 1), b256, 0, stream>>>(wo_b, wuvT, awoT, 2048, 2048, 2048, 512, 0, 0, 0);

  // cq = rmsnorm(h @ wdq^T, g1)
  gemm256<0><<<dim3(32, 4, 1), b512, 0, stream>>>(hb, wdq_b, tmpS, 2048, 2048, 2048, 512, 0, 0, 0);
  rmsnorm_k<2, float><<<dim3(8192), b256, 0, stream>>>(tmpS, g1, nullptr, cq_b, 512);
  // qr = rope(cq @ wqr^T) -> catq[:,512:]
  gemm256<1><<<dim3(32, 16, 1), b512, 0, stream>>>(cq_b, wqr_b, tmpBb, 512, 512, 512, 2048, 0, 0, 0);
  rope_k<false><<<dim3(32768), b256, 0, stream>>>(tmpBb, catq, nullptr, rtab);
  // ckv = rmsnorm(h @ wdkv^T, g2) -> ckv_out (fp32) + catk[:,0:512] (bf16)
  gemm256<0><<<dim3(32, 4, 1), b512, 0, stream>>>(hb, wdkv_b, tmpS, 2048, 2048, 2048, 512, 0, 0, 0);
  rmsnorm_k<2, float><<<dim3(8192), b256, 0, stream>>>(tmpS, g2, ckv_out, catk, 2560);
  // ckvT: 4 x (512,2048) from catk cols 0..511
  transpose_to_bf16<uint16_t><<<dim3(16, 64, 4), tb, 0, stream>>>(
      catk, ckvT, 2560, 2048, 2048L * 2560, 512L * 2048);
  // kr = rope(h @ wkr^T) -> kr_out (fp32) + catk[:,512:]
  gemm256<1><<<dim3(32, 16, 1), b512, 0, stream>>>(hb, wkr_b, tmpBb, 2048, 2048, 2048, 2048, 0, 0, 0);
  rope_k<true><<<dim3(32768), b256, 0, stream>>>(tmpBb, catk, kr_out, rtab);
  // aq = h @ absorbed_w_q -> catq[:,0:512]
  gemm256<1><<<dim3(32, 4, 1), b512, 0, stream>>>(hb, Bqt, catq, 2048, 2048, 2048, 2560, 0, 0, 0);
  // scores[b] = catq_b @ catk_b^T (K=2560) -> tmpB fp32
  gemm256<0><<<dim3(8, 16, 4), b512, 0, stream>>>(
      catq, catk, tmpB, 2560, 2560, 2560, 2048, 5242880L, 5242880L, 4194304L);
  // softmax(scores/12) -> attn bf16 (aliases catq)
  softmax_k<<<dim3(8192), b256, 0, stream>>>(tmpB, attn);
  // o[b] = attn_b @ ckv_b (via ckvT) -> o_b bf16
  gemm256<1><<<dim3(8, 4, 4), b512, 0, stream>>>(
      attn, ckvT, o_b, 2048, 2048, 2048, 512, 4194304L, 1048576L, 1048576L);
  // u = rmsnorm(o @ absorbed_w_o, g3) -> u_out
  gemm256<1><<<dim3(32, 16, 1), b512, 0, stream>>>(o_b, awoT, tmpBb, 512, 512, 512, 2048, 0, 0, 0);
  rmsnorm_k<8, uint16_t><<<dim3(8192), b256, 0, stream>>>(tmpBb, g3, u_out, nullptr, 0);
}

// Round 4
// 578.879 us; speedup vs baseline: 1.2446x; 1.1116x over previous
//
#include <hip/hip_runtime.h>
#include <stdint.h>

// ---------- small helpers ----------
typedef __attribute__((ext_vector_type(8))) short bf16x8;
typedef __attribute__((ext_vector_type(8))) unsigned short u16x8;
typedef __attribute__((ext_vector_type(4))) float floatx4;

__device__ __forceinline__ uint16_t f2bf(float f) {
  union { float f; uint32_t u; } v; v.f = f;
  uint32_t r = v.u + 0x7fffu + ((v.u >> 16) & 1u);
  return (uint16_t)(r >> 16);
}
__device__ __forceinline__ float bf2f(uint16_t b) {
  union { uint32_t u; float f; } v; v.u = ((uint32_t)b) << 16;
  return v.f;
}
__device__ __forceinline__ float ld_as_float(float v) { return v; }
__device__ __forceinline__ float ld_as_float(uint16_t v) { return bf2f(v); }

__device__ __forceinline__ void mfma16(floatx4& d, bf16x8 a, bf16x8 b) {
  asm("v_mfma_f32_16x16x32_bf16 %0, %1, %2, %0" : "+v"(d) : "v"(a), "v"(b));
}

#define FENCE() asm volatile("" ::: "memory")
#define SCHED() __builtin_amdgcn_sched_barrier(0)
#define SBAR()                                  \
  do {                                          \
    FENCE();                                    \
    __builtin_amdgcn_sched_barrier(0);          \
    __builtin_amdgcn_s_barrier();               \
    __builtin_amdgcn_sched_barrier(0);          \
    FENCE();                                    \
  } while (0)

// ================= m201-geometry GEMM: 256x256, BK=64 =================
// C(M,N) = A(M,K) @ B(N,K)^T, bf16 in, fp32 acc.
// 512 threads = 8 waves (2M x 4N), per-wave 128x64 output (8x4 frags).
// LDS: 2 buffers x (A 32KB + B 32KB) = 128 KB. 4 phases per K-tile:
//   p0: stage 4 A-rounds(t+1) | ds_read B all (8) + A rows0-1 (4) | bar |
//       lgkmcnt0 | prio1 16 MFMA prio0 | bar
//   p1: stage 4 B-rounds(t+1) | ds_read A rows2-3 | ... 16 MFMA | bar
//   p2: ds_read A rows4-5 | ... | bar
//   p3: ds_read A rows6-7 | vmcnt(0) | bar | ... | bar  -> flip buffers
// XOR-swizzled LDS ((row&7)<<4 on byte offset) via pre-swizzled global src.
// MODE 0: fp32 out; 1: bf16 out; 2: routed (cols 0-511 fp32 C0 ld512,
//         512-1023 fp32 C1 ld512, 1024-1535 bf16 C2 ld2560).
template<int MODE>
__global__ void __launch_bounds__(512, 1) gemm256sq(
    const uint16_t* __restrict__ A, const uint16_t* __restrict__ B,
    void* __restrict__ C0v, void* __restrict__ C1v, void* __restrict__ C2v,
    int K, int lda, int ldb, int ldc,
    long sA, long sB, long sC)
{
  __shared__ __attribute__((aligned(16))) char lds[131072];
  const int tid = threadIdx.x;
  const int w = tid >> 6, l = tid & 63;
  const int wm = w >> 2, wn = w & 3;

  // XCD-aware swizzle over the (x,y) plane (all grids here have nwg % 8 == 0)
  const int gx = gridDim.x;
  const int nwg = gx * gridDim.y;
  int id = blockIdx.y * gx + blockIdx.x;
  if ((nwg & 7) == 0) id = (id & 7) * (nwg >> 3) + (id >> 3);
  const long bm = (long)(id % gx) * 256;
  const long bn = (long)(id / gx) * 256;
  A += (long)blockIdx.z * sA;
  B += (long)blockIdx.z * sB;

  // ---- staging: round = 64 rows x 128B; wave w owns 8 rows per round ----
  const int sr = l >> 3;               // sub-row within wave's 8 rows
  const int sc = l & 7;                // 16B chunk
  const int scol = ((sc ^ sr) << 3);   // pre-swizzled source col (elements)
  const uint16_t* gA = A + (bm + w * 8 + sr) * (long)lda + scol;
  const uint16_t* gB = B + (bn + w * 8 + sr) * (long)ldb + scol;
  const int ldsw = w * 1024;

#define STG_A(bufi, k0, r)                                                     \
  __builtin_amdgcn_global_load_lds(gA + (k0) + (long)(r) * 64 * lda,           \
      (uint16_t*)(lds + (bufi) * 65536 + (r) * 8192 + ldsw), 16, 0, 0)
#define STG_B(bufi, k0, r)                                                     \
  __builtin_amdgcn_global_load_lds(gB + (k0) + (long)(r) * 64 * ldb,           \
      (uint16_t*)(lds + (bufi) * 65536 + 32768 + (r) * 8192 + ldsw), 16, 0, 0)

  // ---- fragment read geometry ----
  const int kk = (l >> 4) << 4;
  const int msk = (l & 7) << 4;
  const int ko0 = kk ^ msk;
  const int ko1 = (64 + kk) ^ msk;
  const int aoff = (wm * 128 + (l & 15)) * 128;
  const int boff = 32768 + (wn * 64 + (l & 15)) * 128;

  floatx4 acc[8][4];
#pragma unroll
  for (int i = 0; i < 8; i++)
#pragma unroll
    for (int j = 0; j < 4; j++) acc[i][j] = (floatx4){0.f, 0.f, 0.f, 0.f};

  const int nt = K >> 6;
  // prologue: stage tile 0 into buf0
#pragma unroll
  for (int r = 0; r < 4; r++) STG_A(0, 0, r);
#pragma unroll
  for (int r = 0; r < 4; r++) STG_B(0, 0, r);
  asm volatile("s_waitcnt vmcnt(0)" ::: "memory");
  SBAR();

  bf16x8 Bf[4][2];
  for (int t = 0; t < nt; t++) {
    const int buf = t & 1;
    const char* Lb = lds + buf * 65536;
    const long nk0 = (long)(t + 1) << 6;
    const bool pf = (t + 1 < nt);
    bf16x8 Af[2][2];

    // ---------------- phase 0 ----------------
    if (pf) { STG_A(buf ^ 1, nk0, 0); STG_A(buf ^ 1, nk0, 1);
              STG_A(buf ^ 1, nk0, 2); STG_A(buf ^ 1, nk0, 3); }
#pragma unroll
    for (int j = 0; j < 4; j++) {
      Bf[j][0] = *(const bf16x8*)(Lb + boff + j * 2048 + ko0);
      Bf[j][1] = *(const bf16x8*)(Lb + boff + j * 2048 + ko1);
    }
#pragma unroll
    for (int ii = 0; ii < 2; ii++) {
      Af[ii][0] = *(const bf16x8*)(Lb + aoff + ii * 2048 + ko0);
      Af[ii][1] = *(const bf16x8*)(Lb + aoff + ii * 2048 + ko1);
    }
    SBAR();
    asm volatile("s_waitcnt lgkmcnt(0)" ::: "memory");
    SCHED();
    __builtin_amdgcn_s_setprio(1);
#pragma unroll
    for (int ii = 0; ii < 2; ii++)
#pragma unroll
      for (int j = 0; j < 4; j++) {
        mfma16(acc[ii][j], Af[ii][0], Bf[j][0]);
        mfma16(acc[ii][j], Af[ii][1], Bf[j][1]);
      }
    __builtin_amdgcn_s_setprio(0);
    SBAR();

    // ---------------- phase 1 ----------------
    if (pf) { STG_B(buf ^ 1, nk0, 0); STG_B(buf ^ 1, nk0, 1);
              STG_B(buf ^ 1, nk0, 2); STG_B(buf ^ 1, nk0, 3); }
#pragma unroll
    for (int ii = 0; ii < 2; ii++) {
      Af[ii][0] = *(const bf16x8*)(Lb + aoff + (2 + ii) * 2048 + ko0);
      Af[ii][1] = *(const bf16x8*)(Lb + aoff + (2 + ii) * 2048 + ko1);
    }
    SBAR();
    asm volatile("s_waitcnt lgkmcnt(0)" ::: "memory");
    SCHED();
    __builtin_amdgcn_s_setprio(1);
#pragma unroll
    for (int ii = 0; ii < 2; ii++)
#pragma unroll
      for (int j = 0; j < 4; j++) {
        mfma16(acc[2 + ii][j], Af[ii][0], Bf[j][0]);
        mfma16(acc[2 + ii][j], Af[ii][1], Bf[j][1]);
      }
    __builtin_amdgcn_s_setprio(0);
    SBAR();

    // ---------------- phase 2 ----------------
#pragma unroll
    for (int ii = 0; ii < 2; ii++) {
      Af[ii][0] = *(const bf16x8*)(Lb + aoff + (4 + ii) * 2048 + ko0);
      Af[ii][1] = *(const bf16x8*)(Lb + aoff + (4 + ii) * 2048 + ko1);
    }
    SBAR();
    asm volatile("s_waitcnt lgkmcnt(0)" ::: "memory");
    SCHED();
    __builtin_amdgcn_s_setprio(1);
#pragma unroll
    for (int ii = 0; ii < 2; ii++)
#pragma unroll
      for (int j = 0; j < 4; j++) {
        mfma16(acc[4 + ii][j], Af[ii][0], Bf[j][0]);
        mfma16(acc[4 + ii][j], Af[ii][1], Bf[j][1]);
      }
    __builtin_amdgcn_s_setprio(0);
    SBAR();

    // ---------------- phase 3 ----------------
#pragma unroll
    for (int ii = 0; ii < 2; ii++) {
      Af[ii][0] = *(const bf16x8*)(Lb + aoff + (6 + ii) * 2048 + ko0);
      Af[ii][1] = *(const bf16x8*)(Lb + aoff + (6 + ii) * 2048 + ko1);
    }
    asm volatile("s_waitcnt vmcnt(0)" ::: "memory");  // t+1 staging landed
    SBAR();
    asm volatile("s_waitcnt lgkmcnt(0)" ::: "memory");
    SCHED();
    __builtin_amdgcn_s_setprio(1);
#pragma unroll
    for (int ii = 0; ii < 2; ii++)
#pragma unroll
      for (int j = 0; j < 4; j++) {
        mfma16(acc[6 + ii][j], Af[ii][0], Bf[j][0]);
        mfma16(acc[6 + ii][j], Af[ii][1], Bf[j][1]);
      }
    __builtin_amdgcn_s_setprio(0);
    SBAR();
  }
#undef STG_A
#undef STG_B

  const long crow = bm + wm * 128 + ((l >> 4) * 4);
  const long ccol = bn + wn * 64 + (l & 15);
  if constexpr (MODE == 0) {
    float* C = (float*)C0v + (long)blockIdx.z * sC;
#pragma unroll
    for (int i = 0; i < 8; i++)
#pragma unroll
      for (int r = 0; r < 4; r++) {
        long row = crow + i * 16 + r;
#pragma unroll
        for (int j = 0; j < 4; j++) C[row * (long)ldc + ccol + j * 16] = acc[i][j][r];
      }
  } else if constexpr (MODE == 1) {
    uint16_t* C = (uint16_t*)C0v + (long)blockIdx.z * sC;
#pragma unroll
    for (int i = 0; i < 8; i++)
#pragma unroll
      for (int r = 0; r < 4; r++) {
        long row = crow + i * 16 + r;
#pragma unroll
        for (int j = 0; j < 4; j++) C[row * (long)ldc + ccol + j * 16] = f2bf(acc[i][j][r]);
      }
  } else {
    if (bn < 1024) {
      float* C = (bn < 512) ? (float*)C0v : (float*)C1v;
      const long cc = ccol - ((bn < 512) ? 0 : 512);
#pragma unroll
      for (int i = 0; i < 8; i++)
#pragma unroll
        for (int r = 0; r < 4; r++) {
          long row = crow + i * 16 + r;
#pragma unroll
          for (int j = 0; j < 4; j++) C[row * 512 + cc + j * 16] = acc[i][j][r];
        }
    } else {
      uint16_t* C = (uint16_t*)C2v;
      const long cc = ccol - 1024;
#pragma unroll
      for (int i = 0; i < 8; i++)
#pragma unroll
        for (int r = 0; r < 4; r++) {
          long row = crow + i * 16 + r;
#pragma unroll
          for (int j = 0; j < 4; j++) C[row * 2560 + cc + j * 16] = f2bf(acc[i][j][r]);
        }
    }
  }
}

// ================= 256x128 pipelined GEMM (for the small-N o GEMM) =================
template<int OUTB>
__global__ void __launch_bounds__(512, 2) gemm256(
    const uint16_t* __restrict__ A, const uint16_t* __restrict__ B,
    void* __restrict__ Cv, int K, int lda, int ldb, int ldc,
    long sA, long sB, long sC)
{
  __shared__ __attribute__((aligned(16))) char lds[147456];
  const int tid = threadIdx.x;
  const int w = tid >> 6, l = tid & 63;
  const int wm = w >> 1, wn = w & 1;

  const int gx = gridDim.x;
  const int nwg = gx * gridDim.y;
  int id = blockIdx.y * gx + blockIdx.x;
  if ((nwg & 7) == 0) id = (id & 7) * (nwg >> 3) + (id >> 3);
  const long bm = (long)(id % gx) * 256;
  const long bn = (long)(id / gx) * 128;
  A += (long)blockIdx.z * sA;
  B += (long)blockIdx.z * sB;

  const int sr = l >> 3;
  const int sc = l & 7;
  const int scol = ((sc ^ sr) << 3);
  const uint16_t* gA = A + (bm + w * 8 + sr) * (long)lda + scol;
  const uint16_t* gB = B + (bn + w * 8 + sr) * (long)ldb + scol;
  const int ldsw = w * 1024;

#define STAGE_A(bufi, k0, r)                                                     \
  __builtin_amdgcn_global_load_lds(gA + (k0) + (long)(r) * 64 * lda,             \
      (uint16_t*)(lds + (bufi) * 49152 + (r) * 8192 + ldsw), 16, 0, 0)
#define STAGE_B(bufi, k0, r)                                                     \
  __builtin_amdgcn_global_load_lds(gB + (k0) + (long)(r) * 64 * ldb,             \
      (uint16_t*)(lds + (bufi) * 49152 + 32768 + (r) * 8192 + ldsw), 16, 0, 0)

  const int lr = l & 15;
  const int kk = (l >> 4) << 4;
  const int msk = (l & 7) << 4;
  const int ko0 = kk ^ msk;
  const int ko1 = (64 + kk) ^ msk;
  const int arow = (wm * 64 + lr) * 128;
  const int brow = (wn * 64 + lr) * 128;

  floatx4 acc[4][4];
#pragma unroll
  for (int i = 0; i < 4; i++)
#pragma unroll
    for (int j = 0; j < 4; j++) acc[i][j] = (floatx4){0.f, 0.f, 0.f, 0.f};

  const int nt = K >> 6;
#pragma unroll
  for (int r = 0; r < 4; r++) STAGE_A(0, 0, r);
#pragma unroll
  for (int r = 0; r < 2; r++) STAGE_B(0, 0, r);
#pragma unroll
  for (int r = 0; r < 4; r++) STAGE_A(1, 64, r);
#pragma unroll
  for (int r = 0; r < 2; r++) STAGE_B(1, 64, r);
  asm volatile("s_waitcnt vmcnt(6)" ::: "memory");
  SBAR();

  bf16x8 af0[4], bf0[4], af1[4], bf1[4];
  {
    const char* LA = lds + arow;
    const char* LB = lds + 32768 + brow;
#pragma unroll
    for (int i = 0; i < 4; i++) af0[i] = *(const bf16x8*)(LA + i * 2048 + ko0);
#pragma unroll
    for (int j = 0; j < 4; j++) bf0[j] = *(const bf16x8*)(LB + j * 2048 + ko0);
  }

  for (int t = 0; t < nt; t++) {
    const int buf = t % 3;
    const int pbuf = (t + 2) % 3;
    const long pk0 = (long)(t + 2) << 6;
    const char* LA = lds + buf * 49152 + arow;
    const char* LB = lds + buf * 49152 + 32768 + brow;
    const bool pf = (t + 2 < nt);

    if (pf) { STAGE_A(pbuf, pk0, 0); STAGE_A(pbuf, pk0, 1); STAGE_B(pbuf, pk0, 0); }
#pragma unroll
    for (int i = 0; i < 4; i++) af1[i] = *(const bf16x8*)(LA + i * 2048 + ko1);
#pragma unroll
    for (int j = 0; j < 4; j++) bf1[j] = *(const bf16x8*)(LB + j * 2048 + ko1);
    SCHED();
    __builtin_amdgcn_s_setprio(1);
#pragma unroll
    for (int i = 0; i < 4; i++)
#pragma unroll
      for (int j = 0; j < 4; j++) mfma16(acc[i][j], af0[i], bf0[j]);
    __builtin_amdgcn_s_setprio(0);
    SCHED();

    if (pf) { STAGE_A(pbuf, pk0, 2); STAGE_A(pbuf, pk0, 3); STAGE_B(pbuf, pk0, 1); }
    if (t < nt - 2) asm volatile("s_waitcnt vmcnt(6) lgkmcnt(0)" ::: "memory");
    else            asm volatile("s_waitcnt vmcnt(0) lgkmcnt(0)" ::: "memory");
    SBAR();
    if (t < nt - 1) {
      const char* LAn = lds + ((t + 1) % 3) * 49152 + arow;
      const char* LBn = lds + ((t + 1) % 3) * 49152 + 32768 + brow;
#pragma unroll
      for (int i = 0; i < 4; i++) af0[i] = *(const bf16x8*)(LAn + i * 2048 + ko0);
#pragma unroll
      for (int j = 0; j < 4; j++) bf0[j] = *(const bf16x8*)(LBn + j * 2048 + ko0);
    }
    SCHED();
    __builtin_amdgcn_s_setprio(1);
#pragma unroll
    for (int i = 0; i < 4; i++)
#pragma unroll
      for (int j = 0; j < 4; j++) mfma16(acc[i][j], af1[i], bf1[j]);
    __builtin_amdgcn_s_setprio(0);
    SCHED();
  }
#undef STAGE_A
#undef STAGE_B

  const long crow = bm + wm * 64 + ((l >> 4) * 4);
  const long ccol = bn + wn * 64 + (l & 15);
  if constexpr (OUTB == 0) {
    float* C = (float*)Cv + (long)blockIdx.z * sC;
#pragma unroll
    for (int i = 0; i < 4; i++)
#pragma unroll
      for (int r = 0; r < 4; r++) {
        long row = crow + i * 16 + r;
#pragma unroll
        for (int j = 0; j < 4; j++) C[row * (long)ldc + ccol + j * 16] = acc[i][j][r];
      }
  } else {
    uint16_t* C = (uint16_t*)Cv + (long)blockIdx.z * sC;
#pragma unroll
    for (int i = 0; i < 4; i++)
#pragma unroll
      for (int r = 0; r < 4; r++) {
        long row = crow + i * 16 + r;
#pragma unroll
        for (int j = 0; j < 4; j++) C[row * (long)ldc + ccol + j * 16] = f2bf(acc[i][j][r]);
      }
  }
}

// ================= legacy 128x128 GEMM (small weight-prep matmuls) =================
template<int OUTB>
__global__ void __launch_bounds__(256) gemm_bt(
    const uint16_t* __restrict__ A, const uint16_t* __restrict__ B,
    void* __restrict__ Cv, int K, int lda, int ldb, int ldc,
    long sA, long sB, long sC)
{
  __shared__ alignas(16) uint16_t As[4096];
  __shared__ alignas(16) uint16_t Bs[4096];
  const int tid = threadIdx.x;
  const int w = tid >> 6, l = tid & 63;
  const int wr = w >> 1, wc = w & 1;
  const long bm = (long)blockIdx.x * 128, bn = (long)blockIdx.y * 128;
  A += (long)blockIdx.z * sA;
  B += (long)blockIdx.z * sB;

  const uint16_t* ga0 = A + (bm + w * 16 + (l >> 2)) * (long)lda + (l & 3) * 8;
  const uint16_t* ga1 = ga0 + 64L * lda;
  const uint16_t* gb0 = B + (bn + w * 16 + (l >> 2)) * (long)ldb + (l & 3) * 8;
  const uint16_t* gb1 = gb0 + 64L * ldb;
  uint16_t* la0 = &As[w * 512];
  uint16_t* la1 = &As[2048 + w * 512];
  uint16_t* lb0 = &Bs[w * 512];
  uint16_t* lb1 = &Bs[2048 + w * 512];

  floatx4 acc[4][4];
#pragma unroll
  for (int i = 0; i < 4; i++)
#pragma unroll
    for (int j = 0; j < 4; j++) acc[i][j] = (floatx4){0.f, 0.f, 0.f, 0.f};

  const int rA = (wr * 64 + (l & 15)) * 32 + (l >> 4) * 8;
  const int rB = (wc * 64 + (l & 15)) * 32 + (l >> 4) * 8;

  for (int k0 = 0; k0 < K; k0 += 32) {
    __builtin_amdgcn_global_load_lds(ga0, la0, 16, 0, 0);
    __builtin_amdgcn_global_load_lds(ga1, la1, 16, 0, 0);
    __builtin_amdgcn_global_load_lds(gb0, lb0, 16, 0, 0);
    __builtin_amdgcn_global_load_lds(gb1, lb1, 16, 0, 0);
    ga0 += 32; ga1 += 32; gb0 += 32; gb1 += 32;
    __syncthreads();
    bf16x8 af[4], bfr[4];
#pragma unroll
    for (int i = 0; i < 4; i++) af[i] = *(const bf16x8*)&As[rA + i * 512];
#pragma unroll
    for (int j = 0; j < 4; j++) bfr[j] = *(const bf16x8*)&Bs[rB + j * 512];
#pragma unroll
    for (int i = 0; i < 4; i++)
#pragma unroll
      for (int j = 0; j < 4; j++) mfma16(acc[i][j], af[i], bfr[j]);
    __syncthreads();
  }

  const long crow = bm + wr * 64 + ((l >> 4) * 4);
  const long ccol = bn + wc * 64 + (l & 15);
  if constexpr (OUTB == 0) {
    float* C = (float*)Cv + (long)blockIdx.z * sC;
#pragma unroll
    for (int i = 0; i < 4; i++)
#pragma unroll
      for (int r = 0; r < 4; r++) {
        long row = crow + i * 16 + r;
#pragma unroll
        for (int j = 0; j < 4; j++) C[row * (long)ldc + ccol + j * 16] = acc[i][j][r];
      }
  } else {
    uint16_t* C = (uint16_t*)Cv + (long)blockIdx.z * sC;
#pragma unroll
    for (int i = 0; i < 4; i++)
#pragma unroll
      for (int r = 0; r < 4; r++) {
        long row = crow + i * 16 + r;
#pragma unroll
        for (int j = 0; j < 4; j++) C[row * (long)ldc + ccol + j * 16] = f2bf(acc[i][j][r]);
      }
  }
}

// ---------- fp32 -> bf16 convert ----------
__global__ void __launch_bounds__(256) cvt_k(const float* __restrict__ in,
                                             uint16_t* __restrict__ out, long n) {
  long i = ((long)blockIdx.x * 256 + threadIdx.x) * 4;
  if (i >= n) return;
  float4 v = *(const float4*)(in + i);
  ushort4 o; o.x = f2bf(v.x); o.y = f2bf(v.y); o.z = f2bf(v.z); o.w = f2bf(v.w);
  *(ushort4*)(out + i) = o;
}

// ---------- transpose (R,Cc) -> (Cc,R), bf16 out ----------
template<typename TIN>
__global__ void __launch_bounds__(256) transpose_to_bf16(
    const TIN* __restrict__ in, uint16_t* __restrict__ out,
    int ld_in, int ld_out, long sIn, long sOut)
{
  __shared__ float tile[32][33];
  in += (long)blockIdx.z * sIn;
  out += (long)blockIdx.z * sOut;
  const int rb = blockIdx.y * 32, cb = blockIdx.x * 32;
#pragma unroll
  for (int i = 0; i < 32; i += 8)
    tile[threadIdx.y + i][threadIdx.x] =
        ld_as_float(in[(long)(rb + threadIdx.y + i) * ld_in + cb + threadIdx.x]);
  __syncthreads();
#pragma unroll
  for (int i = 0; i < 32; i += 8)
    out[(long)(cb + threadIdx.y + i) * ld_out + rb + threadIdx.x] =
        f2bf(tile[threadIdx.x][threadIdx.y + i]);
}

// ---------- rmsnorm: one block per row; DIM = PT*256 ----------
template<int PT, typename TIN>
__global__ void __launch_bounds__(256) rmsnorm_k(
    const TIN* __restrict__ in, const float* __restrict__ g,
    float* __restrict__ out_f, uint16_t* __restrict__ out_b, int ld_b)
{
  constexpr int DIM = PT * 256;
  __shared__ float sm[9];
  const TIN* x = in + (long)blockIdx.x * DIM;
  const int base = threadIdx.x * PT;
  float v[PT];
  if constexpr (sizeof(TIN) == 2) {
#pragma unroll
    for (int i = 0; i < PT; i += 8) {
      u16x8 t = *(const u16x8*)&x[base + i];
#pragma unroll
      for (int q = 0; q < 8; q++) v[i + q] = bf2f(t[q]);
    }
  } else if constexpr (PT == 2) {
    float2 t = *(const float2*)&x[base]; v[0] = t.x; v[1] = t.y;
  } else {
#pragma unroll
    for (int i = 0; i < PT; i += 4) {
      float4 t = *(const float4*)&x[base + i];
      v[i] = t.x; v[i + 1] = t.y; v[i + 2] = t.z; v[i + 3] = t.w;
    }
  }
  float ss = 0.f;
#pragma unroll
  for (int i = 0; i < PT; i++) ss += v[i] * v[i];
#pragma unroll
  for (int o = 32; o; o >>= 1) ss += __shfl_down(ss, o);
  if ((threadIdx.x & 63) == 0) sm[threadIdx.x >> 6] = ss;
  __syncthreads();
  if (threadIdx.x == 0)
    sm[8] = rsqrtf((sm[0] + sm[1] + sm[2] + sm[3]) * (1.0f / DIM) + 1.1920929e-7f);
  __syncthreads();
  const float sc = sm[8];
#pragma unroll
  for (int i = 0; i < PT; i++) {
    float y = v[i] * sc * g[base + i];
    if (out_f) out_f[(long)blockIdx.x * DIM + base + i] = y;
    if (out_b) out_b[(long)blockIdx.x * ld_b + base + i] = f2bf(y);
  }
}

// ---------- rope table ----------
__global__ void __launch_bounds__(256) rope_table(float2* __restrict__ tab) {
  int idx = blockIdx.x * 256 + threadIdx.x;  // 2048*64
  int s = idx >> 6, fi = idx & 63;
  float f = powf(10000.0f, -(float)fi * (1.0f / 64.0f));
  float ang = (float)s * f;
  tab[idx] = make_float2(cosf(ang), sinf(ang));
}

// ---------- rope apply: in bf16 (8192,2048); bf16 out -> cat[:,512:]; optional fp32 out ----------
template<bool WF32>
__global__ void __launch_bounds__(256) rope_k(
    const uint16_t* __restrict__ in, uint16_t* __restrict__ outb,
    float* __restrict__ outf, const float2* __restrict__ tab)
{
  long idx = (long)blockIdx.x * 256 + threadIdx.x;  // 8192*1024 pairs
  int r = (int)(idx >> 10);
  int pp = (int)idx & 1023;
  int s = r & 2047;
  int fi = pp & 63;
  ushort2 xv = *(const ushort2*)(in + ((long)r << 11) + 2 * pp);
  float x0 = bf2f(xv.x), x1 = bf2f(xv.y);
  float2 cs = tab[(s << 6) + fi];
  float y0 = x0 * cs.x - x1 * cs.y;
  float y1 = x0 * cs.y + x1 * cs.x;
  ushort2 ov; ov.x = f2bf(y0); ov.y = f2bf(y1);
  *(ushort2*)(outb + (long)r * 2560 + 512 + 2 * pp) = ov;
  if (WF32) *(float2*)(outf + ((long)r << 11) + 2 * pp) = make_float2(y0, y1);
}

// ---------- softmax over rows of 2048, scale 1/12, fp32 in, bf16 out ----------
__global__ void __launch_bounds__(256) softmax_k(const float* __restrict__ sc,
                                                 uint16_t* __restrict__ attn) {
  __shared__ float sm[9];
  const float* x = sc + ((long)blockIdx.x << 11);
  const int base = threadIdx.x * 8;
  float v[8];
  *(float4*)&v[0] = *(const float4*)&x[base];
  *(float4*)&v[4] = *(const float4*)&x[base + 4];
  const float inv = 1.0f / 12.0f;
  float m = -1e30f;
#pragma unroll
  for (int i = 0; i < 8; i++) { v[i] *= inv; m = fmaxf(m, v[i]); }
#pragma unroll
  for (int o = 32; o; o >>= 1) m = fmaxf(m, __shfl_down(m, o));
  if ((threadIdx.x & 63) == 0) sm[threadIdx.x >> 6] = m;
  __syncthreads();
  if (threadIdx.x == 0)
    sm[8] = fmaxf(fmaxf(sm[0], sm[1]), fmaxf(sm[2], sm[3]));
  __syncthreads();
  m = sm[8];
  __syncthreads();
  float ss = 0.f;
#pragma unroll
  for (int i = 0; i < 8; i++) { v[i] = __expf(v[i] - m); ss += v[i]; }
#pragma unroll
  for (int o = 32; o; o >>= 1) ss += __shfl_down(ss, o);
  if ((threadIdx.x & 63) == 0) sm[threadIdx.x >> 6] = ss;
  __syncthreads();
  if (threadIdx.x == 0) sm[8] = 1.0f / (sm[0] + sm[1] + sm[2] + sm[3]);
  __syncthreads();
  const float r = sm[8];
  ushort4 o1, o2;
  o1.x = f2bf(v[0] * r); o1.y = f2bf(v[1] * r); o1.z = f2bf(v[2] * r); o1.w = f2bf(v[3] * r);
  o2.x = f2bf(v[4] * r); o2.y = f2bf(v[5] * r); o2.z = f2bf(v[6] * r); o2.w = f2bf(v[7] * r);
  uint16_t* dst = attn + ((long)blockIdx.x << 11) + base;
  *(ushort4*)dst = o1;
  *(ushort4*)(dst + 4) = o2;
}

// ---------- orchestration ----------
extern "C" void kernel_launch(void* const* d_in, const int* in_sizes, int n_in,
                              void* d_out, int out_size, void* d_ws, size_t ws_size,
                              hipStream_t stream) {
  (void)in_sizes; (void)n_in; (void)out_size; (void)ws_size;
  const float* h    = (const float*)d_in[0];
  const float* wdkv = (const float*)d_in[1];
  const float* wuk  = (const float*)d_in[2];
  const float* wuv  = (const float*)d_in[3];
  const float* wdq  = (const float*)d_in[4];
  const float* wuq  = (const float*)d_in[5];
  const float* wkr  = (const float*)d_in[6];
  const float* wqr  = (const float*)d_in[7];
  const float* wo   = (const float*)d_in[8];
  const float* g1   = (const float*)d_in[9];
  const float* g2   = (const float*)d_in[10];
  const float* g3   = (const float*)d_in[11];

  float* u_out   = (float*)d_out;                 // (4,2048,2048)
  float* ckv_out = u_out + 16777216L;             // (4,2048,512)
  float* kr_out  = ckv_out + 4194304L;            // (4,2048,2048)

  char* p = (char*)d_ws;
  auto alloc = [&](size_t bytes) -> void* {
    void* q = (void*)p; p += (bytes + 255) & ~(size_t)255; return q;
  };
  uint16_t* hb     = (uint16_t*)alloc(16777216ULL * 2);  // h bf16
  uint16_t* wcat   = (uint16_t*)alloc(3145728ULL * 2);   // (1536,2048) [wdq;wdkv;Bqt]
  uint16_t* wqr_b  = (uint16_t*)alloc(1048576ULL * 2);
  uint16_t* wkr_b  = (uint16_t*)alloc(4194304ULL * 2);
  uint16_t* wo_b   = (uint16_t*)alloc(4194304ULL * 2);
  uint16_t* wukT   = (uint16_t*)alloc(1048576ULL * 2);   // (512,2048)
  uint16_t* wuqT   = (uint16_t*)alloc(1048576ULL * 2);
  uint16_t* wuvT   = (uint16_t*)alloc(1048576ULL * 2);
  uint16_t* wdqT   = (uint16_t*)alloc(1048576ULL * 2);   // (2048,512)
  uint16_t* T1t    = (uint16_t*)alloc(262144ULL * 2);    // (512,512)
  uint16_t* awoT   = (uint16_t*)alloc(1048576ULL * 2);   // absorbed_w_o^T (2048,512)
  uint16_t* cq_b   = (uint16_t*)alloc(4194304ULL * 2);   // (8192,512)
  uint16_t* catq   = (uint16_t*)alloc(20971520ULL * 2);  // (8192,2560) [aq|qr]
  uint16_t* catk   = (uint16_t*)alloc(20971520ULL * 2);  // (8192,2560) [ckv|kr]
  uint16_t* ckvT   = (uint16_t*)alloc(4194304ULL * 2);   // 4 x (512,2048)
  uint16_t* o_b    = (uint16_t*)alloc(4194304ULL * 2);   // (8192,512)
  float2*   rtab   = (float2*)alloc(131072ULL * 8);      // 2048x64 (cos,sin)
  float*    tmpS   = (float*)alloc(4194304ULL * 4);      // (8192,512) fp32 cq-pre
  float*    tmpS2  = (float*)alloc(4194304ULL * 4);      // (8192,512) fp32 ckv-pre
  float*    tmpB   = (float*)alloc(16777216ULL * 4);     // (8192,2048) fp32 scores
  uint16_t* tmpBb  = (uint16_t*)tmpB;                    // alias: (8192,2048) bf16
  uint16_t* attn   = catq;  // alias: catq dead after scores GEMM

  uint16_t* wdq_b  = wcat;                  // rows 0-511
  uint16_t* wdkv_b = wcat + 1048576;        // rows 512-1023
  uint16_t* Bqt    = wcat + 2097152;        // rows 1024-1535 (absorbed_w_q^T)

  const dim3 b256(256);
  const dim3 b512(512);
  const dim3 tb(32, 8);

  // dtype converts
  cvt_k<<<dim3(16384), b256, 0, stream>>>(h, hb, 16777216L);
  cvt_k<<<dim3(1024),  b256, 0, stream>>>(wdq, wdq_b, 1048576L);
  cvt_k<<<dim3(1024),  b256, 0, stream>>>(wdkv, wdkv_b, 1048576L);
  cvt_k<<<dim3(1024),  b256, 0, stream>>>(wqr, wqr_b, 1048576L);
  cvt_k<<<dim3(4096),  b256, 0, stream>>>(wkr, wkr_b, 4194304L);
  cvt_k<<<dim3(4096),  b256, 0, stream>>>(wo, wo_b, 4194304L);
  // weight transposes (fp32 -> bf16)
  transpose_to_bf16<float><<<dim3(16, 64, 1), tb, 0, stream>>>(wuk, wukT, 512, 2048, 0, 0);
  transpose_to_bf16<float><<<dim3(16, 64, 1), tb, 0, stream>>>(wuq, wuqT, 512, 2048, 0, 0);
  transpose_to_bf16<float><<<dim3(16, 64, 1), tb, 0, stream>>>(wuv, wuvT, 512, 2048, 0, 0);
  transpose_to_bf16<float><<<dim3(64, 16, 1), tb, 0, stream>>>(wdq, wdqT, 2048, 512, 0, 0);
  rope_table<<<dim3(512), b256, 0, stream>>>(rtab);

  // absorbed weights (small — legacy kernel)
  gemm_bt<1><<<dim3(4, 4, 1), b256, 0, stream>>>(wukT, wuqT, T1t, 2048, 2048, 2048, 512, 0, 0, 0);
  gemm_bt<1><<<dim3(4, 16, 1), b256, 0, stream>>>(T1t, wdqT, Bqt, 512, 512, 512, 2048, 0, 0, 0);
  gemm_bt<1><<<dim3(16, 4, 1), b256, 0, stream>>>(wo_b, wuvT, awoT, 2048, 2048, 2048, 512, 0, 0, 0);

  // fused: [cq-pre | ckv-pre | aq] = h @ [wdq; wdkv; Bqt]^T  (N=1536, K=2048)
  gemm256sq<2><<<dim3(32, 6, 1), b512, 0, stream>>>(
      hb, wcat, tmpS, tmpS2, catq, 2048, 2048, 2048, 0, 0, 0, 0);
  // cq = rmsnorm(cq-pre, g1)
  rmsnorm_k<2, float><<<dim3(8192), b256, 0, stream>>>(tmpS, g1, nullptr, cq_b, 512);
  // qr = rope(cq @ wqr^T) -> catq[:,512:]
  gemm256sq<1><<<dim3(32, 8, 1), b512, 0, stream>>>(
      cq_b, wqr_b, tmpBb, nullptr, nullptr, 512, 512, 512, 2048, 0, 0, 0);
  rope_k<false><<<dim3(32768), b256, 0, stream>>>(tmpBb, catq, nullptr, rtab);
  // ckv = rmsnorm(ckv-pre, g2) -> ckv_out (fp32) + catk[:,0:512] (bf16)
  rmsnorm_k<2, float><<<dim3(8192), b256, 0, stream>>>(tmpS2, g2, ckv_out, catk, 2560);
  // ckvT: 4 x (512,2048) from catk cols 0..511
  transpose_to_bf16<uint16_t><<<dim3(16, 64, 4), tb, 0, stream>>>(
      catk, ckvT, 2560, 2048, 2048L * 2560, 512L * 2048);
  // kr = rope(h @ wkr^T) -> kr_out (fp32) + catk[:,512:]
  gemm256sq<1><<<dim3(32, 8, 1), b512, 0, stream>>>(
      hb, wkr_b, tmpBb, nullptr, nullptr, 2048, 2048, 2048, 2048, 0, 0, 0);
  rope_k<true><<<dim3(32768), b256, 0, stream>>>(tmpBb, catk, kr_out, rtab);
  // scores[b] = catq_b @ catk_b^T (K=2560) -> tmpB fp32
  gemm256sq<0><<<dim3(8, 8, 4), b512, 0, stream>>>(
      catq, catk, tmpB, nullptr, nullptr, 2560, 2560, 2560, 2048,
      5242880L, 5242880L, 4194304L);
  // softmax(scores/12) -> attn bf16 (aliases catq)
  softmax_k<<<dim3(8192), b256, 0, stream>>>(tmpB, attn);
  // o[b] = attn_b @ ckv_b (via ckvT) -> o_b bf16
  gemm256<1><<<dim3(8, 4, 4), b512, 0, stream>>>(
      attn, ckvT, o_b, 2048, 2048, 2048, 512, 4194304L, 1048576L, 1048576L);
  // u = rmsnorm(o @ absorbed_w_o, g3) -> u_out
  gemm256sq<1><<<dim3(32, 8, 1), b512, 0, stream>>>(
      o_b, awoT, tmpBb, nullptr, nullptr, 512, 512, 512, 2048, 0, 0, 0);
  rmsnorm_k<8, uint16_t><<<dim3(8192), b256, 0, stream>>>(tmpBb, g3, u_out, nullptr, 0);
}

// Round 5
// 573.265 us; speedup vs baseline: 1.2568x; 1.0098x over previous
//
#include <hip/hip_runtime.h>
#include <stdint.h>

// ---------- small helpers ----------
typedef __attribute__((ext_vector_type(8))) short bf16x8;
typedef __attribute__((ext_vector_type(8))) unsigned short u16x8;
typedef __attribute__((ext_vector_type(4))) float floatx4;

__device__ __forceinline__ uint16_t f2bf(float f) {
  union { float f; uint32_t u; } v; v.f = f;
  uint32_t r = v.u + 0x7fffu + ((v.u >> 16) & 1u);
  return (uint16_t)(r >> 16);
}
__device__ __forceinline__ float bf2f(uint16_t b) {
  union { uint32_t u; float f; } v; v.u = ((uint32_t)b) << 16;
  return v.f;
}
__device__ __forceinline__ float ld_as_float(float v) { return v; }
__device__ __forceinline__ float ld_as_float(uint16_t v) { return bf2f(v); }

__device__ __forceinline__ void mfma16(floatx4& d, bf16x8 a, bf16x8 b) {
  asm("v_mfma_f32_16x16x32_bf16 %0, %1, %2, %0" : "+v"(d) : "v"(a), "v"(b));
}

#define FENCE() asm volatile("" ::: "memory")
#define SCHED() __builtin_amdgcn_sched_barrier(0)
#define SBAR()                                  \
  do {                                          \
    FENCE();                                    \
    __builtin_amdgcn_sched_barrier(0);          \
    __builtin_amdgcn_s_barrier();               \
    __builtin_amdgcn_sched_barrier(0);          \
    FENCE();                                    \
  } while (0)

// ================= m201-geometry GEMM: 256x256, BK=64, counted vmcnt =================
// C(M,N) = A(M,K) @ B(N,K)^T, bf16 in, fp32 acc.
// 512 threads = 8 waves (2M x 4N), per-wave 128x64 output (8x4 frags).
// LDS: 2 buffers x (A 32KB + B 32KB) = 128 KB. 4 phases per K-tile, 16 MFMA each.
// Staging FIFO (2 global_load_lds/phase): B0,B1 | A0,A2 | B2,B3 | A1,A3 into buf^1.
// Counted waits only (T4): vmcnt(4) end-ph1 (retires A1,A3 of current tile,
// consumed by ph2-3 reads), vmcnt(2) end-ph3 (retires B-all+A0,A2 of next tile,
// consumed by ph0-1 reads; its A1,A3 stay in flight). Never drains in main loop.
// XOR-swizzled LDS ((row&7)<<4 on byte offset) via pre-swizzled global src.
// MODE 0: fp32 out; 1: bf16 out; 2: routed (cols 0-511 fp32 C0 ld512,
//         512-1023 fp32 C1 ld512, 1024-1535 bf16 C2 ld2560).
template<int MODE>
__global__ void __launch_bounds__(512, 1) gemm256sq(
    const uint16_t* __restrict__ A, const uint16_t* __restrict__ B,
    void* __restrict__ C0v, void* __restrict__ C1v, void* __restrict__ C2v,
    int K, int lda, int ldb, int ldc,
    long sA, long sB, long sC)
{
  __shared__ __attribute__((aligned(16))) char lds[131072];
  const int tid = threadIdx.x;
  const int w = tid >> 6, l = tid & 63;
  const int wm = w >> 2, wn = w & 3;

  // XCD-aware swizzle over the (x,y) plane (all grids here have nwg % 8 == 0)
  const int gx = gridDim.x;
  const int nwg = gx * gridDim.y;
  int id = blockIdx.y * gx + blockIdx.x;
  if ((nwg & 7) == 0) id = (id & 7) * (nwg >> 3) + (id >> 3);
  const long bm = (long)(id % gx) * 256;
  const long bn = (long)(id / gx) * 256;
  A += (long)blockIdx.z * sA;
  B += (long)blockIdx.z * sB;

  // ---- staging: round = 64 rows x 128B; wave w owns 8 rows per round ----
  const int sr = l >> 3;               // sub-row within wave's 8 rows
  const int sc = l & 7;                // 16B chunk
  const int scol = ((sc ^ sr) << 3);   // pre-swizzled source col (elements)
  const uint16_t* gA = A + (bm + w * 8 + sr) * (long)lda + scol;
  const uint16_t* gB = B + (bn + w * 8 + sr) * (long)ldb + scol;
  const int ldsw = w * 1024;

#define STG_A(bufi, k0, r)                                                     \
  __builtin_amdgcn_global_load_lds(gA + (k0) + (long)(r) * 64 * lda,           \
      (uint16_t*)(lds + (bufi) * 65536 + (r) * 8192 + ldsw), 16, 0, 0)
#define STG_B(bufi, k0, r)                                                     \
  __builtin_amdgcn_global_load_lds(gB + (k0) + (long)(r) * 64 * ldb,           \
      (uint16_t*)(lds + (bufi) * 65536 + 32768 + (r) * 8192 + ldsw), 16, 0, 0)

  // ---- fragment read geometry ----
  const int kk = (l >> 4) << 4;
  const int msk = (l & 7) << 4;
  const int ko0 = kk ^ msk;
  const int ko1 = (64 + kk) ^ msk;
  const int aoff = (wm * 128 + (l & 15)) * 128;
  const int boff = 32768 + (wn * 64 + (l & 15)) * 128;

  floatx4 acc[8][4];
#pragma unroll
  for (int i = 0; i < 8; i++)
#pragma unroll
    for (int j = 0; j < 4; j++) acc[i][j] = (floatx4){0.f, 0.f, 0.f, 0.f};

  const int nt = K >> 6;
  // prologue: stage tile 0 into buf0 in loop FIFO order
  STG_B(0, 0, 0); STG_B(0, 0, 1);
  STG_A(0, 0, 0); STG_A(0, 0, 2);
  STG_B(0, 0, 2); STG_B(0, 0, 3);
  STG_A(0, 0, 1); STG_A(0, 0, 3);
  asm volatile("s_waitcnt vmcnt(2)" ::: "memory");  // all but A1,A3 landed
  SBAR();

  bf16x8 Bf[4][2];
  for (int t = 0; t < nt; t++) {
    const int buf = t & 1;
    const int nbuf = buf ^ 1;
    const char* Lb = lds + buf * 65536;
    const long nk0 = (long)(t + 1) << 6;
    const bool pf = (t + 1 < nt);
    bf16x8 Af[2][2];

    // ---------------- phase 0: MFMA i=0,1 (reads B-all + A rounds 0/2) ----------------
    if (pf) { STG_B(nbuf, nk0, 0); STG_B(nbuf, nk0, 1); }
#pragma unroll
    for (int j = 0; j < 4; j++) {
      Bf[j][0] = *(const bf16x8*)(Lb + boff + j * 2048 + ko0);
      Bf[j][1] = *(const bf16x8*)(Lb + boff + j * 2048 + ko1);
    }
#pragma unroll
    for (int ii = 0; ii < 2; ii++) {
      Af[ii][0] = *(const bf16x8*)(Lb + aoff + ii * 2048 + ko0);
      Af[ii][1] = *(const bf16x8*)(Lb + aoff + ii * 2048 + ko1);
    }
    SBAR();
    asm volatile("s_waitcnt lgkmcnt(0)" ::: "memory");
    SCHED();
    __builtin_amdgcn_s_setprio(1);
#pragma unroll
    for (int ii = 0; ii < 2; ii++)
#pragma unroll
      for (int j = 0; j < 4; j++) {
        mfma16(acc[ii][j], Af[ii][0], Bf[j][0]);
        mfma16(acc[ii][j], Af[ii][1], Bf[j][1]);
      }
    __builtin_amdgcn_s_setprio(0);
    SBAR();

    // ---------------- phase 1: MFMA i=2,3 (reads A rounds 0/2) ----------------
    if (pf) { STG_A(nbuf, nk0, 0); STG_A(nbuf, nk0, 2); }
#pragma unroll
    for (int ii = 0; ii < 2; ii++) {
      Af[ii][0] = *(const bf16x8*)(Lb + aoff + (2 + ii) * 2048 + ko0);
      Af[ii][1] = *(const bf16x8*)(Lb + aoff + (2 + ii) * 2048 + ko1);
    }
    SBAR();
    asm volatile("s_waitcnt lgkmcnt(0)" ::: "memory");
    SCHED();
    __builtin_amdgcn_s_setprio(1);
#pragma unroll
    for (int ii = 0; ii < 2; ii++)
#pragma unroll
      for (int j = 0; j < 4; j++) {
        mfma16(acc[2 + ii][j], Af[ii][0], Bf[j][0]);
        mfma16(acc[2 + ii][j], Af[ii][1], Bf[j][1]);
      }
    __builtin_amdgcn_s_setprio(0);
    // counted: retire A rounds 1,3 of THIS tile (needed by ph2-3 reads);
    // in-flight stays 4 (B0,B1,A0,A2 of t+1) when prefetching.
    if (pf) asm volatile("s_waitcnt vmcnt(4)" ::: "memory");
    else    asm volatile("s_waitcnt vmcnt(0)" ::: "memory");
    SBAR();

    // ---------------- phase 2: MFMA i=4,5 (reads A rounds 1/3) ----------------
    if (pf) { STG_B(nbuf, nk0, 2); STG_B(nbuf, nk0, 3); }
#pragma unroll
    for (int ii = 0; ii < 2; ii++) {
      Af[ii][0] = *(const bf16x8*)(Lb + aoff + (4 + ii) * 2048 + ko0);
      Af[ii][1] = *(const bf16x8*)(Lb + aoff + (4 + ii) * 2048 + ko1);
    }
    SBAR();
    asm volatile("s_waitcnt lgkmcnt(0)" ::: "memory");
    SCHED();
    __builtin_amdgcn_s_setprio(1);
#pragma unroll
    for (int ii = 0; ii < 2; ii++)
#pragma unroll
      for (int j = 0; j < 4; j++) {
        mfma16(acc[4 + ii][j], Af[ii][0], Bf[j][0]);
        mfma16(acc[4 + ii][j], Af[ii][1], Bf[j][1]);
      }
    __builtin_amdgcn_s_setprio(0);
    SBAR();

    // ---------------- phase 3: MFMA i=6,7 (reads A rounds 1/3) ----------------
    if (pf) { STG_A(nbuf, nk0, 1); STG_A(nbuf, nk0, 3); }
#pragma unroll
    for (int ii = 0; ii < 2; ii++) {
      Af[ii][0] = *(const bf16x8*)(Lb + aoff + (6 + ii) * 2048 + ko0);
      Af[ii][1] = *(const bf16x8*)(Lb + aoff + (6 + ii) * 2048 + ko1);
    }
    SBAR();
    asm volatile("s_waitcnt lgkmcnt(0)" ::: "memory");
    SCHED();
    __builtin_amdgcn_s_setprio(1);
#pragma unroll
    for (int ii = 0; ii < 2; ii++)
#pragma unroll
      for (int j = 0; j < 4; j++) {
        mfma16(acc[6 + ii][j], Af[ii][0], Bf[j][0]);
        mfma16(acc[6 + ii][j], Af[ii][1], Bf[j][1]);
      }
    __builtin_amdgcn_s_setprio(0);
    // counted: retire B-all + A rounds 0,2 of t+1 (needed by ph0-1 of t+1);
    // its A rounds 1,3 (2 loads) stay in flight.
    if (pf) asm volatile("s_waitcnt vmcnt(2)" ::: "memory");
    SBAR();
  }
#undef STG_A
#undef STG_B

  const long crow = bm + wm * 128 + ((l >> 4) * 4);
  const long ccol = bn + wn * 64 + (l & 15);
  if constexpr (MODE == 0) {
    float* C = (float*)C0v + (long)blockIdx.z * sC;
#pragma unroll
    for (int i = 0; i < 8; i++)
#pragma unroll
      for (int r = 0; r < 4; r++) {
        long row = crow + i * 16 + r;
#pragma unroll
        for (int j = 0; j < 4; j++) C[row * (long)ldc + ccol + j * 16] = acc[i][j][r];
      }
  } else if constexpr (MODE == 1) {
    uint16_t* C = (uint16_t*)C0v + (long)blockIdx.z * sC;
#pragma unroll
    for (int i = 0; i < 8; i++)
#pragma unroll
      for (int r = 0; r < 4; r++) {
        long row = crow + i * 16 + r;
#pragma unroll
        for (int j = 0; j < 4; j++) C[row * (long)ldc + ccol + j * 16] = f2bf(acc[i][j][r]);
      }
  } else {
    if (bn < 1024) {
      float* C = (bn < 512) ? (float*)C0v : (float*)C1v;
      const long cc = ccol - ((bn < 512) ? 0 : 512);
#pragma unroll
      for (int i = 0; i < 8; i++)
#pragma unroll
        for (int r = 0; r < 4; r++) {
          long row = crow + i * 16 + r;
#pragma unroll
          for (int j = 0; j < 4; j++) C[row * 512 + cc + j * 16] = acc[i][j][r];
        }
    } else {
      uint16_t* C = (uint16_t*)C2v;
      const long cc = ccol - 1024;
#pragma unroll
      for (int i = 0; i < 8; i++)
#pragma unroll
        for (int r = 0; r < 4; r++) {
          long row = crow + i * 16 + r;
#pragma unroll
          for (int j = 0; j < 4; j++) C[row * 2560 + cc + j * 16] = f2bf(acc[i][j][r]);
        }
    }
  }
}

// ================= 256x128 pipelined GEMM (for the small-N o GEMM) =================
template<int OUTB>
__global__ void __launch_bounds__(512, 2) gemm256(
    const uint16_t* __restrict__ A, const uint16_t* __restrict__ B,
    void* __restrict__ Cv, int K, int lda, int ldb, int ldc,
    long sA, long sB, long sC)
{
  __shared__ __attribute__((aligned(16))) char lds[147456];
  const int tid = threadIdx.x;
  const int w = tid >> 6, l = tid & 63;
  const int wm = w >> 1, wn = w & 1;

  const int gx = gridDim.x;
  const int nwg = gx * gridDim.y;
  int id = blockIdx.y * gx + blockIdx.x;
  if ((nwg & 7) == 0) id = (id & 7) * (nwg >> 3) + (id >> 3);
  const long bm = (long)(id % gx) * 256;
  const long bn = (long)(id / gx) * 128;
  A += (long)blockIdx.z * sA;
  B += (long)blockIdx.z * sB;

  const int sr = l >> 3;
  const int sc = l & 7;
  const int scol = ((sc ^ sr) << 3);
  const uint16_t* gA = A + (bm + w * 8 + sr) * (long)lda + scol;
  const uint16_t* gB = B + (bn + w * 8 + sr) * (long)ldb + scol;
  const int ldsw = w * 1024;

#define STAGE_A(bufi, k0, r)                                                     \
  __builtin_amdgcn_global_load_lds(gA + (k0) + (long)(r) * 64 * lda,             \
      (uint16_t*)(lds + (bufi) * 49152 + (r) * 8192 + ldsw), 16, 0, 0)
#define STAGE_B(bufi, k0, r)                                                     \
  __builtin_amdgcn_global_load_lds(gB + (k0) + (long)(r) * 64 * ldb,             \
      (uint16_t*)(lds + (bufi) * 49152 + 32768 + (r) * 8192 + ldsw), 16, 0, 0)

  const int lr = l & 15;
  const int kk = (l >> 4) << 4;
  const int msk = (l & 7) << 4;
  const int ko0 = kk ^ msk;
  const int ko1 = (64 + kk) ^ msk;
  const int arow = (wm * 64 + lr) * 128;
  const int brow = (wn * 64 + lr) * 128;

  floatx4 acc[4][4];
#pragma unroll
  for (int i = 0; i < 4; i++)
#pragma unroll
    for (int j = 0; j < 4; j++) acc[i][j] = (floatx4){0.f, 0.f, 0.f, 0.f};

  const int nt = K >> 6;
#pragma unroll
  for (int r = 0; r < 4; r++) STAGE_A(0, 0, r);
#pragma unroll
  for (int r = 0; r < 2; r++) STAGE_B(0, 0, r);
#pragma unroll
  for (int r = 0; r < 4; r++) STAGE_A(1, 64, r);
#pragma unroll
  for (int r = 0; r < 2; r++) STAGE_B(1, 64, r);
  asm volatile("s_waitcnt vmcnt(6)" ::: "memory");
  SBAR();

  bf16x8 af0[4], bf0[4], af1[4], bf1[4];
  {
    const char* LA = lds + arow;
    const char* LB = lds + 32768 + brow;
#pragma unroll
    for (int i = 0; i < 4; i++) af0[i] = *(const bf16x8*)(LA + i * 2048 + ko0);
#pragma unroll
    for (int j = 0; j < 4; j++) bf0[j] = *(const bf16x8*)(LB + j * 2048 + ko0);
  }

  for (int t = 0; t < nt; t++) {
    const int buf = t % 3;
    const int pbuf = (t + 2) % 3;
    const long pk0 = (long)(t + 2) << 6;
    const char* LA = lds + buf * 49152 + arow;
    const char* LB = lds + buf * 49152 + 32768 + brow;
    const bool pf = (t + 2 < nt);

    if (pf) { STAGE_A(pbuf, pk0, 0); STAGE_A(pbuf, pk0, 1); STAGE_B(pbuf, pk0, 0); }
#pragma unroll
    for (int i = 0; i < 4; i++) af1[i] = *(const bf16x8*)(LA + i * 2048 + ko1);
#pragma unroll
    for (int j = 0; j < 4; j++) bf1[j] = *(const bf16x8*)(LB + j * 2048 + ko1);
    SCHED();
    __builtin_amdgcn_s_setprio(1);
#pragma unroll
    for (int i = 0; i < 4; i++)
#pragma unroll
      for (int j = 0; j < 4; j++) mfma16(acc[i][j], af0[i], bf0[j]);
    __builtin_amdgcn_s_setprio(0);
    SCHED();

    if (pf) { STAGE_A(pbuf, pk0, 2); STAGE_A(pbuf, pk0, 3); STAGE_B(pbuf, pk0, 1); }
    if (t < nt - 2) asm volatile("s_waitcnt vmcnt(6) lgkmcnt(0)" ::: "memory");
    else            asm volatile("s_waitcnt vmcnt(0) lgkmcnt(0)" ::: "memory");
    SBAR();
    if (t < nt - 1) {
      const char* LAn = lds + ((t + 1) % 3) * 49152 + arow;
      const char* LBn = lds + ((t + 1) % 3) * 49152 + 32768 + brow;
#pragma unroll
      for (int i = 0; i < 4; i++) af0[i] = *(const bf16x8*)(LAn + i * 2048 + ko0);
#pragma unroll
      for (int j = 0; j < 4; j++) bf0[j] = *(const bf16x8*)(LBn + j * 2048 + ko0);
    }
    SCHED();
    __builtin_amdgcn_s_setprio(1);
#pragma unroll
    for (int i = 0; i < 4; i++)
#pragma unroll
      for (int j = 0; j < 4; j++) mfma16(acc[i][j], af1[i], bf1[j]);
    __builtin_amdgcn_s_setprio(0);
    SCHED();
  }
#undef STAGE_A
#undef STAGE_B

  const long crow = bm + wm * 64 + ((l >> 4) * 4);
  const long ccol = bn + wn * 64 + (l & 15);
  if constexpr (OUTB == 0) {
    float* C = (float*)Cv + (long)blockIdx.z * sC;
#pragma unroll
    for (int i = 0; i < 4; i++)
#pragma unroll
      for (int r = 0; r < 4; r++) {
        long row = crow + i * 16 + r;
#pragma unroll
        for (int j = 0; j < 4; j++) C[row * (long)ldc + ccol + j * 16] = acc[i][j][r];
      }
  } else {
    uint16_t* C = (uint16_t*)Cv + (long)blockIdx.z * sC;
#pragma unroll
    for (int i = 0; i < 4; i++)
#pragma unroll
      for (int r = 0; r < 4; r++) {
        long row = crow + i * 16 + r;
#pragma unroll
        for (int j = 0; j < 4; j++) C[row * (long)ldc + ccol + j * 16] = f2bf(acc[i][j][r]);
      }
  }
}

// ================= legacy 128x128 GEMM (small weight-prep matmuls) =================
template<int OUTB>
__global__ void __launch_bounds__(256) gemm_bt(
    const uint16_t* __restrict__ A, const uint16_t* __restrict__ B,
    void* __restrict__ Cv, int K, int lda, int ldb, int ldc,
    long sA, long sB, long sC)
{
  __shared__ alignas(16) uint16_t As[4096];
  __shared__ alignas(16) uint16_t Bs[4096];
  const int tid = threadIdx.x;
  const int w = tid >> 6, l = tid & 63;
  const int wr = w >> 1, wc = w & 1;
  const long bm = (long)blockIdx.x * 128, bn = (long)blockIdx.y * 128;
  A += (long)blockIdx.z * sA;
  B += (long)blockIdx.z * sB;

  const uint16_t* ga0 = A + (bm + w * 16 + (l >> 2)) * (long)lda + (l & 3) * 8;
  const uint16_t* ga1 = ga0 + 64L * lda;
  const uint16_t* gb0 = B + (bn + w * 16 + (l >> 2)) * (long)ldb + (l & 3) * 8;
  const uint16_t* gb1 = gb0 + 64L * ldb;
  uint16_t* la0 = &As[w * 512];
  uint16_t* la1 = &As[2048 + w * 512];
  uint16_t* lb0 = &Bs[w * 512];
  uint16_t* lb1 = &Bs[2048 + w * 512];

  floatx4 acc[4][4];
#pragma unroll
  for (int i = 0; i < 4; i++)
#pragma unroll
    for (int j = 0; j < 4; j++) acc[i][j] = (floatx4){0.f, 0.f, 0.f, 0.f};

  const int rA = (wr * 64 + (l & 15)) * 32 + (l >> 4) * 8;
  const int rB = (wc * 64 + (l & 15)) * 32 + (l >> 4) * 8;

  for (int k0 = 0; k0 < K; k0 += 32) {
    __builtin_amdgcn_global_load_lds(ga0, la0, 16, 0, 0);
    __builtin_amdgcn_global_load_lds(ga1, la1, 16, 0, 0);
    __builtin_amdgcn_global_load_lds(gb0, lb0, 16, 0, 0);
    __builtin_amdgcn_global_load_lds(gb1, lb1, 16, 0, 0);
    ga0 += 32; ga1 += 32; gb0 += 32; gb1 += 32;
    __syncthreads();
    bf16x8 af[4], bfr[4];
#pragma unroll
    for (int i = 0; i < 4; i++) af[i] = *(const bf16x8*)&As[rA + i * 512];
#pragma unroll
    for (int j = 0; j < 4; j++) bfr[j] = *(const bf16x8*)&Bs[rB + j * 512];
#pragma unroll
    for (int i = 0; i < 4; i++)
#pragma unroll
      for (int j = 0; j < 4; j++) mfma16(acc[i][j], af[i], bfr[j]);
    __syncthreads();
  }

  const long crow = bm + wr * 64 + ((l >> 4) * 4);
  const long ccol = bn + wc * 64 + (l & 15);
  if constexpr (OUTB == 0) {
    float* C = (float*)Cv + (long)blockIdx.z * sC;
#pragma unroll
    for (int i = 0; i < 4; i++)
#pragma unroll
      for (int r = 0; r < 4; r++) {
        long row = crow + i * 16 + r;
#pragma unroll
        for (int j = 0; j < 4; j++) C[row * (long)ldc + ccol + j * 16] = acc[i][j][r];
      }
  } else {
    uint16_t* C = (uint16_t*)Cv + (long)blockIdx.z * sC;
#pragma unroll
    for (int i = 0; i < 4; i++)
#pragma unroll
      for (int r = 0; r < 4; r++) {
        long row = crow + i * 16 + r;
#pragma unroll
        for (int j = 0; j < 4; j++) C[row * (long)ldc + ccol + j * 16] = f2bf(acc[i][j][r]);
      }
  }
}

// ---------- fp32 -> bf16 convert ----------
__global__ void __launch_bounds__(256) cvt_k(const float* __restrict__ in,
                                             uint16_t* __restrict__ out, long n) {
  long i = ((long)blockIdx.x * 256 + threadIdx.x) * 4;
  if (i >= n) return;
  float4 v = *(const float4*)(in + i);
  ushort4 o; o.x = f2bf(v.x); o.y = f2bf(v.y); o.z = f2bf(v.z); o.w = f2bf(v.w);
  *(ushort4*)(out + i) = o;
}

// ---------- transpose (R,Cc) -> (Cc,R), bf16 out ----------
template<typename TIN>
__global__ void __launch_bounds__(256) transpose_to_bf16(
    const TIN* __restrict__ in, uint16_t* __restrict__ out,
    int ld_in, int ld_out, long sIn, long sOut)
{
  __shared__ float tile[32][33];
  in += (long)blockIdx.z * sIn;
  out += (long)blockIdx.z * sOut;
  const int rb = blockIdx.y * 32, cb = blockIdx.x * 32;
#pragma unroll
  for (int i = 0; i < 32; i += 8)
    tile[threadIdx.y + i][threadIdx.x] =
        ld_as_float(in[(long)(rb + threadIdx.y + i) * ld_in + cb + threadIdx.x]);
  __syncthreads();
#pragma unroll
  for (int i = 0; i < 32; i += 8)
    out[(long)(cb + threadIdx.y + i) * ld_out + rb + threadIdx.x] =
        f2bf(tile[threadIdx.x][threadIdx.y + i]);
}

// ---------- rmsnorm: one block per row; DIM = PT*256 ----------
template<int PT, typename TIN>
__global__ void __launch_bounds__(256) rmsnorm_k(
    const TIN* __restrict__ in, const float* __restrict__ g,
    float* __restrict__ out_f, uint16_t* __restrict__ out_b, int ld_b)
{
  constexpr int DIM = PT * 256;
  __shared__ float sm[9];
  const TIN* x = in + (long)blockIdx.x * DIM;
  const int base = threadIdx.x * PT;
  float v[PT];
  if constexpr (sizeof(TIN) == 2) {
#pragma unroll
    for (int i = 0; i < PT; i += 8) {
      u16x8 t = *(const u16x8*)&x[base + i];
#pragma unroll
      for (int q = 0; q < 8; q++) v[i + q] = bf2f(t[q]);
    }
  } else if constexpr (PT == 2) {
    float2 t = *(const float2*)&x[base]; v[0] = t.x; v[1] = t.y;
  } else {
#pragma unroll
    for (int i = 0; i < PT; i += 4) {
      float4 t = *(const float4*)&x[base + i];
      v[i] = t.x; v[i + 1] = t.y; v[i + 2] = t.z; v[i + 3] = t.w;
    }
  }
  float ss = 0.f;
#pragma unroll
  for (int i = 0; i < PT; i++) ss += v[i] * v[i];
#pragma unroll
  for (int o = 32; o; o >>= 1) ss += __shfl_down(ss, o);
  if ((threadIdx.x & 63) == 0) sm[threadIdx.x >> 6] = ss;
  __syncthreads();
  if (threadIdx.x == 0)
    sm[8] = rsqrtf((sm[0] + sm[1] + sm[2] + sm[3]) * (1.0f / DIM) + 1.1920929e-7f);
  __syncthreads();
  const float sc = sm[8];
#pragma unroll
  for (int i = 0; i < PT; i++) {
    float y = v[i] * sc * g[base + i];
    if (out_f) out_f[(long)blockIdx.x * DIM + base + i] = y;
    if (out_b) out_b[(long)blockIdx.x * ld_b + base + i] = f2bf(y);
  }
}

// ---------- rope table ----------
__global__ void __launch_bounds__(256) rope_table(float2* __restrict__ tab) {
  int idx = blockIdx.x * 256 + threadIdx.x;  // 2048*64
  int s = idx >> 6, fi = idx & 63;
  float f = powf(10000.0f, -(float)fi * (1.0f / 64.0f));
  float ang = (float)s * f;
  tab[idx] = make_float2(cosf(ang), sinf(ang));
}

// ---------- rope apply: in bf16 (8192,2048); bf16 out -> cat[:,512:]; optional fp32 out ----------
template<bool WF32>
__global__ void __launch_bounds__(256) rope_k(
    const uint16_t* __restrict__ in, uint16_t* __restrict__ outb,
    float* __restrict__ outf, const float2* __restrict__ tab)
{
  long idx = (long)blockIdx.x * 256 + threadIdx.x;  // 8192*1024 pairs
  int r = (int)(idx >> 10);
  int pp = (int)idx & 1023;
  int s = r & 2047;
  int fi = pp & 63;
  ushort2 xv = *(const ushort2*)(in + ((long)r << 11) + 2 * pp);
  float x0 = bf2f(xv.x), x1 = bf2f(xv.y);
  float2 cs = tab[(s << 6) + fi];
  float y0 = x0 * cs.x - x1 * cs.y;
  float y1 = x0 * cs.y + x1 * cs.x;
  ushort2 ov; ov.x = f2bf(y0); ov.y = f2bf(y1);
  *(ushort2*)(outb + (long)r * 2560 + 512 + 2 * pp) = ov;
  if (WF32) *(float2*)(outf + ((long)r << 11) + 2 * pp) = make_float2(y0, y1);
}

// ---------- softmax over rows of 2048, scale 1/12, fp32 in, bf16 out ----------
__global__ void __launch_bounds__(256) softmax_k(const float* __restrict__ sc,
                                                 uint16_t* __restrict__ attn) {
  __shared__ float sm[9];
  const float* x = sc + ((long)blockIdx.x << 11);
  const int base = threadIdx.x * 8;
  float v[8];
  *(float4*)&v[0] = *(const float4*)&x[base];
  *(float4*)&v[4] = *(const float4*)&x[base + 4];
  const float inv = 1.0f / 12.0f;
  float m = -1e30f;
#pragma unroll
  for (int i = 0; i < 8; i++) { v[i] *= inv; m = fmaxf(m, v[i]); }
#pragma unroll
  for (int o = 32; o; o >>= 1) m = fmaxf(m, __shfl_down(m, o));
  if ((threadIdx.x & 63) == 0) sm[threadIdx.x >> 6] = m;
  __syncthreads();
  if (threadIdx.x == 0)
    sm[8] = fmaxf(fmaxf(sm[0], sm[1]), fmaxf(sm[2], sm[3]));
  __syncthreads();
  m = sm[8];
  __syncthreads();
  float ss = 0.f;
#pragma unroll
  for (int i = 0; i < 8; i++) { v[i] = __expf(v[i] - m); ss += v[i]; }
#pragma unroll
  for (int o = 32; o; o >>= 1) ss += __shfl_down(ss, o);
  if ((threadIdx.x & 63) == 0) sm[threadIdx.x >> 6] = ss;
  __syncthreads();
  if (threadIdx.x == 0) sm[8] = 1.0f / (sm[0] + sm[1] + sm[2] + sm[3]);
  __syncthreads();
  const float r = sm[8];
  ushort4 o1, o2;
  o1.x = f2bf(v[0] * r); o1.y = f2bf(v[1] * r); o1.z = f2bf(v[2] * r); o1.w = f2bf(v[3] * r);
  o2.x = f2bf(v[4] * r); o2.y = f2bf(v[5] * r); o2.z = f2bf(v[6] * r); o2.w = f2bf(v[7] * r);
  uint16_t* dst = attn + ((long)blockIdx.x << 11) + base;
  *(ushort4*)dst = o1;
  *(ushort4*)(dst + 4) = o2;
}

// ---------- orchestration ----------
extern "C" void kernel_launch(void* const* d_in, const int* in_sizes, int n_in,
                              void* d_out, int out_size, void* d_ws, size_t ws_size,
                              hipStream_t stream) {
  (void)in_sizes; (void)n_in; (void)out_size; (void)ws_size;
  const float* h    = (const float*)d_in[0];
  const float* wdkv = (const float*)d_in[1];
  const float* wuk  = (const float*)d_in[2];
  const float* wuv  = (const float*)d_in[3];
  const float* wdq  = (const float*)d_in[4];
  const float* wuq  = (const float*)d_in[5];
  const float* wkr  = (const float*)d_in[6];
  const float* wqr  = (const float*)d_in[7];
  const float* wo   = (const float*)d_in[8];
  const float* g1   = (const float*)d_in[9];
  const float* g2   = (const float*)d_in[10];
  const float* g3   = (const float*)d_in[11];

  float* u_out   = (float*)d_out;                 // (4,2048,2048)
  float* ckv_out = u_out + 16777216L;             // (4,2048,512)
  float* kr_out  = ckv_out + 4194304L;            // (4,2048,2048)

  char* p = (char*)d_ws;
  auto alloc = [&](size_t bytes) -> void* {
    void* q = (void*)p; p += (bytes + 255) & ~(size_t)255; return q;
  };
  uint16_t* hb     = (uint16_t*)alloc(16777216ULL * 2);  // h bf16
  uint16_t* wcat   = (uint16_t*)alloc(3145728ULL * 2);   // (1536,2048) [wdq;wdkv;Bqt]
  uint16_t* wqr_b  = (uint16_t*)alloc(1048576ULL * 2);
  uint16_t* wkr_b  = (uint16_t*)alloc(4194304ULL * 2);
  uint16_t* wo_b   = (uint16_t*)alloc(4194304ULL * 2);
  uint16_t* wukT   = (uint16_t*)alloc(1048576ULL * 2);   // (512,2048)
  uint16_t* wuqT   = (uint16_t*)alloc(1048576ULL * 2);
  uint16_t* wuvT   = (uint16_t*)alloc(1048576ULL * 2);
  uint16_t* wdqT   = (uint16_t*)alloc(1048576ULL * 2);   // (2048,512)
  uint16_t* T1t    = (uint16_t*)alloc(262144ULL * 2);    // (512,512)
  uint16_t* awoT   = (uint16_t*)alloc(1048576ULL * 2);   // absorbed_w_o^T (2048,512)
  uint16_t* cq_b   = (uint16_t*)alloc(4194304ULL * 2);   // (8192,512)
  uint16_t* catq   = (uint16_t*)alloc(20971520ULL * 2);  // (8192,2560) [aq|qr]
  uint16_t* catk   = (uint16_t*)alloc(20971520ULL * 2);  // (8192,2560) [ckv|kr]
  uint16_t* ckvT   = (uint16_t*)alloc(4194304ULL * 2);   // 4 x (512,2048)
  uint16_t* o_b    = (uint16_t*)alloc(4194304ULL * 2);   // (8192,512)
  float2*   rtab   = (float2*)alloc(131072ULL * 8);      // 2048x64 (cos,sin)
  float*    tmpS   = (float*)alloc(4194304ULL * 4);      // (8192,512) fp32 cq-pre
  float*    tmpS2  = (float*)alloc(4194304ULL * 4);      // (8192,512) fp32 ckv-pre
  float*    tmpB   = (float*)alloc(16777216ULL * 4);     // (8192,2048) fp32 scores
  uint16_t* tmpBb  = (uint16_t*)tmpB;                    // alias: (8192,2048) bf16
  uint16_t* attn   = catq;  // alias: catq dead after scores GEMM

  uint16_t* wdq_b  = wcat;                  // rows 0-511
  uint16_t* wdkv_b = wcat + 1048576;        // rows 512-1023
  uint16_t* Bqt    = wcat + 2097152;        // rows 1024-1535 (absorbed_w_q^T)

  const dim3 b256(256);
  const dim3 b512(512);
  const dim3 tb(32, 8);

  // dtype converts
  cvt_k<<<dim3(16384), b256, 0, stream>>>(h, hb, 16777216L);
  cvt_k<<<dim3(1024),  b256, 0, stream>>>(wdq, wdq_b, 1048576L);
  cvt_k<<<dim3(1024),  b256, 0, stream>>>(wdkv, wdkv_b, 1048576L);
  cvt_k<<<dim3(1024),  b256, 0, stream>>>(wqr, wqr_b, 1048576L);
  cvt_k<<<dim3(4096),  b256, 0, stream>>>(wkr, wkr_b, 4194304L);
  cvt_k<<<dim3(4096),  b256, 0, stream>>>(wo, wo_b, 4194304L);
  // weight transposes (fp32 -> bf16)
  transpose_to_bf16<float><<<dim3(16, 64, 1), tb, 0, stream>>>(wuk, wukT, 512, 2048, 0, 0);
  transpose_to_bf16<float><<<dim3(16, 64, 1), tb, 0, stream>>>(wuq, wuqT, 512, 2048, 0, 0);
  transpose_to_bf16<float><<<dim3(16, 64, 1), tb, 0, stream>>>(wuv, wuvT, 512, 2048, 0, 0);
  transpose_to_bf16<float><<<dim3(64, 16, 1), tb, 0, stream>>>(wdq, wdqT, 2048, 512, 0, 0);
  rope_table<<<dim3(512), b256, 0, stream>>>(rtab);

  // absorbed weights (small — legacy kernel)
  gemm_bt<1><<<dim3(4, 4, 1), b256, 0, stream>>>(wukT, wuqT, T1t, 2048, 2048, 2048, 512, 0, 0, 0);
  gemm_bt<1><<<dim3(4, 16, 1), b256, 0, stream>>>(T1t, wdqT, Bqt, 512, 512, 512, 2048, 0, 0, 0);
  gemm_bt<1><<<dim3(16, 4, 1), b256, 0, stream>>>(wo_b, wuvT, awoT, 2048, 2048, 2048, 512, 0, 0, 0);

  // fused: [cq-pre | ckv-pre | aq] = h @ [wdq; wdkv; Bqt]^T  (N=1536, K=2048)
  gemm256sq<2><<<dim3(32, 6, 1), b512, 0, stream>>>(
      hb, wcat, tmpS, tmpS2, catq, 2048, 2048, 2048, 0, 0, 0, 0);
  // cq = rmsnorm(cq-pre, g1)
  rmsnorm_k<2, float><<<dim3(8192), b256, 0, stream>>>(tmpS, g1, nullptr, cq_b, 512);
  // qr = rope(cq @ wqr^T) -> catq[:,512:]
  gemm256sq<1><<<dim3(32, 8, 1), b512, 0, stream>>>(
      cq_b, wqr_b, tmpBb, nullptr, nullptr, 512, 512, 512, 2048, 0, 0, 0);
  rope_k<false><<<dim3(32768), b256, 0, stream>>>(tmpBb, catq, nullptr, rtab);
  // ckv = rmsnorm(ckv-pre, g2) -> ckv_out (fp32) + catk[:,0:512] (bf16)
  rmsnorm_k<2, float><<<dim3(8192), b256, 0, stream>>>(tmpS2, g2, ckv_out, catk, 2560);
  // ckvT: 4 x (512,2048) from catk cols 0..511
  transpose_to_bf16<uint16_t><<<dim3(16, 64, 4), tb, 0, stream>>>(
      catk, ckvT, 2560, 2048, 2048L * 2560, 512L * 2048);
  // kr = rope(h @ wkr^T) -> kr_out (fp32) + catk[:,512:]
  gemm256sq<1><<<dim3(32, 8, 1), b512, 0, stream>>>(
      hb, wkr_b, tmpBb, nullptr, nullptr, 2048, 2048, 2048, 2048, 0, 0, 0);
  rope_k<true><<<dim3(32768), b256, 0, stream>>>(tmpBb, catk, kr_out, rtab);
  // scores[b] = catq_b @ catk_b^T (K=2560) -> tmpB fp32
  gemm256sq<0><<<dim3(8, 8, 4), b512, 0, stream>>>(
      catq, catk, tmpB, nullptr, nullptr, 2560, 2560, 2560, 2048,
      5242880L, 5242880L, 4194304L);
  // softmax(scores/12) -> attn bf16 (aliases catq)
  softmax_k<<<dim3(8192), b256, 0, stream>>>(tmpB, attn);
  // o[b] = attn_b @ ckv_b (via ckvT) -> o_b bf16
  gemm256<1><<<dim3(8, 4, 4), b512, 0, stream>>>(
      attn, ckvT, o_b, 2048, 2048, 2048, 512, 4194304L, 1048576L, 1048576L);
  // u = rmsnorm(o @ absorbed_w_o, g3) -> u_out
  gemm256sq<1><<<dim3(32, 8, 1), b512, 0, stream>>>(
      o_b, awoT, tmpBb, nullptr, nullptr, 512, 512, 512, 2048, 0, 0, 0);
  rmsnorm_k<8, uint16_t><<<dim3(8192), b256, 0, stream>>>(tmpBb, g3, u_out, nullptr, 0);
}

// Round 6
// 560.230 us; speedup vs baseline: 1.2861x; 1.0233x over previous
//
#include <hip/hip_runtime.h>
#include <stdint.h>

// ---------- small helpers ----------
typedef __attribute__((ext_vector_type(8))) short bf16x8;
typedef __attribute__((ext_vector_type(8))) unsigned short u16x8;
typedef __attribute__((ext_vector_type(4))) float floatx4;

__device__ __forceinline__ uint16_t f2bf(float f) {
  union { float f; uint32_t u; } v; v.f = f;
  uint32_t r = v.u + 0x7fffu + ((v.u >> 16) & 1u);
  return (uint16_t)(r >> 16);
}
__device__ __forceinline__ float bf2f(uint16_t b) {
  union { uint32_t u; float f; } v; v.u = ((uint32_t)b) << 16;
  return v.f;
}
__device__ __forceinline__ float ld_as_float(float v) { return v; }
__device__ __forceinline__ float ld_as_float(uint16_t v) { return bf2f(v); }

__device__ __forceinline__ void mfma16(floatx4& d, bf16x8 a, bf16x8 b) {
  asm("v_mfma_f32_16x16x32_bf16 %0, %1, %2, %0" : "+v"(d) : "v"(a), "v"(b));
}

#define FENCE() asm volatile("" ::: "memory")
#define SCHED() __builtin_amdgcn_sched_barrier(0)
#define SBAR()                                  \
  do {                                          \
    FENCE();                                    \
    __builtin_amdgcn_sched_barrier(0);          \
    __builtin_amdgcn_s_barrier();               \
    __builtin_amdgcn_sched_barrier(0);          \
    FENCE();                                    \
  } while (0)

// ================= v3 GEMM: 256x256, BK=32, 4-slot ring, 1 barrier/tile =================
// C(M,N) = A(M,K) @ B(N,K)^T, bf16 in, fp32 acc. Requires K % 32 == 0, K >= 96.
// 512 threads = 8 waves (2M x 4N), per-wave 128x64 output (8x4 frags).
// LDS: 4 slots x (A 16KB + B 16KB) = 128 KB. Tile t lives in slot t%4.
// Prefetch depth 3 tiles: while computing t, stage t+3 into slot (t+3)%4
// (== slot of t-1, whose reads drained before this tile's barrier -> WAR safe).
// Per tile: vmcnt(8) [own t loads landed; t+1,t+2 in flight] -> s_barrier
// [all waves' loads visible] -> 12 ds_reads + staging issue, lgkmcnt(4),
// 16 MFMA, lgkmcnt(0), 16 MFMA. No intra-tile barriers: LDS service overlaps MFMA.
// BK=32 rows are 64B: naturally bank-conflict-free (8 lanes per 16B slot). No swizzle.
// MODE 0: fp32 C0; 1: bf16 C0; 2: routed (cols 0-511 bf16 C0 ld512 cq-pre,
//   512-1023 fp32 C1 ld512 ckv-pre, 1024-1535 bf16 C2 ld2560 aq);
// 3: bf16 C0 with fused *(1/12) scale.
template<int MODE>
__global__ void __launch_bounds__(512, 1) gemm256v3(
    const uint16_t* __restrict__ A, const uint16_t* __restrict__ B,
    void* __restrict__ C0v, void* __restrict__ C1v, void* __restrict__ C2v,
    int K, int lda, int ldb, int ldc,
    long sA, long sB, long sC)
{
  __shared__ __attribute__((aligned(16))) char lds[131072];
  const int tid = threadIdx.x;
  const int w = tid >> 6, l = tid & 63;
  const int wm = w >> 2, wn = w & 3;

  // XCD-aware swizzle over the (x,y) plane (all grids here have nwg % 8 == 0)
  const int gx = gridDim.x;
  const int nwg = gx * gridDim.y;
  int id = blockIdx.y * gx + blockIdx.x;
  if ((nwg & 7) == 0) id = (id & 7) * (nwg >> 3) + (id >> 3);
  const long bm = (long)(id % gx) * 256;
  const long bn = (long)(id / gx) * 256;
  A += (long)blockIdx.z * sA;
  B += (long)blockIdx.z * sB;

  // staging: one global_load_lds covers 128 rows x 64B (8 waves x 16 rows).
  // lane: row = w*16 + (l>>2) (+128*r), col = (l&3)*8 elems. LDS dest linear.
  const uint16_t* gA = A + (bm + w * 16 + (l >> 2)) * (long)lda + (l & 3) * 8;
  const uint16_t* gB = B + (bn + w * 16 + (l >> 2)) * (long)ldb + (l & 3) * 8;
  const int ldsw = w * 1024;

#define STG_A3(slot, k0, r)                                                    \
  __builtin_amdgcn_global_load_lds(gA + (k0) + (long)(r) * 128 * lda,          \
      (uint16_t*)(lds + (slot) * 32768 + (r) * 8192 + ldsw), 16, 0, 0)
#define STG_B3(slot, k0, r)                                                    \
  __builtin_amdgcn_global_load_lds(gB + (k0) + (long)(r) * 128 * ldb,          \
      (uint16_t*)(lds + (slot) * 32768 + 16384 + (r) * 8192 + ldsw), 16, 0, 0)

  // fragment read geometry: row stride 64B, lane reads 16B at kb=(l>>4)*16
  const int lr = l & 15;
  const int kb = (l >> 4) * 16;
  const int aoff = (wm * 128 + lr) * 64 + kb;
  const int boff = 16384 + (wn * 64 + lr) * 64 + kb;

  floatx4 acc[8][4];
#pragma unroll
  for (int i = 0; i < 8; i++)
#pragma unroll
    for (int j = 0; j < 4; j++) acc[i][j] = (floatx4){0.f, 0.f, 0.f, 0.f};

  const int nt = K >> 5;  // assumes nt >= 3
  // prologue: stage tiles 0,1,2 (FIFO order matches in-loop per-tile order A,A,B,B)
#pragma unroll
  for (int tt = 0; tt < 3; tt++) {
    STG_A3(tt, tt * 32, 0); STG_A3(tt, tt * 32, 1);
    STG_B3(tt, tt * 32, 0); STG_B3(tt, tt * 32, 1);
  }

  for (int t = 0; t < nt; t++) {
    const char* Ls = lds + (t & 3) * 32768;
    // own tile-t loads retired (8 newer stay in flight), then cross-wave fence
    if (t + 2 < nt) asm volatile("s_waitcnt vmcnt(8)" ::: "memory");
    else            asm volatile("s_waitcnt vmcnt(0)" ::: "memory");
    SBAR();

    bf16x8 Bf[4], Af0[4], Af1[4];
#pragma unroll
    for (int j = 0; j < 4; j++) Bf[j] = *(const bf16x8*)(Ls + boff + j * 1024);
#pragma unroll
    for (int i = 0; i < 4; i++) Af0[i] = *(const bf16x8*)(Ls + aoff + i * 1024);
    SCHED();  // pin DS issue count: first 8 = Bf + Af0

    const long pk0 = (long)(t + 3) << 5;
    const int pslot = (t + 3) & 3;
    const bool pf = (t + 3 < nt);
    if (pf) { STG_A3(pslot, pk0, 0); STG_A3(pslot, pk0, 1); }

#pragma unroll
    for (int i = 0; i < 4; i++) Af1[i] = *(const bf16x8*)(Ls + aoff + (4 + i) * 1024);
    SCHED();

    asm volatile("s_waitcnt lgkmcnt(4)" ::: "memory");  // Bf+Af0 landed; Af1 drains under MFMA
    SCHED();
    __builtin_amdgcn_s_setprio(1);
#pragma unroll
    for (int i = 0; i < 4; i++)
#pragma unroll
      for (int j = 0; j < 4; j++) mfma16(acc[i][j], Af0[i], Bf[j]);
    __builtin_amdgcn_s_setprio(0);
    SCHED();

    if (pf) { STG_B3(pslot, pk0, 0); STG_B3(pslot, pk0, 1); }

    asm volatile("s_waitcnt lgkmcnt(0)" ::: "memory");
    SCHED();
    __builtin_amdgcn_s_setprio(1);
#pragma unroll
    for (int i = 0; i < 4; i++)
#pragma unroll
      for (int j = 0; j < 4; j++) mfma16(acc[4 + i][j], Af1[i], Bf[j]);
    __builtin_amdgcn_s_setprio(0);
    SCHED();
  }
#undef STG_A3
#undef STG_B3

  const long crow = bm + wm * 128 + ((l >> 4) * 4);
  const long ccol = bn + wn * 64 + (l & 15);
  if constexpr (MODE == 0) {
    float* C = (float*)C0v + (long)blockIdx.z * sC;
#pragma unroll
    for (int i = 0; i < 8; i++)
#pragma unroll
      for (int r = 0; r < 4; r++) {
        long row = crow + i * 16 + r;
#pragma unroll
        for (int j = 0; j < 4; j++) C[row * (long)ldc + ccol + j * 16] = acc[i][j][r];
      }
  } else if constexpr (MODE == 1) {
    uint16_t* C = (uint16_t*)C0v + (long)blockIdx.z * sC;
#pragma unroll
    for (int i = 0; i < 8; i++)
#pragma unroll
      for (int r = 0; r < 4; r++) {
        long row = crow + i * 16 + r;
#pragma unroll
        for (int j = 0; j < 4; j++) C[row * (long)ldc + ccol + j * 16] = f2bf(acc[i][j][r]);
      }
  } else if constexpr (MODE == 3) {
    const float s = 1.0f / 12.0f;
    uint16_t* C = (uint16_t*)C0v + (long)blockIdx.z * sC;
#pragma unroll
    for (int i = 0; i < 8; i++)
#pragma unroll
      for (int r = 0; r < 4; r++) {
        long row = crow + i * 16 + r;
#pragma unroll
        for (int j = 0; j < 4; j++) C[row * (long)ldc + ccol + j * 16] = f2bf(acc[i][j][r] * s);
      }
  } else {
    if (bn < 512) {
      uint16_t* C = (uint16_t*)C0v;
#pragma unroll
      for (int i = 0; i < 8; i++)
#pragma unroll
        for (int r = 0; r < 4; r++) {
          long row = crow + i * 16 + r;
#pragma unroll
          for (int j = 0; j < 4; j++) C[row * 512 + ccol + j * 16] = f2bf(acc[i][j][r]);
        }
    } else if (bn < 1024) {
      float* C = (float*)C1v;
      const long cc = ccol - 512;
#pragma unroll
      for (int i = 0; i < 8; i++)
#pragma unroll
        for (int r = 0; r < 4; r++) {
          long row = crow + i * 16 + r;
#pragma unroll
          for (int j = 0; j < 4; j++) C[row * 512 + cc + j * 16] = acc[i][j][r];
        }
    } else {
      uint16_t* C = (uint16_t*)C2v;
      const long cc = ccol - 1024;
#pragma unroll
      for (int i = 0; i < 8; i++)
#pragma unroll
        for (int r = 0; r < 4; r++) {
          long row = crow + i * 16 + r;
#pragma unroll
          for (int j = 0; j < 4; j++) C[row * 2560 + cc + j * 16] = f2bf(acc[i][j][r]);
        }
    }
  }
}

// ================= 256x128 pipelined GEMM (for the small-N o GEMM) =================
template<int OUTB>
__global__ void __launch_bounds__(512, 2) gemm256(
    const uint16_t* __restrict__ A, const uint16_t* __restrict__ B,
    void* __restrict__ Cv, int K, int lda, int ldb, int ldc,
    long sA, long sB, long sC)
{
  __shared__ __attribute__((aligned(16))) char lds[147456];
  const int tid = threadIdx.x;
  const int w = tid >> 6, l = tid & 63;
  const int wm = w >> 1, wn = w & 1;

  const int gx = gridDim.x;
  const int nwg = gx * gridDim.y;
  int id = blockIdx.y * gx + blockIdx.x;
  if ((nwg & 7) == 0) id = (id & 7) * (nwg >> 3) + (id >> 3);
  const long bm = (long)(id % gx) * 256;
  const long bn = (long)(id / gx) * 128;
  A += (long)blockIdx.z * sA;
  B += (long)blockIdx.z * sB;

  const int sr = l >> 3;
  const int sc = l & 7;
  const int scol = ((sc ^ sr) << 3);
  const uint16_t* gA = A + (bm + w * 8 + sr) * (long)lda + scol;
  const uint16_t* gB = B + (bn + w * 8 + sr) * (long)ldb + scol;
  const int ldsw = w * 1024;

#define STAGE_A(bufi, k0, r)                                                     \
  __builtin_amdgcn_global_load_lds(gA + (k0) + (long)(r) * 64 * lda,             \
      (uint16_t*)(lds + (bufi) * 49152 + (r) * 8192 + ldsw), 16, 0, 0)
#define STAGE_B(bufi, k0, r)                                                     \
  __builtin_amdgcn_global_load_lds(gB + (k0) + (long)(r) * 64 * ldb,             \
      (uint16_t*)(lds + (bufi) * 49152 + 32768 + (r) * 8192 + ldsw), 16, 0, 0)

  const int lr = l & 15;
  const int kk = (l >> 4) << 4;
  const int msk = (l & 7) << 4;
  const int ko0 = kk ^ msk;
  const int ko1 = (64 + kk) ^ msk;
  const int arow = (wm * 64 + lr) * 128;
  const int brow = (wn * 64 + lr) * 128;

  floatx4 acc[4][4];
#pragma unroll
  for (int i = 0; i < 4; i++)
#pragma unroll
    for (int j = 0; j < 4; j++) acc[i][j] = (floatx4){0.f, 0.f, 0.f, 0.f};

  const int nt = K >> 6;
#pragma unroll
  for (int r = 0; r < 4; r++) STAGE_A(0, 0, r);
#pragma unroll
  for (int r = 0; r < 2; r++) STAGE_B(0, 0, r);
#pragma unroll
  for (int r = 0; r < 4; r++) STAGE_A(1, 64, r);
#pragma unroll
  for (int r = 0; r < 2; r++) STAGE_B(1, 64, r);
  asm volatile("s_waitcnt vmcnt(6)" ::: "memory");
  SBAR();

  bf16x8 af0[4], bf0[4], af1[4], bf1[4];
  {
    const char* LA = lds + arow;
    const char* LB = lds + 32768 + brow;
#pragma unroll
    for (int i = 0; i < 4; i++) af0[i] = *(const bf16x8*)(LA + i * 2048 + ko0);
#pragma unroll
    for (int j = 0; j < 4; j++) bf0[j] = *(const bf16x8*)(LB + j * 2048 + ko0);
  }

  for (int t = 0; t < nt; t++) {
    const int buf = t % 3;
    const int pbuf = (t + 2) % 3;
    const long pk0 = (long)(t + 2) << 6;
    const char* LA = lds + buf * 49152 + arow;
    const char* LB = lds + buf * 49152 + 32768 + brow;
    const bool pf = (t + 2 < nt);

    if (pf) { STAGE_A(pbuf, pk0, 0); STAGE_A(pbuf, pk0, 1); STAGE_B(pbuf, pk0, 0); }
#pragma unroll
    for (int i = 0; i < 4; i++) af1[i] = *(const bf16x8*)(LA + i * 2048 + ko1);
#pragma unroll
    for (int j = 0; j < 4; j++) bf1[j] = *(const bf16x8*)(LB + j * 2048 + ko1);
    SCHED();
    __builtin_amdgcn_s_setprio(1);
#pragma unroll
    for (int i = 0; i < 4; i++)
#pragma unroll
      for (int j = 0; j < 4; j++) mfma16(acc[i][j], af0[i], bf0[j]);
    __builtin_amdgcn_s_setprio(0);
    SCHED();

    if (pf) { STAGE_A(pbuf, pk0, 2); STAGE_A(pbuf, pk0, 3); STAGE_B(pbuf, pk0, 1); }
    if (t < nt - 2) asm volatile("s_waitcnt vmcnt(6) lgkmcnt(0)" ::: "memory");
    else            asm volatile("s_waitcnt vmcnt(0) lgkmcnt(0)" ::: "memory");
    SBAR();
    if (t < nt - 1) {
      const char* LAn = lds + ((t + 1) % 3) * 49152 + arow;
      const char* LBn = lds + ((t + 1) % 3) * 49152 + 32768 + brow;
#pragma unroll
      for (int i = 0; i < 4; i++) af0[i] = *(const bf16x8*)(LAn + i * 2048 + ko0);
#pragma unroll
      for (int j = 0; j < 4; j++) bf0[j] = *(const bf16x8*)(LBn + j * 2048 + ko0);
    }
    SCHED();
    __builtin_amdgcn_s_setprio(1);
#pragma unroll
    for (int i = 0; i < 4; i++)
#pragma unroll
      for (int j = 0; j < 4; j++) mfma16(acc[i][j], af1[i], bf1[j]);
    __builtin_amdgcn_s_setprio(0);
    SCHED();
  }
#undef STAGE_A
#undef STAGE_B

  const long crow = bm + wm * 64 + ((l >> 4) * 4);
  const long ccol = bn + wn * 64 + (l & 15);
  if constexpr (OUTB == 0) {
    float* C = (float*)Cv + (long)blockIdx.z * sC;
#pragma unroll
    for (int i = 0; i < 4; i++)
#pragma unroll
      for (int r = 0; r < 4; r++) {
        long row = crow + i * 16 + r;
#pragma unroll
        for (int j = 0; j < 4; j++) C[row * (long)ldc + ccol + j * 16] = acc[i][j][r];
      }
  } else {
    uint16_t* C = (uint16_t*)Cv + (long)blockIdx.z * sC;
#pragma unroll
    for (int i = 0; i < 4; i++)
#pragma unroll
      for (int r = 0; r < 4; r++) {
        long row = crow + i * 16 + r;
#pragma unroll
        for (int j = 0; j < 4; j++) C[row * (long)ldc + ccol + j * 16] = f2bf(acc[i][j][r]);
      }
  }
}

// ================= legacy 128x128 GEMM (small weight-prep matmuls) =================
template<int OUTB>
__global__ void __launch_bounds__(256) gemm_bt(
    const uint16_t* __restrict__ A, const uint16_t* __restrict__ B,
    void* __restrict__ Cv, int K, int lda, int ldb, int ldc,
    long sA, long sB, long sC)
{
  __shared__ alignas(16) uint16_t As[4096];
  __shared__ alignas(16) uint16_t Bs[4096];
  const int tid = threadIdx.x;
  const int w = tid >> 6, l = tid & 63;
  const int wr = w >> 1, wc = w & 1;
  const long bm = (long)blockIdx.x * 128, bn = (long)blockIdx.y * 128;
  A += (long)blockIdx.z * sA;
  B += (long)blockIdx.z * sB;

  const uint16_t* ga0 = A + (bm + w * 16 + (l >> 2)) * (long)lda + (l & 3) * 8;
  const uint16_t* ga1 = ga0 + 64L * lda;
  const uint16_t* gb0 = B + (bn + w * 16 + (l >> 2)) * (long)ldb + (l & 3) * 8;
  const uint16_t* gb1 = gb0 + 64L * ldb;
  uint16_t* la0 = &As[w * 512];
  uint16_t* la1 = &As[2048 + w * 512];
  uint16_t* lb0 = &Bs[w * 512];
  uint16_t* lb1 = &Bs[2048 + w * 512];

  floatx4 acc[4][4];
#pragma unroll
  for (int i = 0; i < 4; i++)
#pragma unroll
    for (int j = 0; j < 4; j++) acc[i][j] = (floatx4){0.f, 0.f, 0.f, 0.f};

  const int rA = (wr * 64 + (l & 15)) * 32 + (l >> 4) * 8;
  const int rB = (wc * 64 + (l & 15)) * 32 + (l >> 4) * 8;

  for (int k0 = 0; k0 < K; k0 += 32) {
    __builtin_amdgcn_global_load_lds(ga0, la0, 16, 0, 0);
    __builtin_amdgcn_global_load_lds(ga1, la1, 16, 0, 0);
    __builtin_amdgcn_global_load_lds(gb0, lb0, 16, 0, 0);
    __builtin_amdgcn_global_load_lds(gb1, lb1, 16, 0, 0);
    ga0 += 32; ga1 += 32; gb0 += 32; gb1 += 32;
    __syncthreads();
    bf16x8 af[4], bfr[4];
#pragma unroll
    for (int i = 0; i < 4; i++) af[i] = *(const bf16x8*)&As[rA + i * 512];
#pragma unroll
    for (int j = 0; j < 4; j++) bfr[j] = *(const bf16x8*)&Bs[rB + j * 512];
#pragma unroll
    for (int i = 0; i < 4; i++)
#pragma unroll
      for (int j = 0; j < 4; j++) mfma16(acc[i][j], af[i], bfr[j]);
    __syncthreads();
  }

  const long crow = bm + wr * 64 + ((l >> 4) * 4);
  const long ccol = bn + wc * 64 + (l & 15);
  if constexpr (OUTB == 0) {
    float* C = (float*)Cv + (long)blockIdx.z * sC;
#pragma unroll
    for (int i = 0; i < 4; i++)
#pragma unroll
      for (int r = 0; r < 4; r++) {
        long row = crow + i * 16 + r;
#pragma unroll
        for (int j = 0; j < 4; j++) C[row * (long)ldc + ccol + j * 16] = acc[i][j][r];
      }
  } else {
    uint16_t* C = (uint16_t*)Cv + (long)blockIdx.z * sC;
#pragma unroll
    for (int i = 0; i < 4; i++)
#pragma unroll
      for (int r = 0; r < 4; r++) {
        long row = crow + i * 16 + r;
#pragma unroll
        for (int j = 0; j < 4; j++) C[row * (long)ldc + ccol + j * 16] = f2bf(acc[i][j][r]);
      }
  }
}

// ---------- fp32 -> bf16 convert (h) ----------
__global__ void __launch_bounds__(256) cvt_k(const float* __restrict__ in,
                                             uint16_t* __restrict__ out, long n) {
  long i = ((long)blockIdx.x * 256 + threadIdx.x) * 4;
  if (i >= n) return;
  float4 v = *(const float4*)(in + i);
  ushort4 o; o.x = f2bf(v.x); o.y = f2bf(v.y); o.z = f2bf(v.z); o.w = f2bf(v.w);
  *(ushort4*)(out + i) = o;
}

// ---------- fused small-weight converts + rope table (one launch) ----------
__global__ void __launch_bounds__(256) prep_small(
    const float* __restrict__ wdq, const float* __restrict__ wdkv,
    const float* __restrict__ wqr, const float* __restrict__ wkr,
    const float* __restrict__ wo,
    uint16_t* __restrict__ wdq_b, uint16_t* __restrict__ wdkv_b,
    uint16_t* __restrict__ wqr_b, uint16_t* __restrict__ wkr_b,
    uint16_t* __restrict__ wo_b, float2* __restrict__ rtab)
{
  const int b = blockIdx.x;
  if (b < 11264) {
    const float* src; uint16_t* dst; long off;
    if (b < 1024)      { src = wdq;  dst = wdq_b;  off = b; }
    else if (b < 2048) { src = wdkv; dst = wdkv_b; off = b - 1024; }
    else if (b < 3072) { src = wqr;  dst = wqr_b;  off = b - 2048; }
    else if (b < 7168) { src = wkr;  dst = wkr_b;  off = b - 3072; }
    else               { src = wo;   dst = wo_b;   off = b - 7168; }
    long i = (off * 256 + threadIdx.x) * 4;
    float4 v = *(const float4*)(src + i);
    ushort4 o; o.x = f2bf(v.x); o.y = f2bf(v.y); o.z = f2bf(v.z); o.w = f2bf(v.w);
    *(ushort4*)(dst + i) = o;
  } else {
    int idx = (b - 11264) * 256 + threadIdx.x;  // 2048*64
    int s = idx >> 6, fi = idx & 63;
    float f = powf(10000.0f, -(float)fi * (1.0f / 64.0f));
    float ang = (float)s * f;
    rtab[idx] = make_float2(cosf(ang), sinf(ang));
  }
}

// ---------- transpose (R,Cc) -> (Cc,R), bf16 out ----------
template<typename TIN>
__global__ void __launch_bounds__(256) transpose_to_bf16(
    const TIN* __restrict__ in, uint16_t* __restrict__ out,
    int ld_in, int ld_out, long sIn, long sOut)
{
  __shared__ float tile[32][33];
  in += (long)blockIdx.z * sIn;
  out += (long)blockIdx.z * sOut;
  const int rb = blockIdx.y * 32, cb = blockIdx.x * 32;
#pragma unroll
  for (int i = 0; i < 32; i += 8)
    tile[threadIdx.y + i][threadIdx.x] =
        ld_as_float(in[(long)(rb + threadIdx.y + i) * ld_in + cb + threadIdx.x]);
  __syncthreads();
#pragma unroll
  for (int i = 0; i < 32; i += 8)
    out[(long)(cb + threadIdx.y + i) * ld_out + rb + threadIdx.x] =
        f2bf(tile[threadIdx.x][threadIdx.y + i]);
}

// ---------- rmsnorm: one block per row; DIM = PT*256 ----------
template<int PT, typename TIN>
__global__ void __launch_bounds__(256) rmsnorm_k(
    const TIN* __restrict__ in, const float* __restrict__ g,
    float* __restrict__ out_f, uint16_t* __restrict__ out_b, int ld_b)
{
  constexpr int DIM = PT * 256;
  __shared__ float sm[9];
  const TIN* x = in + (long)blockIdx.x * DIM;
  const int base = threadIdx.x * PT;
  float v[PT];
  if constexpr (sizeof(TIN) == 2) {
    if constexpr (PT >= 8) {
#pragma unroll
      for (int i = 0; i < PT; i += 8) {
        u16x8 t = *(const u16x8*)&x[base + i];
#pragma unroll
        for (int q = 0; q < 8; q++) v[i + q] = bf2f(t[q]);
      }
    } else {
#pragma unroll
      for (int i = 0; i < PT; i += 2) {
        ushort2 t = *(const ushort2*)&x[base + i];
        v[i] = bf2f(t.x); v[i + 1] = bf2f(t.y);
      }
    }
  } else if constexpr (PT == 2) {
    float2 t = *(const float2*)&x[base]; v[0] = t.x; v[1] = t.y;
  } else {
#pragma unroll
    for (int i = 0; i < PT; i += 4) {
      float4 t = *(const float4*)&x[base + i];
      v[i] = t.x; v[i + 1] = t.y; v[i + 2] = t.z; v[i + 3] = t.w;
    }
  }
  float ss = 0.f;
#pragma unroll
  for (int i = 0; i < PT; i++) ss += v[i] * v[i];
#pragma unroll
  for (int o = 32; o; o >>= 1) ss += __shfl_down(ss, o);
  if ((threadIdx.x & 63) == 0) sm[threadIdx.x >> 6] = ss;
  __syncthreads();
  if (threadIdx.x == 0)
    sm[8] = rsqrtf((sm[0] + sm[1] + sm[2] + sm[3]) * (1.0f / DIM) + 1.1920929e-7f);
  __syncthreads();
  const float sc = sm[8];
#pragma unroll
  for (int i = 0; i < PT; i++) {
    float y = v[i] * sc * g[base + i];
    if (out_f) out_f[(long)blockIdx.x * DIM + base + i] = y;
    if (out_b) out_b[(long)blockIdx.x * ld_b + base + i] = f2bf(y);
  }
}

// ---------- rope apply: in bf16 (8192,2048); bf16 out -> cat[:,512:]; optional fp32 out ----------
template<bool WF32>
__global__ void __launch_bounds__(256) rope_k(
    const uint16_t* __restrict__ in, uint16_t* __restrict__ outb,
    float* __restrict__ outf, const float2* __restrict__ tab)
{
  long idx = (long)blockIdx.x * 256 + threadIdx.x;  // 8192*1024 pairs
  int r = (int)(idx >> 10);
  int pp = (int)idx & 1023;
  int s = r & 2047;
  int fi = pp & 63;
  ushort2 xv = *(const ushort2*)(in + ((long)r << 11) + 2 * pp);
  float x0 = bf2f(xv.x), x1 = bf2f(xv.y);
  float2 cs = tab[(s << 6) + fi];
  float y0 = x0 * cs.x - x1 * cs.y;
  float y1 = x0 * cs.y + x1 * cs.x;
  ushort2 ov; ov.x = f2bf(y0); ov.y = f2bf(y1);
  *(ushort2*)(outb + (long)r * 2560 + 512 + 2 * pp) = ov;
  if (WF32) *(float2*)(outf + ((long)r << 11) + 2 * pp) = make_float2(y0, y1);
}

// ---------- softmax over rows of 2048, bf16 in (pre-scaled), bf16 out ----------
__global__ void __launch_bounds__(256) softmax_k(const uint16_t* __restrict__ sc,
                                                 uint16_t* __restrict__ attn) {
  __shared__ float sm[9];
  const uint16_t* x = sc + ((long)blockIdx.x << 11);
  const int base = threadIdx.x * 8;
  float v[8];
  u16x8 t = *(const u16x8*)&x[base];
#pragma unroll
  for (int i = 0; i < 8; i++) v[i] = bf2f(t[i]);
  float m = -1e30f;
#pragma unroll
  for (int i = 0; i < 8; i++) m = fmaxf(m, v[i]);
#pragma unroll
  for (int o = 32; o; o >>= 1) m = fmaxf(m, __shfl_down(m, o));
  if ((threadIdx.x & 63) == 0) sm[threadIdx.x >> 6] = m;
  __syncthreads();
  if (threadIdx.x == 0)
    sm[8] = fmaxf(fmaxf(sm[0], sm[1]), fmaxf(sm[2], sm[3]));
  __syncthreads();
  m = sm[8];
  __syncthreads();
  float ss = 0.f;
#pragma unroll
  for (int i = 0; i < 8; i++) { v[i] = __expf(v[i] - m); ss += v[i]; }
#pragma unroll
  for (int o = 32; o; o >>= 1) ss += __shfl_down(ss, o);
  if ((threadIdx.x & 63) == 0) sm[threadIdx.x >> 6] = ss;
  __syncthreads();
  if (threadIdx.x == 0) sm[8] = 1.0f / (sm[0] + sm[1] + sm[2] + sm[3]);
  __syncthreads();
  const float r = sm[8];
  ushort4 o1, o2;
  o1.x = f2bf(v[0] * r); o1.y = f2bf(v[1] * r); o1.z = f2bf(v[2] * r); o1.w = f2bf(v[3] * r);
  o2.x = f2bf(v[4] * r); o2.y = f2bf(v[5] * r); o2.z = f2bf(v[6] * r); o2.w = f2bf(v[7] * r);
  uint16_t* dst = attn + ((long)blockIdx.x << 11) + base;
  *(ushort4*)dst = o1;
  *(ushort4*)(dst + 4) = o2;
}

// ---------- orchestration ----------
extern "C" void kernel_launch(void* const* d_in, const int* in_sizes, int n_in,
                              void* d_out, int out_size, void* d_ws, size_t ws_size,
                              hipStream_t stream) {
  (void)in_sizes; (void)n_in; (void)out_size; (void)ws_size;
  const float* h    = (const float*)d_in[0];
  const float* wdkv = (const float*)d_in[1];
  const float* wuk  = (const float*)d_in[2];
  const float* wuv  = (const float*)d_in[3];
  const float* wdq  = (const float*)d_in[4];
  const float* wuq  = (const float*)d_in[5];
  const float* wkr  = (const float*)d_in[6];
  const float* wqr  = (const float*)d_in[7];
  const float* wo   = (const float*)d_in[8];
  const float* g1   = (const float*)d_in[9];
  const float* g2   = (const float*)d_in[10];
  const float* g3   = (const float*)d_in[11];

  float* u_out   = (float*)d_out;                 // (4,2048,2048)
  float* ckv_out = u_out + 16777216L;             // (4,2048,512)
  float* kr_out  = ckv_out + 4194304L;            // (4,2048,2048)

  char* p = (char*)d_ws;
  auto alloc = [&](size_t bytes) -> void* {
    void* q = (void*)p; p += (bytes + 255) & ~(size_t)255; return q;
  };
  uint16_t* hb     = (uint16_t*)alloc(16777216ULL * 2);  // h bf16
  uint16_t* wcat   = (uint16_t*)alloc(3145728ULL * 2);   // (1536,2048) [wdq;wdkv;Bqt]
  uint16_t* wqr_b  = (uint16_t*)alloc(1048576ULL * 2);
  uint16_t* wkr_b  = (uint16_t*)alloc(4194304ULL * 2);
  uint16_t* wo_b   = (uint16_t*)alloc(4194304ULL * 2);
  uint16_t* wukT   = (uint16_t*)alloc(1048576ULL * 2);   // (512,2048)
  uint16_t* wuqT   = (uint16_t*)alloc(1048576ULL * 2);
  uint16_t* wuvT   = (uint16_t*)alloc(1048576ULL * 2);
  uint16_t* wdqT   = (uint16_t*)alloc(1048576ULL * 2);   // (2048,512)
  uint16_t* T1t    = (uint16_t*)alloc(262144ULL * 2);    // (512,512)
  uint16_t* awoT   = (uint16_t*)alloc(1048576ULL * 2);   // absorbed_w_o^T (2048,512)
  uint16_t* cqpre  = (uint16_t*)alloc(4194304ULL * 2);   // (8192,512) bf16 cq-pre
  uint16_t* cq_b   = (uint16_t*)alloc(4194304ULL * 2);   // (8192,512)
  uint16_t* catq   = (uint16_t*)alloc(20971520ULL * 2);  // (8192,2560) [aq|qr]
  uint16_t* catk   = (uint16_t*)alloc(20971520ULL * 2);  // (8192,2560) [ckv|kr]
  uint16_t* ckvT   = (uint16_t*)alloc(4194304ULL * 2);   // 4 x (512,2048)
  uint16_t* o_b    = (uint16_t*)alloc(4194304ULL * 2);   // (8192,512)
  float2*   rtab   = (float2*)alloc(131072ULL * 8);      // 2048x64 (cos,sin)
  float*    tmpS2  = (float*)alloc(4194304ULL * 4);      // (8192,512) fp32 ckv-pre
  float*    tmpB   = (float*)alloc(16777216ULL * 4);     // (8192,2048) scratch
  uint16_t* tmpBb  = (uint16_t*)tmpB;                    // alias: (8192,2048) bf16
  uint16_t* attn   = catq;  // alias: catq dead after scores GEMM

  uint16_t* wdq_b  = wcat;                  // rows 0-511
  uint16_t* wdkv_b = wcat + 1048576;        // rows 512-1023
  uint16_t* Bqt    = wcat + 2097152;        // rows 1024-1535 (absorbed_w_q^T)

  const dim3 b256(256);
  const dim3 b512(512);
  const dim3 tb(32, 8);

  // h convert + fused small-weight converts + rope table
  cvt_k<<<dim3(16384), b256, 0, stream>>>(h, hb, 16777216L);
  prep_small<<<dim3(11776), b256, 0, stream>>>(
      wdq, wdkv, wqr, wkr, wo, wdq_b, wdkv_b, wqr_b, wkr_b, wo_b, rtab);
  // weight transposes (fp32 -> bf16)
  transpose_to_bf16<float><<<dim3(16, 64, 1), tb, 0, stream>>>(wuk, wukT, 512, 2048, 0, 0);
  transpose_to_bf16<float><<<dim3(16, 64, 1), tb, 0, stream>>>(wuq, wuqT, 512, 2048, 0, 0);
  transpose_to_bf16<float><<<dim3(16, 64, 1), tb, 0, stream>>>(wuv, wuvT, 512, 2048, 0, 0);
  transpose_to_bf16<float><<<dim3(64, 16, 1), tb, 0, stream>>>(wdq, wdqT, 2048, 512, 0, 0);

  // absorbed weights (small — legacy kernel)
  gemm_bt<1><<<dim3(4, 4, 1), b256, 0, stream>>>(wukT, wuqT, T1t, 2048, 2048, 2048, 512, 0, 0, 0);
  gemm_bt<1><<<dim3(4, 16, 1), b256, 0, stream>>>(T1t, wdqT, Bqt, 512, 512, 512, 2048, 0, 0, 0);
  gemm_bt<1><<<dim3(16, 4, 1), b256, 0, stream>>>(wo_b, wuvT, awoT, 2048, 2048, 2048, 512, 0, 0, 0);

  // fused: [cq-pre(bf16) | ckv-pre(fp32) | aq(bf16)] = h @ [wdq; wdkv; Bqt]^T
  gemm256v3<2><<<dim3(32, 6, 1), b512, 0, stream>>>(
      hb, wcat, cqpre, tmpS2, catq, 2048, 2048, 2048, 0, 0, 0, 0);
  // cq = rmsnorm(cq-pre, g1)
  rmsnorm_k<2, uint16_t><<<dim3(8192), b256, 0, stream>>>(cqpre, g1, nullptr, cq_b, 512);
  // qr = rope(cq @ wqr^T) -> catq[:,512:]
  gemm256v3<1><<<dim3(32, 8, 1), b512, 0, stream>>>(
      cq_b, wqr_b, tmpBb, nullptr, nullptr, 512, 512, 512, 2048, 0, 0, 0);
  rope_k<false><<<dim3(32768), b256, 0, stream>>>(tmpBb, catq, nullptr, rtab);
  // ckv = rmsnorm(ckv-pre, g2) -> ckv_out (fp32) + catk[:,0:512] (bf16)
  rmsnorm_k<2, float><<<dim3(8192), b256, 0, stream>>>(tmpS2, g2, ckv_out, catk, 2560);
  // ckvT: 4 x (512,2048) from catk cols 0..511
  transpose_to_bf16<uint16_t><<<dim3(16, 64, 4), tb, 0, stream>>>(
      catk, ckvT, 2560, 2048, 2048L * 2560, 512L * 2048);
  // kr = rope(h @ wkr^T) -> kr_out (fp32) + catk[:,512:]
  gemm256v3<1><<<dim3(32, 8, 1), b512, 0, stream>>>(
      hb, wkr_b, tmpBb, nullptr, nullptr, 2048, 2048, 2048, 2048, 0, 0, 0);
  rope_k<true><<<dim3(32768), b256, 0, stream>>>(tmpBb, catk, kr_out, rtab);
  // scores[b]/12 = (catq_b @ catk_b^T)/12 -> tmpBb bf16 (K=2560)
  gemm256v3<3><<<dim3(8, 8, 4), b512, 0, stream>>>(
      catq, catk, tmpBb, nullptr, nullptr, 2560, 2560, 2560, 2048,
      5242880L, 5242880L, 4194304L);
  // softmax -> attn bf16 (aliases catq)
  softmax_k<<<dim3(8192), b256, 0, stream>>>(tmpBb, attn);
  // o[b] = attn_b @ ckv_b (via ckvT) -> o_b bf16
  gemm256<1><<<dim3(8, 4, 4), b512, 0, stream>>>(
      attn, ckvT, o_b, 2048, 2048, 2048, 512, 4194304L, 1048576L, 1048576L);
  // u = rmsnorm(o @ absorbed_w_o, g3) -> u_out
  gemm256v3<1><<<dim3(32, 8, 1), b512, 0, stream>>>(
      o_b, awoT, tmpBb, nullptr, nullptr, 512, 512, 512, 2048, 0, 0, 0);
  rmsnorm_k<8, uint16_t><<<dim3(8192), b256, 0, stream>>>(tmpBb, g3, u_out, nullptr, 0);
}

// Round 7
// 551.525 us; speedup vs baseline: 1.3064x; 1.0158x over previous
//
#include <hip/hip_runtime.h>
#include <stdint.h>

// ---------- small helpers ----------
typedef __attribute__((ext_vector_type(8))) short bf16x8;
typedef __attribute__((ext_vector_type(8))) unsigned short u16x8;
typedef __attribute__((ext_vector_type(4))) float floatx4;

__device__ __forceinline__ uint16_t f2bf(float f) {
  union { float f; uint32_t u; } v; v.f = f;
  uint32_t r = v.u + 0x7fffu + ((v.u >> 16) & 1u);
  return (uint16_t)(r >> 16);
}
__device__ __forceinline__ float bf2f(uint16_t b) {
  union { uint32_t u; float f; } v; v.u = ((uint32_t)b) << 16;
  return v.f;
}
__device__ __forceinline__ float ld_as_float(float v) { return v; }
__device__ __forceinline__ float ld_as_float(uint16_t v) { return bf2f(v); }

__device__ __forceinline__ void mfma16(floatx4& d, bf16x8 a, bf16x8 b) {
  asm("v_mfma_f32_16x16x32_bf16 %0, %1, %2, %0" : "+v"(d) : "v"(a), "v"(b));
}

#define FENCE() asm volatile("" ::: "memory")
#define SCHED() __builtin_amdgcn_sched_barrier(0)
#define SBAR()                                  \
  do {                                          \
    FENCE();                                    \
    __builtin_amdgcn_sched_barrier(0);          \
    __builtin_amdgcn_s_barrier();               \
    __builtin_amdgcn_sched_barrier(0);          \
    FENCE();                                    \
  } while (0)

// ================= v3 GEMM: 256x256, BK=32, 4-slot ring, 1 barrier/tile =================
// C(M,N) = A(M,K) @ B(N,K)^T, bf16 in, fp32 acc. Requires K % 32 == 0, K >= 96.
// 512 threads = 8 waves (2M x 4N), per-wave 128x64 output (8x4 frags).
// LDS: 4 slots x (A 16KB + B 16KB) = 128 KB. Tile t lives in slot t%4.
// Prefetch depth 3 tiles; per tile: vmcnt(8) -> s_barrier -> 12 ds_reads +
// staging issue, lgkmcnt(4), 16 MFMA, lgkmcnt(0), 16 MFMA.
// Chunk-XOR swizzle (both sides, same involution — rule #21):
//   write: source chunk = (l&3) ^ ((l>>3)&3)   [row within round = l>>2]
//   read:  chunk = (l>>4) ^ ((lr>>1)&3)
// -> 16 lanes/k-group spread over 8 LDS 16B slots, 2/slot = free (m136).
// MODE 0: fp32 C0; 1: bf16 C0; 2: routed (cols 0-511 bf16 C0 ld512 cq-pre,
//   512-1023 fp32 C1 ld512 ckv-pre, 1024-1535 bf16 C2 ld2560 aq);
// 3: bf16 C0 with fused *(1/12) scale.
template<int MODE>
__global__ void __launch_bounds__(512, 1) gemm256v3(
    const uint16_t* __restrict__ A, const uint16_t* __restrict__ B,
    void* __restrict__ C0v, void* __restrict__ C1v, void* __restrict__ C2v,
    int K, int lda, int ldb, int ldc,
    long sA, long sB, long sC)
{
  __shared__ __attribute__((aligned(16))) char lds[131072];
  const int tid = threadIdx.x;
  const int w = tid >> 6, l = tid & 63;
  const int wm = w >> 2, wn = w & 3;

  // XCD-aware swizzle over the (x,y) plane (all grids here have nwg % 8 == 0)
  const int gx = gridDim.x;
  const int nwg = gx * gridDim.y;
  int id = blockIdx.y * gx + blockIdx.x;
  if ((nwg & 7) == 0) id = (id & 7) * (nwg >> 3) + (id >> 3);
  const long bm = (long)(id % gx) * 256;
  const long bn = (long)(id / gx) * 256;
  A += (long)blockIdx.z * sA;
  B += (long)blockIdx.z * sB;

  // staging: one global_load_lds covers 128 rows x 64B (8 waves x 16 rows).
  // lane: row = w*16 + (l>>2) (+128*r); source chunk pre-swizzled (XOR involution).
  const int scol = (((l & 3) ^ ((l >> 3) & 3)) << 3);  // elements
  const uint16_t* gA = A + (bm + w * 16 + (l >> 2)) * (long)lda + scol;
  const uint16_t* gB = B + (bn + w * 16 + (l >> 2)) * (long)ldb + scol;
  const int ldsw = w * 1024;

#define STG_A3(slot, k0, r)                                                    \
  __builtin_amdgcn_global_load_lds(gA + (k0) + (long)(r) * 128 * lda,          \
      (uint16_t*)(lds + (slot) * 32768 + (r) * 8192 + ldsw), 16, 0, 0)
#define STG_B3(slot, k0, r)                                                    \
  __builtin_amdgcn_global_load_lds(gB + (k0) + (long)(r) * 128 * ldb,          \
      (uint16_t*)(lds + (slot) * 32768 + 16384 + (r) * 8192 + ldsw), 16, 0, 0)

  // fragment read geometry: row stride 64B; lane reads 16B at swizzled chunk
  const int lr = l & 15;
  const int chunkx = (((l >> 4) ^ ((lr >> 1) & 3)) << 4);  // bytes
  const int aoff = (wm * 128 + lr) * 64 + chunkx;
  const int boff = 16384 + (wn * 64 + lr) * 64 + chunkx;

  floatx4 acc[8][4];
#pragma unroll
  for (int i = 0; i < 8; i++)
#pragma unroll
    for (int j = 0; j < 4; j++) acc[i][j] = (floatx4){0.f, 0.f, 0.f, 0.f};

  const int nt = K >> 5;  // assumes nt >= 3
  // prologue: stage tiles 0,1,2 (FIFO order matches in-loop per-tile order A,A,B,B)
#pragma unroll
  for (int tt = 0; tt < 3; tt++) {
    STG_A3(tt, tt * 32, 0); STG_A3(tt, tt * 32, 1);
    STG_B3(tt, tt * 32, 0); STG_B3(tt, tt * 32, 1);
  }

  for (int t = 0; t < nt; t++) {
    const char* Ls = lds + (t & 3) * 32768;
    // own tile-t loads retired (8 newer stay in flight), then cross-wave fence
    if (t + 2 < nt) asm volatile("s_waitcnt vmcnt(8)" ::: "memory");
    else            asm volatile("s_waitcnt vmcnt(0)" ::: "memory");
    SBAR();

    bf16x8 Bf[4], Af0[4], Af1[4];
#pragma unroll
    for (int j = 0; j < 4; j++) Bf[j] = *(const bf16x8*)(Ls + boff + j * 1024);
#pragma unroll
    for (int i = 0; i < 4; i++) Af0[i] = *(const bf16x8*)(Ls + aoff + i * 1024);
    SCHED();  // pin DS issue count: first 8 = Bf + Af0

    const long pk0 = (long)(t + 3) << 5;
    const int pslot = (t + 3) & 3;
    const bool pf = (t + 3 < nt);
    if (pf) { STG_A3(pslot, pk0, 0); STG_A3(pslot, pk0, 1); }

#pragma unroll
    for (int i = 0; i < 4; i++) Af1[i] = *(const bf16x8*)(Ls + aoff + (4 + i) * 1024);
    SCHED();

    asm volatile("s_waitcnt lgkmcnt(4)" ::: "memory");  // Bf+Af0 landed; Af1 drains under MFMA
    SCHED();
    __builtin_amdgcn_s_setprio(1);
#pragma unroll
    for (int i = 0; i < 4; i++)
#pragma unroll
      for (int j = 0; j < 4; j++) mfma16(acc[i][j], Af0[i], Bf[j]);
    __builtin_amdgcn_s_setprio(0);
    SCHED();

    if (pf) { STG_B3(pslot, pk0, 0); STG_B3(pslot, pk0, 1); }

    asm volatile("s_waitcnt lgkmcnt(0)" ::: "memory");
    SCHED();
    __builtin_amdgcn_s_setprio(1);
#pragma unroll
    for (int i = 0; i < 4; i++)
#pragma unroll
      for (int j = 0; j < 4; j++) mfma16(acc[4 + i][j], Af1[i], Bf[j]);
    __builtin_amdgcn_s_setprio(0);
    SCHED();
  }
#undef STG_A3
#undef STG_B3

  const long crow = bm + wm * 128 + ((l >> 4) * 4);
  const long ccol = bn + wn * 64 + (l & 15);
  if constexpr (MODE == 0) {
    float* C = (float*)C0v + (long)blockIdx.z * sC;
#pragma unroll
    for (int i = 0; i < 8; i++)
#pragma unroll
      for (int r = 0; r < 4; r++) {
        long row = crow + i * 16 + r;
#pragma unroll
        for (int j = 0; j < 4; j++) C[row * (long)ldc + ccol + j * 16] = acc[i][j][r];
      }
  } else if constexpr (MODE == 1) {
    uint16_t* C = (uint16_t*)C0v + (long)blockIdx.z * sC;
#pragma unroll
    for (int i = 0; i < 8; i++)
#pragma unroll
      for (int r = 0; r < 4; r++) {
        long row = crow + i * 16 + r;
#pragma unroll
        for (int j = 0; j < 4; j++) C[row * (long)ldc + ccol + j * 16] = f2bf(acc[i][j][r]);
      }
  } else if constexpr (MODE == 3) {
    const float s = 1.0f / 12.0f;
    uint16_t* C = (uint16_t*)C0v + (long)blockIdx.z * sC;
#pragma unroll
    for (int i = 0; i < 8; i++)
#pragma unroll
      for (int r = 0; r < 4; r++) {
        long row = crow + i * 16 + r;
#pragma unroll
        for (int j = 0; j < 4; j++) C[row * (long)ldc + ccol + j * 16] = f2bf(acc[i][j][r] * s);
      }
  } else {
    if (bn < 512) {
      uint16_t* C = (uint16_t*)C0v;
#pragma unroll
      for (int i = 0; i < 8; i++)
#pragma unroll
        for (int r = 0; r < 4; r++) {
          long row = crow + i * 16 + r;
#pragma unroll
          for (int j = 0; j < 4; j++) C[row * 512 + ccol + j * 16] = f2bf(acc[i][j][r]);
        }
    } else if (bn < 1024) {
      float* C = (float*)C1v;
      const long cc = ccol - 512;
#pragma unroll
      for (int i = 0; i < 8; i++)
#pragma unroll
        for (int r = 0; r < 4; r++) {
          long row = crow + i * 16 + r;
#pragma unroll
          for (int j = 0; j < 4; j++) C[row * 512 + cc + j * 16] = acc[i][j][r];
        }
    } else {
      uint16_t* C = (uint16_t*)C2v;
      const long cc = ccol - 1024;
#pragma unroll
      for (int i = 0; i < 8; i++)
#pragma unroll
        for (int r = 0; r < 4; r++) {
          long row = crow + i * 16 + r;
#pragma unroll
          for (int j = 0; j < 4; j++) C[row * 2560 + cc + j * 16] = f2bf(acc[i][j][r]);
        }
    }
  }
}

// ================= 256x128 pipelined GEMM (for the small-N o GEMM) =================
template<int OUTB>
__global__ void __launch_bounds__(512, 2) gemm256(
    const uint16_t* __restrict__ A, const uint16_t* __restrict__ B,
    void* __restrict__ Cv, int K, int lda, int ldb, int ldc,
    long sA, long sB, long sC)
{
  __shared__ __attribute__((aligned(16))) char lds[147456];
  const int tid = threadIdx.x;
  const int w = tid >> 6, l = tid & 63;
  const int wm = w >> 1, wn = w & 1;

  const int gx = gridDim.x;
  const int nwg = gx * gridDim.y;
  int id = blockIdx.y * gx + blockIdx.x;
  if ((nwg & 7) == 0) id = (id & 7) * (nwg >> 3) + (id >> 3);
  const long bm = (long)(id % gx) * 256;
  const long bn = (long)(id / gx) * 128;
  A += (long)blockIdx.z * sA;
  B += (long)blockIdx.z * sB;

  const int sr = l >> 3;
  const int sc = l & 7;
  const int scol = ((sc ^ sr) << 3);
  const uint16_t* gA = A + (bm + w * 8 + sr) * (long)lda + scol;
  const uint16_t* gB = B + (bn + w * 8 + sr) * (long)ldb + scol;
  const int ldsw = w * 1024;

#define STAGE_A(bufi, k0, r)                                                     \
  __builtin_amdgcn_global_load_lds(gA + (k0) + (long)(r) * 64 * lda,             \
      (uint16_t*)(lds + (bufi) * 49152 + (r) * 8192 + ldsw), 16, 0, 0)
#define STAGE_B(bufi, k0, r)                                                     \
  __builtin_amdgcn_global_load_lds(gB + (k0) + (long)(r) * 64 * ldb,             \
      (uint16_t*)(lds + (bufi) * 49152 + 32768 + (r) * 8192 + ldsw), 16, 0, 0)

  const int lr = l & 15;
  const int kk = (l >> 4) << 4;
  const int msk = (l & 7) << 4;
  const int ko0 = kk ^ msk;
  const int ko1 = (64 + kk) ^ msk;
  const int arow = (wm * 64 + lr) * 128;
  const int brow = (wn * 64 + lr) * 128;

  floatx4 acc[4][4];
#pragma unroll
  for (int i = 0; i < 4; i++)
#pragma unroll
    for (int j = 0; j < 4; j++) acc[i][j] = (floatx4){0.f, 0.f, 0.f, 0.f};

  const int nt = K >> 6;
#pragma unroll
  for (int r = 0; r < 4; r++) STAGE_A(0, 0, r);
#pragma unroll
  for (int r = 0; r < 2; r++) STAGE_B(0, 0, r);
#pragma unroll
  for (int r = 0; r < 4; r++) STAGE_A(1, 64, r);
#pragma unroll
  for (int r = 0; r < 2; r++) STAGE_B(1, 64, r);
  asm volatile("s_waitcnt vmcnt(6)" ::: "memory");
  SBAR();

  bf16x8 af0[4], bf0[4], af1[4], bf1[4];
  {
    const char* LA = lds + arow;
    const char* LB = lds + 32768 + brow;
#pragma unroll
    for (int i = 0; i < 4; i++) af0[i] = *(const bf16x8*)(LA + i * 2048 + ko0);
#pragma unroll
    for (int j = 0; j < 4; j++) bf0[j] = *(const bf16x8*)(LB + j * 2048 + ko0);
  }

  for (int t = 0; t < nt; t++) {
    const int buf = t % 3;
    const int pbuf = (t + 2) % 3;
    const long pk0 = (long)(t + 2) << 6;
    const char* LA = lds + buf * 49152 + arow;
    const char* LB = lds + buf * 49152 + 32768 + brow;
    const bool pf = (t + 2 < nt);

    if (pf) { STAGE_A(pbuf, pk0, 0); STAGE_A(pbuf, pk0, 1); STAGE_B(pbuf, pk0, 0); }
#pragma unroll
    for (int i = 0; i < 4; i++) af1[i] = *(const bf16x8*)(LA + i * 2048 + ko1);
#pragma unroll
    for (int j = 0; j < 4; j++) bf1[j] = *(const bf16x8*)(LB + j * 2048 + ko1);
    SCHED();
    __builtin_amdgcn_s_setprio(1);
#pragma unroll
    for (int i = 0; i < 4; i++)
#pragma unroll
      for (int j = 0; j < 4; j++) mfma16(acc[i][j], af0[i], bf0[j]);
    __builtin_amdgcn_s_setprio(0);
    SCHED();

    if (pf) { STAGE_A(pbuf, pk0, 2); STAGE_A(pbuf, pk0, 3); STAGE_B(pbuf, pk0, 1); }
    if (t < nt - 2) asm volatile("s_waitcnt vmcnt(6) lgkmcnt(0)" ::: "memory");
    else            asm volatile("s_waitcnt vmcnt(0) lgkmcnt(0)" ::: "memory");
    SBAR();
    if (t < nt - 1) {
      const char* LAn = lds + ((t + 1) % 3) * 49152 + arow;
      const char* LBn = lds + ((t + 1) % 3) * 49152 + 32768 + brow;
#pragma unroll
      for (int i = 0; i < 4; i++) af0[i] = *(const bf16x8*)(LAn + i * 2048 + ko0);
#pragma unroll
      for (int j = 0; j < 4; j++) bf0[j] = *(const bf16x8*)(LBn + j * 2048 + ko0);
    }
    SCHED();
    __builtin_amdgcn_s_setprio(1);
#pragma unroll
    for (int i = 0; i < 4; i++)
#pragma unroll
      for (int j = 0; j < 4; j++) mfma16(acc[i][j], af1[i], bf1[j]);
    __builtin_amdgcn_s_setprio(0);
    SCHED();
  }
#undef STAGE_A
#undef STAGE_B

  const long crow = bm + wm * 64 + ((l >> 4) * 4);
  const long ccol = bn + wn * 64 + (l & 15);
  if constexpr (OUTB == 0) {
    float* C = (float*)Cv + (long)blockIdx.z * sC;
#pragma unroll
    for (int i = 0; i < 4; i++)
#pragma unroll
      for (int r = 0; r < 4; r++) {
        long row = crow + i * 16 + r;
#pragma unroll
        for (int j = 0; j < 4; j++) C[row * (long)ldc + ccol + j * 16] = acc[i][j][r];
      }
  } else {
    uint16_t* C = (uint16_t*)Cv + (long)blockIdx.z * sC;
#pragma unroll
    for (int i = 0; i < 4; i++)
#pragma unroll
      for (int r = 0; r < 4; r++) {
        long row = crow + i * 16 + r;
#pragma unroll
        for (int j = 0; j < 4; j++) C[row * (long)ldc + ccol + j * 16] = f2bf(acc[i][j][r]);
      }
  }
}

// ================= legacy 128x128 GEMM (small weight-prep matmuls) =================
template<int OUTB>
__global__ void __launch_bounds__(256) gemm_bt(
    const uint16_t* __restrict__ A, const uint16_t* __restrict__ B,
    void* __restrict__ Cv, int K, int lda, int ldb, int ldc,
    long sA, long sB, long sC)
{
  __shared__ alignas(16) uint16_t As[4096];
  __shared__ alignas(16) uint16_t Bs[4096];
  const int tid = threadIdx.x;
  const int w = tid >> 6, l = tid & 63;
  const int wr = w >> 1, wc = w & 1;
  const long bm = (long)blockIdx.x * 128, bn = (long)blockIdx.y * 128;
  A += (long)blockIdx.z * sA;
  B += (long)blockIdx.z * sB;

  const uint16_t* ga0 = A + (bm + w * 16 + (l >> 2)) * (long)lda + (l & 3) * 8;
  const uint16_t* ga1 = ga0 + 64L * lda;
  const uint16_t* gb0 = B + (bn + w * 16 + (l >> 2)) * (long)ldb + (l & 3) * 8;
  const uint16_t* gb1 = gb0 + 64L * ldb;
  uint16_t* la0 = &As[w * 512];
  uint16_t* la1 = &As[2048 + w * 512];
  uint16_t* lb0 = &Bs[w * 512];
  uint16_t* lb1 = &Bs[2048 + w * 512];

  floatx4 acc[4][4];
#pragma unroll
  for (int i = 0; i < 4; i++)
#pragma unroll
    for (int j = 0; j < 4; j++) acc[i][j] = (floatx4){0.f, 0.f, 0.f, 0.f};

  const int rA = (wr * 64 + (l & 15)) * 32 + (l >> 4) * 8;
  const int rB = (wc * 64 + (l & 15)) * 32 + (l >> 4) * 8;

  for (int k0 = 0; k0 < K; k0 += 32) {
    __builtin_amdgcn_global_load_lds(ga0, la0, 16, 0, 0);
    __builtin_amdgcn_global_load_lds(ga1, la1, 16, 0, 0);
    __builtin_amdgcn_global_load_lds(gb0, lb0, 16, 0, 0);
    __builtin_amdgcn_global_load_lds(gb1, lb1, 16, 0, 0);
    ga0 += 32; ga1 += 32; gb0 += 32; gb1 += 32;
    __syncthreads();
    bf16x8 af[4], bfr[4];
#pragma unroll
    for (int i = 0; i < 4; i++) af[i] = *(const bf16x8*)&As[rA + i * 512];
#pragma unroll
    for (int j = 0; j < 4; j++) bfr[j] = *(const bf16x8*)&Bs[rB + j * 512];
#pragma unroll
    for (int i = 0; i < 4; i++)
#pragma unroll
      for (int j = 0; j < 4; j++) mfma16(acc[i][j], af[i], bfr[j]);
    __syncthreads();
  }

  const long crow = bm + wr * 64 + ((l >> 4) * 4);
  const long ccol = bn + wc * 64 + (l & 15);
  if constexpr (OUTB == 0) {
    float* C = (float*)Cv + (long)blockIdx.z * sC;
#pragma unroll
    for (int i = 0; i < 4; i++)
#pragma unroll
      for (int r = 0; r < 4; r++) {
        long row = crow + i * 16 + r;
#pragma unroll
        for (int j = 0; j < 4; j++) C[row * (long)ldc + ccol + j * 16] = acc[i][j][r];
      }
  } else {
    uint16_t* C = (uint16_t*)Cv + (long)blockIdx.z * sC;
#pragma unroll
    for (int i = 0; i < 4; i++)
#pragma unroll
      for (int r = 0; r < 4; r++) {
        long row = crow + i * 16 + r;
#pragma unroll
        for (int j = 0; j < 4; j++) C[row * (long)ldc + ccol + j * 16] = f2bf(acc[i][j][r]);
      }
  }
}

// ---------- fp32 -> bf16 convert (h) ----------
__global__ void __launch_bounds__(256) cvt_k(const float* __restrict__ in,
                                             uint16_t* __restrict__ out, long n) {
  long i = ((long)blockIdx.x * 256 + threadIdx.x) * 4;
  if (i >= n) return;
  float4 v = *(const float4*)(in + i);
  ushort4 o; o.x = f2bf(v.x); o.y = f2bf(v.y); o.z = f2bf(v.z); o.w = f2bf(v.w);
  *(ushort4*)(out + i) = o;
}

// ---------- fused small-weight converts + rope table (one launch) ----------
__global__ void __launch_bounds__(256) prep_small(
    const float* __restrict__ wdq, const float* __restrict__ wdkv,
    const float* __restrict__ wqr, const float* __restrict__ wkr,
    const float* __restrict__ wo,
    uint16_t* __restrict__ wdq_b, uint16_t* __restrict__ wdkv_b,
    uint16_t* __restrict__ wqr_b, uint16_t* __restrict__ wkr_b,
    uint16_t* __restrict__ wo_b, float2* __restrict__ rtab)
{
  const int b = blockIdx.x;
  if (b < 11264) {
    const float* src; uint16_t* dst; long off;
    if (b < 1024)      { src = wdq;  dst = wdq_b;  off = b; }
    else if (b < 2048) { src = wdkv; dst = wdkv_b; off = b - 1024; }
    else if (b < 3072) { src = wqr;  dst = wqr_b;  off = b - 2048; }
    else if (b < 7168) { src = wkr;  dst = wkr_b;  off = b - 3072; }
    else               { src = wo;   dst = wo_b;   off = b - 7168; }
    long i = (off * 256 + threadIdx.x) * 4;
    float4 v = *(const float4*)(src + i);
    ushort4 o; o.x = f2bf(v.x); o.y = f2bf(v.y); o.z = f2bf(v.z); o.w = f2bf(v.w);
    *(ushort4*)(dst + i) = o;
  } else {
    int idx = (b - 11264) * 256 + threadIdx.x;  // 2048*64
    int s = idx >> 6, fi = idx & 63;
    float f = powf(10000.0f, -(float)fi * (1.0f / 64.0f));
    float ang = (float)s * f;
    rtab[idx] = make_float2(cosf(ang), sinf(ang));
  }
}

// ---------- transpose (R,Cc) -> (Cc,R), bf16 out ----------
template<typename TIN>
__global__ void __launch_bounds__(256) transpose_to_bf16(
    const TIN* __restrict__ in, uint16_t* __restrict__ out,
    int ld_in, int ld_out, long sIn, long sOut)
{
  __shared__ float tile[32][33];
  in += (long)blockIdx.z * sIn;
  out += (long)blockIdx.z * sOut;
  const int rb = blockIdx.y * 32, cb = blockIdx.x * 32;
#pragma unroll
  for (int i = 0; i < 32; i += 8)
    tile[threadIdx.y + i][threadIdx.x] =
        ld_as_float(in[(long)(rb + threadIdx.y + i) * ld_in + cb + threadIdx.x]);
  __syncthreads();
#pragma unroll
  for (int i = 0; i < 32; i += 8)
    out[(long)(cb + threadIdx.y + i) * ld_out + rb + threadIdx.x] =
        f2bf(tile[threadIdx.x][threadIdx.y + i]);
}

// ---------- rmsnorm: one block per row; DIM = PT*256 ----------
template<int PT, typename TIN>
__global__ void __launch_bounds__(256) rmsnorm_k(
    const TIN* __restrict__ in, const float* __restrict__ g,
    float* __restrict__ out_f, uint16_t* __restrict__ out_b, int ld_b)
{
  constexpr int DIM = PT * 256;
  __shared__ float sm[9];
  const TIN* x = in + (long)blockIdx.x * DIM;
  const int base = threadIdx.x * PT;
  float v[PT];
  if constexpr (sizeof(TIN) == 2) {
    if constexpr (PT >= 8) {
#pragma unroll
      for (int i = 0; i < PT; i += 8) {
        u16x8 t = *(const u16x8*)&x[base + i];
#pragma unroll
        for (int q = 0; q < 8; q++) v[i + q] = bf2f(t[q]);
      }
    } else {
#pragma unroll
      for (int i = 0; i < PT; i += 2) {
        ushort2 t = *(const ushort2*)&x[base + i];
        v[i] = bf2f(t.x); v[i + 1] = bf2f(t.y);
      }
    }
  } else if constexpr (PT == 2) {
    float2 t = *(const float2*)&x[base]; v[0] = t.x; v[1] = t.y;
  } else {
#pragma unroll
    for (int i = 0; i < PT; i += 4) {
      float4 t = *(const float4*)&x[base + i];
      v[i] = t.x; v[i + 1] = t.y; v[i + 2] = t.z; v[i + 3] = t.w;
    }
  }
  float ss = 0.f;
#pragma unroll
  for (int i = 0; i < PT; i++) ss += v[i] * v[i];
#pragma unroll
  for (int o = 32; o; o >>= 1) ss += __shfl_down(ss, o);
  if ((threadIdx.x & 63) == 0) sm[threadIdx.x >> 6] = ss;
  __syncthreads();
  if (threadIdx.x == 0)
    sm[8] = rsqrtf((sm[0] + sm[1] + sm[2] + sm[3]) * (1.0f / DIM) + 1.1920929e-7f);
  __syncthreads();
  const float sc = sm[8];
#pragma unroll
  for (int i = 0; i < PT; i++) {
    float y = v[i] * sc * g[base + i];
    if (out_f) out_f[(long)blockIdx.x * DIM + base + i] = y;
    if (out_b) out_b[(long)blockIdx.x * ld_b + base + i] = f2bf(y);
  }
}

// ---------- rope apply: in bf16 (8192,2048); bf16 out -> cat[:,512:]; optional fp32 out ----------
template<bool WF32>
__global__ void __launch_bounds__(256) rope_k(
    const uint16_t* __restrict__ in, uint16_t* __restrict__ outb,
    float* __restrict__ outf, const float2* __restrict__ tab)
{
  long idx = (long)blockIdx.x * 256 + threadIdx.x;  // 8192*1024 pairs
  int r = (int)(idx >> 10);
  int pp = (int)idx & 1023;
  int s = r & 2047;
  int fi = pp & 63;
  ushort2 xv = *(const ushort2*)(in + ((long)r << 11) + 2 * pp);
  float x0 = bf2f(xv.x), x1 = bf2f(xv.y);
  float2 cs = tab[(s << 6) + fi];
  float y0 = x0 * cs.x - x1 * cs.y;
  float y1 = x0 * cs.y + x1 * cs.x;
  ushort2 ov; ov.x = f2bf(y0); ov.y = f2bf(y1);
  *(ushort2*)(outb + (long)r * 2560 + 512 + 2 * pp) = ov;
  if (WF32) *(float2*)(outf + ((long)r << 11) + 2 * pp) = make_float2(y0, y1);
}

// ---------- softmax over rows of 2048, bf16 in (pre-scaled), bf16 out ----------
__global__ void __launch_bounds__(256) softmax_k(const uint16_t* __restrict__ sc,
                                                 uint16_t* __restrict__ attn) {
  __shared__ float sm[9];
  const uint16_t* x = sc + ((long)blockIdx.x << 11);
  const int base = threadIdx.x * 8;
  float v[8];
  u16x8 t = *(const u16x8*)&x[base];
#pragma unroll
  for (int i = 0; i < 8; i++) v[i] = bf2f(t[i]);
  float m = -1e30f;
#pragma unroll
  for (int i = 0; i < 8; i++) m = fmaxf(m, v[i]);
#pragma unroll
  for (int o = 32; o; o >>= 1) m = fmaxf(m, __shfl_down(m, o));
  if ((threadIdx.x & 63) == 0) sm[threadIdx.x >> 6] = m;
  __syncthreads();
  if (threadIdx.x == 0)
    sm[8] = fmaxf(fmaxf(sm[0], sm[1]), fmaxf(sm[2], sm[3]));
  __syncthreads();
  m = sm[8];
  __syncthreads();
  float ss = 0.f;
#pragma unroll
  for (int i = 0; i < 8; i++) { v[i] = __expf(v[i] - m); ss += v[i]; }
#pragma unroll
  for (int o = 32; o; o >>= 1) ss += __shfl_down(ss, o);
  if ((threadIdx.x & 63) == 0) sm[threadIdx.x >> 6] = ss;
  __syncthreads();
  if (threadIdx.x == 0) sm[8] = 1.0f / (sm[0] + sm[1] + sm[2] + sm[3]);
  __syncthreads();
  const float r = sm[8];
  ushort4 o1, o2;
  o1.x = f2bf(v[0] * r); o1.y = f2bf(v[1] * r); o1.z = f2bf(v[2] * r); o1.w = f2bf(v[3] * r);
  o2.x = f2bf(v[4] * r); o2.y = f2bf(v[5] * r); o2.z = f2bf(v[6] * r); o2.w = f2bf(v[7] * r);
  uint16_t* dst = attn + ((long)blockIdx.x << 11) + base;
  *(ushort4*)dst = o1;
  *(ushort4*)(dst + 4) = o2;
}

// ---------- orchestration ----------
extern "C" void kernel_launch(void* const* d_in, const int* in_sizes, int n_in,
                              void* d_out, int out_size, void* d_ws, size_t ws_size,
                              hipStream_t stream) {
  (void)in_sizes; (void)n_in; (void)out_size; (void)ws_size;
  const float* h    = (const float*)d_in[0];
  const float* wdkv = (const float*)d_in[1];
  const float* wuk  = (const float*)d_in[2];
  const float* wuv  = (const float*)d_in[3];
  const float* wdq  = (const float*)d_in[4];
  const float* wuq  = (const float*)d_in[5];
  const float* wkr  = (const float*)d_in[6];
  const float* wqr  = (const float*)d_in[7];
  const float* wo   = (const float*)d_in[8];
  const float* g1   = (const float*)d_in[9];
  const float* g2   = (const float*)d_in[10];
  const float* g3   = (const float*)d_in[11];

  float* u_out   = (float*)d_out;                 // (4,2048,2048)
  float* ckv_out = u_out + 16777216L;             // (4,2048,512)
  float* kr_out  = ckv_out + 4194304L;            // (4,2048,2048)

  char* p = (char*)d_ws;
  auto alloc = [&](size_t bytes) -> void* {
    void* q = (void*)p; p += (bytes + 255) & ~(size_t)255; return q;
  };
  uint16_t* hb     = (uint16_t*)alloc(16777216ULL * 2);  // h bf16
  uint16_t* wcat   = (uint16_t*)alloc(3145728ULL * 2);   // (1536,2048) [wdq;wdkv;Bqt]
  uint16_t* wqr_b  = (uint16_t*)alloc(1048576ULL * 2);
  uint16_t* wkr_b  = (uint16_t*)alloc(4194304ULL * 2);
  uint16_t* wo_b   = (uint16_t*)alloc(4194304ULL * 2);
  uint16_t* wukT   = (uint16_t*)alloc(1048576ULL * 2);   // (512,2048)
  uint16_t* wuqT   = (uint16_t*)alloc(1048576ULL * 2);
  uint16_t* wuvT   = (uint16_t*)alloc(1048576ULL * 2);
  uint16_t* wdqT   = (uint16_t*)alloc(1048576ULL * 2);   // (2048,512)
  uint16_t* T1t    = (uint16_t*)alloc(262144ULL * 2);    // (512,512)
  uint16_t* awoT   = (uint16_t*)alloc(1048576ULL * 2);   // absorbed_w_o^T (2048,512)
  uint16_t* cqpre  = (uint16_t*)alloc(4194304ULL * 2);   // (8192,512) bf16 cq-pre
  uint16_t* cq_b   = (uint16_t*)alloc(4194304ULL * 2);   // (8192,512)
  uint16_t* catq   = (uint16_t*)alloc(20971520ULL * 2);  // (8192,2560) [aq|qr]
  uint16_t* catk   = (uint16_t*)alloc(20971520ULL * 2);  // (8192,2560) [ckv|kr]
  uint16_t* ckvT   = (uint16_t*)alloc(4194304ULL * 2);   // 4 x (512,2048)
  uint16_t* o_b    = (uint16_t*)alloc(4194304ULL * 2);   // (8192,512)
  float2*   rtab   = (float2*)alloc(131072ULL * 8);      // 2048x64 (cos,sin)
  float*    tmpS2  = (float*)alloc(4194304ULL * 4);      // (8192,512) fp32 ckv-pre
  float*    tmpB   = (float*)alloc(16777216ULL * 4);     // (8192,2048) scratch
  uint16_t* tmpBb  = (uint16_t*)tmpB;                    // alias: (8192,2048) bf16
  uint16_t* attn   = catq;  // alias: catq dead after scores GEMM

  uint16_t* wdq_b  = wcat;                  // rows 0-511
  uint16_t* wdkv_b = wcat + 1048576;        // rows 512-1023
  uint16_t* Bqt    = wcat + 2097152;        // rows 1024-1535 (absorbed_w_q^T)

  const dim3 b256(256);
  const dim3 b512(512);
  const dim3 tb(32, 8);

  // h convert + fused small-weight converts + rope table
  cvt_k<<<dim3(16384), b256, 0, stream>>>(h, hb, 16777216L);
  prep_small<<<dim3(11776), b256, 0, stream>>>(
      wdq, wdkv, wqr, wkr, wo, wdq_b, wdkv_b, wqr_b, wkr_b, wo_b, rtab);
  // weight transposes (fp32 -> bf16)
  transpose_to_bf16<float><<<dim3(16, 64, 1), tb, 0, stream>>>(wuk, wukT, 512, 2048, 0, 0);
  transpose_to_bf16<float><<<dim3(16, 64, 1), tb, 0, stream>>>(wuq, wuqT, 512, 2048, 0, 0);
  transpose_to_bf16<float><<<dim3(16, 64, 1), tb, 0, stream>>>(wuv, wuvT, 512, 2048, 0, 0);
  transpose_to_bf16<float><<<dim3(64, 16, 1), tb, 0, stream>>>(wdq, wdqT, 2048, 512, 0, 0);

  // absorbed weights (small — legacy kernel)
  gemm_bt<1><<<dim3(4, 4, 1), b256, 0, stream>>>(wukT, wuqT, T1t, 2048, 2048, 2048, 512, 0, 0, 0);
  gemm_bt<1><<<dim3(4, 16, 1), b256, 0, stream>>>(T1t, wdqT, Bqt, 512, 512, 512, 2048, 0, 0, 0);
  gemm_bt<1><<<dim3(16, 4, 1), b256, 0, stream>>>(wo_b, wuvT, awoT, 2048, 2048, 2048, 512, 0, 0, 0);

  // fused: [cq-pre(bf16) | ckv-pre(fp32) | aq(bf16)] = h @ [wdq; wdkv; Bqt]^T
  gemm256v3<2><<<dim3(32, 6, 1), b512, 0, stream>>>(
      hb, wcat, cqpre, tmpS2, catq, 2048, 2048, 2048, 0, 0, 0, 0);
  // cq = rmsnorm(cq-pre, g1)
  rmsnorm_k<2, uint16_t><<<dim3(8192), b256, 0, stream>>>(cqpre, g1, nullptr, cq_b, 512);
  // qr = rope(cq @ wqr^T) -> catq[:,512:]
  gemm256v3<1><<<dim3(32, 8, 1), b512, 0, stream>>>(
      cq_b, wqr_b, tmpBb, nullptr, nullptr, 512, 512, 512, 2048, 0, 0, 0);
  rope_k<false><<<dim3(32768), b256, 0, stream>>>(tmpBb, catq, nullptr, rtab);
  // ckv = rmsnorm(ckv-pre, g2) -> ckv_out (fp32) + catk[:,0:512] (bf16)
  rmsnorm_k<2, float><<<dim3(8192), b256, 0, stream>>>(tmpS2, g2, ckv_out, catk, 2560);
  // ckvT: 4 x (512,2048) from catk cols 0..511
  transpose_to_bf16<uint16_t><<<dim3(16, 64, 4), tb, 0, stream>>>(
      catk, ckvT, 2560, 2048, 2048L * 2560, 512L * 2048);
  // kr = rope(h @ wkr^T) -> kr_out (fp32) + catk[:,512:]
  gemm256v3<1><<<dim3(32, 8, 1), b512, 0, stream>>>(
      hb, wkr_b, tmpBb, nullptr, nullptr, 2048, 2048, 2048, 2048, 0, 0, 0);
  rope_k<true><<<dim3(32768), b256, 0, stream>>>(tmpBb, catk, kr_out, rtab);
  // scores[b]/12 = (catq_b @ catk_b^T)/12 -> tmpBb bf16 (K=2560)
  gemm256v3<3><<<dim3(8, 8, 4), b512, 0, stream>>>(
      catq, catk, tmpBb, nullptr, nullptr, 2560, 2560, 2560, 2048,
      5242880L, 5242880L, 4194304L);
  // softmax -> attn bf16 (aliases catq)
  softmax_k<<<dim3(8192), b256, 0, stream>>>(tmpBb, attn);
  // o[b] = attn_b @ ckv_b (via ckvT) -> o_b bf16
  gemm256<1><<<dim3(8, 4, 4), b512, 0, stream>>>(
      attn, ckvT, o_b, 2048, 2048, 2048, 512, 4194304L, 1048576L, 1048576L);
  // u = rmsnorm(o @ absorbed_w_o, g3) -> u_out
  gemm256v3<1><<<dim3(32, 8, 1), b512, 0, stream>>>(
      o_b, awoT, tmpBb, nullptr, nullptr, 512, 512, 512, 2048, 0, 0, 0);
  rmsnorm_k<8, uint16_t><<<dim3(8192), b256, 0, stream>>>(tmpBb, g3, u_out, nullptr, 0);
}